// Round 7
// baseline (294.829 us; speedup 1.0000x reference)
//
#include <hip/hip_runtime.h>

#define Bq 2
#define Hh 8
#define Ss 512
#define HD 64
#define DIM 512

using f32x4   = __attribute__((ext_vector_type(4))) float;
using bf16x8s = __attribute__((ext_vector_type(8))) short;
typedef _Float16 f16x8 __attribute__((ext_vector_type(8)));

__constant__ int d_tIs[36] = {0,1,1,2,2,2,3,3,3,3,4,4,4,4,4,5,5,5,5,5,5,6,6,6,6,6,6,6,7,7,7,7,7,7,7,7};
__constant__ int d_tJs[36] = {0,0,1,0,1,2,0,1,2,3,0,1,2,3,4,0,1,2,3,4,5,0,1,2,3,4,5,6,0,1,2,3,4,5,6,7};

__device__ __forceinline__ float bf2f(unsigned short u) {
    return __uint_as_float(((unsigned int)u) << 16);
}
__device__ __forceinline__ unsigned short f2bf(float f) {
    unsigned int u = __float_as_uint(f);
    u = (u + 0x7FFFu + ((u >> 16) & 1u)) >> 16;   // RNE
    return (unsigned short)u;
}

// ============ mm_k: C = A @ B^T + bias (fp32 io, split bf16x2 MFMA, 128x128) ============
__global__ __launch_bounds__(256) void mm_k(
    const float* __restrict__ A, const float* __restrict__ B,
    const float* __restrict__ bias, float* __restrict__ C,
    int K, int ldc)
{
    const int row0 = blockIdx.y * 128, col0 = blockIdx.x * 128;
    __shared__ unsigned short AsH[128][40], AsL[128][40];
    __shared__ unsigned short BsH[128][40], BsL[128][40];
    const int t = threadIdx.x;
    const int wave = t >> 6, lane = t & 63;
    const int ln = lane & 15, quad = lane >> 4;
    const int wm = (wave & 1) * 64, wn = (wave >> 1) * 64;

    f32x4 acc[4][4];
#pragma unroll
    for (int i = 0; i < 4; ++i)
#pragma unroll
        for (int j = 0; j < 4; ++j)
            acc[i][j] = (f32x4){0.f, 0.f, 0.f, 0.f};

    const int sr = t >> 2, sg = (t & 3) * 8;

    for (int k0 = 0; k0 < K; k0 += 32) {
        __syncthreads();
#pragma unroll
        for (int half = 0; half < 4; ++half) {
            const float* src = (half < 2) ? A : B;
            int base = (half < 2) ? row0 : col0;
            int row = sr + ((half & 1) ? 64 : 0);
            const float* p = &src[(long)(base + row) * K + k0 + sg];
            float4 f0 = *(const float4*)p;
            float4 f1 = *(const float4*)(p + 4);
            float fv[8] = {f0.x, f0.y, f0.z, f0.w, f1.x, f1.y, f1.z, f1.w};
            unsigned short hv[8], lv[8];
#pragma unroll
            for (int e = 0; e < 8; ++e) {
                hv[e] = f2bf(fv[e]);
                lv[e] = f2bf(fv[e] - bf2f(hv[e]));
            }
            uint4 H, L;
            H.x = hv[0] | (hv[1] << 16); H.y = hv[2] | (hv[3] << 16);
            H.z = hv[4] | (hv[5] << 16); H.w = hv[6] | (hv[7] << 16);
            L.x = lv[0] | (lv[1] << 16); L.y = lv[2] | (lv[3] << 16);
            L.z = lv[4] | (lv[5] << 16); L.w = lv[6] | (lv[7] << 16);
            if (half < 2) { *(uint4*)&AsH[row][sg] = H; *(uint4*)&AsL[row][sg] = L; }
            else          { *(uint4*)&BsH[row][sg] = H; *(uint4*)&BsL[row][sg] = L; }
        }
        __syncthreads();

        bf16x8s afH[4], afL[4], bfH[4], bfL[4];
#pragma unroll
        for (int mt = 0; mt < 4; ++mt) {
            afH[mt] = *(const bf16x8s*)&AsH[wm + mt * 16 + ln][quad * 8];
            afL[mt] = *(const bf16x8s*)&AsL[wm + mt * 16 + ln][quad * 8];
        }
#pragma unroll
        for (int nt = 0; nt < 4; ++nt) {
            bfH[nt] = *(const bf16x8s*)&BsH[wn + nt * 16 + ln][quad * 8];
            bfL[nt] = *(const bf16x8s*)&BsL[wn + nt * 16 + ln][quad * 8];
        }
#pragma unroll
        for (int mt = 0; mt < 4; ++mt)
#pragma unroll
            for (int nt = 0; nt < 4; ++nt) {
                acc[mt][nt] = __builtin_amdgcn_mfma_f32_16x16x32_bf16(afH[mt], bfH[nt], acc[mt][nt], 0, 0, 0);
                acc[mt][nt] = __builtin_amdgcn_mfma_f32_16x16x32_bf16(afH[mt], bfL[nt], acc[mt][nt], 0, 0, 0);
                acc[mt][nt] = __builtin_amdgcn_mfma_f32_16x16x32_bf16(afL[mt], bfH[nt], acc[mt][nt], 0, 0, 0);
            }
    }

#pragma unroll
    for (int mt = 0; mt < 4; ++mt) {
        const int gr0 = row0 + wm + mt * 16 + quad * 4;
#pragma unroll
        for (int nt = 0; nt < 4; ++nt) {
            const int gc = col0 + wn + nt * 16 + ln;
            float bb = bias[gc];
#pragma unroll
            for (int r = 0; r < 4; ++r)
                C[(long)(gr0 + r) * ldc + gc] = acc[mt][nt][r] + bb;
        }
    }
}

// ============ wt_fused: 64x64 tiles, W fp16 (both layouts) + partials + vT ============
__global__ __launch_bounds__(256) void wt_fused(const float* __restrict__ qkv,
                                                _Float16* __restrict__ Wh,
                                                _Float16* __restrict__ Wt,
                                                _Float16* __restrict__ vT,
                                                float* __restrict__ rsum,
                                                float* __restrict__ rsq,
                                                float* __restrict__ csum)
{
    __shared__ float qs[32][64];
    __shared__ float ks[32][64];
    __shared__ float colacc[64];
    int z = blockIdx.y;
    int b = z >> 3, h = z & 7;
    int t = threadIdx.x;
    int bx = blockIdx.x;
    long zo = (long)z * Ss * Ss;

    if (bx >= 64) {            // vT pack: half dh (d 32-chunk), all k
        float (*sT)[33] = (float(*)[33])qs;
        int dt = (bx - 64) * 32;
        int d = t & 31, kr = t >> 5;
        for (int kt = 0; kt < Ss; kt += 32) {
            __syncthreads();
#pragma unroll
            for (int p = 0; p < 4; ++p) {
                int kk = kr + p * 8;
                sT[kk][d] = qkv[(long)b * (Ss * 3 * DIM) + (long)(kt + kk) * (3 * DIM) + 2 * DIM + h * HD + dt + d];
            }
            __syncthreads();
#pragma unroll
            for (int p = 0; p < 4; ++p) {
                int dd = kr + p * 8;
                vT[(long)z * (HD * Ss) + (long)(dt + dd) * Ss + kt + d] = (_Float16)sT[d][dd];
            }
        }
        return;
    }

    int ti = bx >> 3, tj = bx & 7;
    int i0 = ti * 64, j0 = tj * 64;

    if (tj > ti) {             // fully-masked: zero only the partial slots
        if (t < 64) {
            rsum[((z * 8 + ti) * 512) + j0 + t] = 0.f;
            rsq [((z * 8 + ti) * 512) + j0 + t] = 0.f;
            csum[((z * 8 + tj) * 512) + i0 + t] = 0.f;
        }
        return;
    }

    int ia = (t & 15) * 4;
    int ja = (t >> 4) * 4;
    const float* qb = qkv + (long)b * Ss * (3 * DIM) + h * HD;
    const float* kb = qb + DIM;
    float acc[4][4] = {};

    for (int d0 = 0; d0 < 64; d0 += 32) {
        __syncthreads();
        int row = t & 63, dg = (t >> 6) * 8;
        float4 qv  = *(const float4*)&qb[(long)(i0 + row) * (3 * DIM) + d0 + dg];
        float4 qv2 = *(const float4*)&qb[(long)(i0 + row) * (3 * DIM) + d0 + dg + 4];
        float4 kv  = *(const float4*)&kb[(long)(j0 + row) * (3 * DIM) + d0 + dg];
        float4 kv2 = *(const float4*)&kb[(long)(j0 + row) * (3 * DIM) + d0 + dg + 4];
        qs[dg+0][row] = qv.x;  qs[dg+1][row] = qv.y;  qs[dg+2][row] = qv.z;  qs[dg+3][row] = qv.w;
        qs[dg+4][row] = qv2.x; qs[dg+5][row] = qv2.y; qs[dg+6][row] = qv2.z; qs[dg+7][row] = qv2.w;
        ks[dg+0][row] = kv.x;  ks[dg+1][row] = kv.y;  ks[dg+2][row] = kv.z;  ks[dg+3][row] = kv.w;
        ks[dg+4][row] = kv2.x; ks[dg+5][row] = kv2.y; ks[dg+6][row] = kv2.z; ks[dg+7][row] = kv2.w;
        __syncthreads();
#pragma unroll
        for (int d = 0; d < 32; ++d) {
            float4 q0 = *(const float4*)&qs[d][ia];
            float4 k0 = *(const float4*)&ks[d][ja];
            float qv_[4] = {q0.x, q0.y, q0.z, q0.w};
            float kv_[4] = {k0.x, k0.y, k0.z, k0.w};
#pragma unroll
            for (int aa = 0; aa < 4; ++aa)
#pragma unroll
                for (int c = 0; c < 4; ++c)
                    acc[aa][c] += fabsf(qv_[aa] - kv_[c]);
        }
    }

#pragma unroll
    for (int aa = 0; aa < 4; ++aa) {
        int i = i0 + ia + aa;
#pragma unroll
        for (int c = 0; c < 4; ++c) {
            int j = j0 + ja + c;
            float e = expf(-acc[aa][c] * 0.25f);
            acc[aa][c] = (j <= i) ? e : 0.0f;
        }
    }
    // Wt rows + per-j partials
#pragma unroll
    for (int c = 0; c < 4; ++c) {
        int j = j0 + ja + c;
        float rs = 0.f, rq = 0.f;
#pragma unroll
        for (int aa = 0; aa < 4; ++aa) { rs += acc[aa][c]; rq += acc[aa][c] * acc[aa][c]; }
        _Float16 ha[4] __attribute__((aligned(8))) = {(_Float16)acc[0][c], (_Float16)acc[1][c], (_Float16)acc[2][c], (_Float16)acc[3][c]};
        *(uint2*)&Wt[zo + (long)j * Ss + i0 + ia] = *(const uint2*)ha;
#pragma unroll
        for (int off = 8; off > 0; off >>= 1) {
            rs += __shfl_down(rs, off, 16);
            rq += __shfl_down(rq, off, 16);
        }
        if ((t & 15) == 0) {
            rsum[((z * 8 + ti) * 512) + j] = rs;
            rsq [((z * 8 + ti) * 512) + j] = rq;
        }
    }
    // Wh rows
#pragma unroll
    for (int aa = 0; aa < 4; ++aa) {
        int i = i0 + ia + aa;
        _Float16 hb[4] __attribute__((aligned(8))) = {(_Float16)acc[aa][0], (_Float16)acc[aa][1], (_Float16)acc[aa][2], (_Float16)acc[aa][3]};
        *(uint2*)&Wh[zo + (long)i * Ss + j0 + ja] = *(const uint2*)hb;
    }
    // per-i partials via LDS
    __syncthreads();
    if (t < 64) colacc[t] = 0.f;
    __syncthreads();
#pragma unroll
    for (int aa = 0; aa < 4; ++aa) {
        float cs = acc[aa][0] + acc[aa][1] + acc[aa][2] + acc[aa][3];
        atomicAdd(&colacc[ia + aa], cs);
    }
    __syncthreads();
    if (t < 64) csum[((z * 8 + tj) * 512) + i0 + t] = colacc[t];
}

// ============ fp16-A wide core: A direct global->VGPR (wave-private rows),
//              B LDS double-buffered (1 barrier / K-step) ============
__device__ __forceinline__ void wk_core(char* smc, const _Float16* A, const _Float16* B,
                                        long zA, long zB, int col0, int kbeg, int kend,
                                        f32x4* acc)
{
    _Float16 (*Bs0)[40] = (_Float16(*)[40])smc;
    _Float16 (*Bs1)[40] = (_Float16(*)[40])(smc + 5120);
    const int t = threadIdx.x;
    const int wave = t >> 6, lane = t & 63;
    const int ln = lane & 15, quad = lane >> 4;
    const int r4 = t >> 2, c4 = (t & 3) * 8;
    const long boff = zB + (long)(col0 + r4) * Ss;
    const _Float16* ap = &A[zA + (long)(wave * 16 + ln) * Ss + quad * 8];

    uint4 ub = *(const uint4*)&B[boff + kbeg + c4];
    f16x8 af = *(const f16x8*)&ap[kbeg];
    *(uint4*)&Bs0[r4][c4] = ub;
    int cur = 0;
    for (int k0 = kbeg; k0 < kend; k0 += 32) {
        int kn = k0 + 32;
        f16x8 afn;
        if (kn < kend) {
            ub  = *(const uint4*)&B[boff + kn + c4];
            afn = *(const f16x8*)&ap[kn];
        }
        __syncthreads();                 // buf[cur] ready
        _Float16 (*Bs)[40] = cur ? Bs1 : Bs0;
#pragma unroll
        for (int nt = 0; nt < 4; ++nt) {
            f16x8 bf = *(const f16x8*)&Bs[nt * 16 + ln][quad * 8];
            acc[nt] = __builtin_amdgcn_mfma_f32_16x16x32_f16(af, bf, acc[nt], 0, 0, 0);
        }
        if (kn < kend) {
            _Float16 (*Bn)[40] = cur ? Bs0 : Bs1;
            *(uint4*)&Bn[r4][c4] = ub;
            af = afn;
        }
        cur ^= 1;
    }
}

// ============ fp32-halves-A wide core: A direct + lane-local convert, B LDS dbuf ============
template<int HASA1>
__device__ __forceinline__ void wk_core32(char* smc, const float* A0, const float* A1,
                                          const _Float16* B, long zA, long zB, int col0,
                                          int kbeg, int kend, f32x4* acc)
{
    _Float16 (*Bs0)[40] = (_Float16(*)[40])smc;
    _Float16 (*Bs1)[40] = (_Float16(*)[40])(smc + 5120);
    const int t = threadIdx.x;
    const int wave = t >> 6, lane = t & 63;
    const int ln = lane & 15, quad = lane >> 4;
    const int r4 = t >> 2, c4 = (t & 3) * 8;
    const long boff = zB + (long)(col0 + r4) * Ss;
    const long aoff = zA + (long)(wave * 16 + ln) * Ss + quad * 8;

    uint4 ub = *(const uint4*)&B[boff + kbeg + c4];
    float4 p0 = *(const float4*)&A0[aoff + kbeg];
    float4 p1 = *(const float4*)&A0[aoff + kbeg + 4];
    float4 q0, q1;
    if constexpr (HASA1) {
        q0 = *(const float4*)&A1[aoff + kbeg];
        q1 = *(const float4*)&A1[aoff + kbeg + 4];
    }
    *(uint4*)&Bs0[r4][c4] = ub;
    int cur = 0;
    for (int k0 = kbeg; k0 < kend; k0 += 32) {
        int kn = k0 + 32;
        float4 p0n, p1n, q0n, q1n;
        if (kn < kend) {
            ub  = *(const uint4*)&B[boff + kn + c4];
            p0n = *(const float4*)&A0[aoff + kn];
            p1n = *(const float4*)&A0[aoff + kn + 4];
            if constexpr (HASA1) {
                q0n = *(const float4*)&A1[aoff + kn];
                q1n = *(const float4*)&A1[aoff + kn + 4];
            }
        }
        _Float16 hv[8] __attribute__((aligned(16)));
        if constexpr (HASA1) {
            hv[0] = (_Float16)(p0.x + q0.x); hv[1] = (_Float16)(p0.y + q0.y);
            hv[2] = (_Float16)(p0.z + q0.z); hv[3] = (_Float16)(p0.w + q0.w);
            hv[4] = (_Float16)(p1.x + q1.x); hv[5] = (_Float16)(p1.y + q1.y);
            hv[6] = (_Float16)(p1.z + q1.z); hv[7] = (_Float16)(p1.w + q1.w);
        } else {
            hv[0] = (_Float16)p0.x; hv[1] = (_Float16)p0.y;
            hv[2] = (_Float16)p0.z; hv[3] = (_Float16)p0.w;
            hv[4] = (_Float16)p1.x; hv[5] = (_Float16)p1.y;
            hv[6] = (_Float16)p1.z; hv[7] = (_Float16)p1.w;
        }
        f16x8 af = *(const f16x8*)hv;
        __syncthreads();
        _Float16 (*Bs)[40] = cur ? Bs1 : Bs0;
#pragma unroll
        for (int nt = 0; nt < 4; ++nt) {
            f16x8 bf = *(const f16x8*)&Bs[nt * 16 + ln][quad * 8];
            acc[nt] = __builtin_amdgcn_mfma_f32_16x16x32_f16(af, bf, acc[nt], 0, 0, 0);
        }
        if (kn < kend) {
            _Float16 (*Bn)[40] = cur ? Bs0 : Bs1;
            *(uint4*)&Bn[r4][c4] = ub;
            p0 = p0n; p1 = p1n;
            if constexpr (HASA1) { q0 = q0n; q1 = q1n; }
        }
        cur ^= 1;
    }
}

// ============ sym_core: 64x64 tile of A @ A^T, A-rows direct, B LDS dbuf ============
__device__ __forceinline__ void sym_core(char* smc, const _Float16* A, long zo,
                                         int row0, int col0, int kend, f32x4* acc)
{
    _Float16 (*Bs0)[40] = (_Float16(*)[40])smc;
    _Float16 (*Bs1)[40] = (_Float16(*)[40])(smc + 5120);
    const int t = threadIdx.x;
    const int wave = t >> 6, lane = t & 63;
    const int ln = lane & 15, quad = lane >> 4;
    const int r4 = t >> 2, c4 = (t & 3) * 8;
    const long boff = zo + (long)(col0 + r4) * Ss;
    const _Float16* ap = &A[zo + (long)(row0 + wave * 16 + ln) * Ss + quad * 8];

    uint4 ub = *(const uint4*)&A[boff + c4];
    f16x8 af = *(const f16x8*)&ap[0];
    *(uint4*)&Bs0[r4][c4] = ub;
    int cur = 0;
    for (int k0 = 0; k0 < kend; k0 += 32) {
        int kn = k0 + 32;
        f16x8 afn;
        if (kn < kend) {
            ub  = *(const uint4*)&A[boff + kn + c4];
            afn = *(const f16x8*)&ap[kn];
        }
        __syncthreads();
        _Float16 (*Bs)[40] = cur ? Bs1 : Bs0;
#pragma unroll
        for (int nt = 0; nt < 4; ++nt) {
            f16x8 bf = *(const f16x8*)&Bs[nt * 16 + ln][quad * 8];
            acc[nt] = __builtin_amdgcn_mfma_f32_16x16x32_f16(af, bf, acc[nt], 0, 0, 0);
        }
        if (kn < kend) {
            _Float16 (*Bn)[40] = cur ? Bs0 : Bs1;
            *(uint4*)&Bn[r4][c4] = ub;
            af = afn;
        }
        cur ^= 1;
    }
}

// ============ mid_k: 0..127 y0 = vT x Wt; 128..143 scal; 144..151 stats; 152..727 U ============
__global__ __launch_bounds__(256) void mid_k(const _Float16* __restrict__ vT,
                                             const _Float16* __restrict__ Wt,
                                             float* __restrict__ y0,
                                             const float* __restrict__ rsum,
                                             const float* __restrict__ rsq,
                                             const float* __restrict__ csum,
                                             float* __restrict__ scal,
                                             float* __restrict__ mu,
                                             float* __restrict__ inv_sig,
                                             const _Float16* __restrict__ Wh,
                                             _Float16* __restrict__ U)
{
    __shared__ __align__(16) char sm[10240];
    int bx = blockIdx.x, t = threadIdx.x;
    if (bx < 128) {
        int z = bx >> 3, cc = bx & 7;
        int col0 = cc * 64;
        long zA = (long)z * (HD * Ss), zB = (long)z * Ss * Ss;
        f32x4 acc[4];
#pragma unroll
        for (int i = 0; i < 4; ++i) acc[i] = (f32x4){0.f, 0.f, 0.f, 0.f};
        wk_core(sm, vT, Wt, zA, zB, col0, col0, Ss, acc);
        const int wave = t >> 6, lane = t & 63;
        const int ln = lane & 15, quad = lane >> 4;
        const int gr = wave * 16 + quad * 4;
#pragma unroll
        for (int nt = 0; nt < 4; ++nt) {
            const int gc = col0 + nt * 16 + ln;
#pragma unroll
            for (int r = 0; r < 4; ++r)
                y0[zA + (long)(gr + r) * Ss + gc] = acc[nt][r];
        }
    } else if (bx < 144) {
        int z = bx - 128;
        float* s1 = (float*)sm;
        float* s2 = s1 + 256;
        float mx1 = 0.f, mx2 = 0.f;
        for (int jj = t; jj < 512; jj += 256) {
            float rs = 0.f, cs = 0.f;
#pragma unroll
            for (int ti = 0; ti < 8; ++ti) {
                rs += rsum[(z * 8 + ti) * 512 + jj];
                cs += csum[(z * 8 + ti) * 512 + jj];
            }
            mx1 = fmaxf(mx1, rs);
            mx2 = fmaxf(mx2, cs);
        }
        s1[t] = mx1; s2[t] = mx2;
        __syncthreads();
        for (int off = 128; off > 0; off >>= 1) {
            if (t < off) {
                s1[t] = fmaxf(s1[t], s1[t + off]);
                s2[t] = fmaxf(s2[t], s2[t + off]);
            }
            __syncthreads();
        }
        if (t == 0) scal[z] = 1.0f / (s1[0] * s2[0]);
    } else if (bx < 152) {
        int h = bx - 144;
        for (int jj = t; jj < 512; jj += 256) {
            float s = 0.f, q = 0.f;
#pragma unroll
            for (int b = 0; b < 2; ++b)
#pragma unroll
                for (int ti = 0; ti < 8; ++ti) {
                    int zz = b * 8 + h;
                    s += rsum[(zz * 8 + ti) * 512 + jj];
                    q += rsq [(zz * 8 + ti) * 512 + jj];
                }
            float m_ = s / 1024.f;
            float var = (q - s * s / 1024.f) / 1023.f;
            inv_sig[h * 512 + jj] = 1.0f / sqrtf(var + 1e-5f);
            mu[h * 512 + jj] = m_;
        }
    } else {
        // U = W @ W^T (unscaled, fp16), 36 lower 64-tiles + mirror per z
        int u = bx - 152;
        int z = u / 36;
        int tile = u - z * 36;
        const long zo = (long)z * Ss * Ss;
        const int ti = d_tIs[tile], tj = d_tJs[tile];
        const int row0 = ti * 64, col0 = tj * 64;
        f32x4 acc[4];
#pragma unroll
        for (int i = 0; i < 4; ++i) acc[i] = (f32x4){0.f, 0.f, 0.f, 0.f};
        sym_core(sm, Wh, zo, row0, col0, col0 + 64, acc);   // K truncated: W lower-tri
        const int wave = t >> 6, lane = t & 63;
        const int ln = lane & 15, quad = lane >> 4;
        const int gr0 = row0 + wave * 16 + quad * 4;
#pragma unroll
        for (int nt = 0; nt < 4; ++nt) {
            const int gc = col0 + nt * 16 + ln;
            _Float16 rb[4] __attribute__((aligned(8)));
#pragma unroll
            for (int r = 0; r < 4; ++r) {
                _Float16 o = (_Float16)acc[nt][r];
                U[zo + (long)(gr0 + r) * Ss + gc] = o;
                rb[r] = o;
            }
            if (ti != tj)
                *(uint2*)&U[zo + (long)gc * Ss + gr0] = *(const uint2*)rb;
        }
    }
}

// ============ sq_k<FIRST>: fused T-squaring + y-update (commuting NS factors) ============
template<int FIRST>
__global__ __launch_bounds__(256) void sq_k(const _Float16* __restrict__ Tc,
                                            _Float16* __restrict__ Tn,
                                            const float* __restrict__ Y0,
                                            const float* __restrict__ Y1,
                                            float* __restrict__ O0,
                                            float* __restrict__ O1,
                                            const float* __restrict__ scal)
{
    __shared__ __align__(16) char sm[10240];
    const int z = blockIdx.y;
    const int t = threadIdx.x;
    const int wave = t >> 6, lane = t & 63;
    const int ln = lane & 15, quad = lane >> 4;

    if (blockIdx.x < 36) {
        const long zo = (long)z * Ss * Ss;
        const int ti = d_tIs[blockIdx.x], tj = d_tJs[blockIdx.x];
        const int row0 = ti * 64, col0 = tj * 64;
        f32x4 acc[4];
#pragma unroll
        for (int i = 0; i < 4; ++i) acc[i] = (f32x4){0.f, 0.f, 0.f, 0.f};
        sym_core(sm, Tc, zo, row0, col0, Ss, acc);
        const float s = FIRST ? scal[z] : 0.f;
        const int gr0 = row0 + wave * 16 + quad * 4;
#pragma unroll
        for (int nt = 0; nt < 4; ++nt) {
            const int gc = col0 + nt * 16 + ln;
            _Float16 rb[4] __attribute__((aligned(8)));
#pragma unroll
            for (int r = 0; r < 4; ++r) {
                const long gi = zo + (long)(gr0 + r) * Ss + gc;
                float val;
                if (FIRST) val = s * s * acc[nt][r] - 2.0f * s * (float)Tc[gi];
                else       val = 2.0f * (float)Tc[gi] + acc[nt][r];
                _Float16 o = (_Float16)val;
                Tn[gi] = o;
                rb[r] = o;
            }
            if (ti != tj)
                *(uint2*)&Tn[zo + (long)gc * Ss + gr0] = *(const uint2*)rb;
        }
    } else {
        const int bx = blockIdx.x - 36;
        const int cc = bx & 7, kh = bx >> 3;
        const int col0 = cc * 64;
        const long zA = (long)z * (HD * Ss);
        const long zB = (long)z * Ss * Ss;
        f32x4 acc[4];
#pragma unroll
        for (int i = 0; i < 4; ++i) acc[i] = (f32x4){0.f, 0.f, 0.f, 0.f};
        wk_core32<FIRST ? 0 : 1>(sm, Y0, Y1, Tc, zA, zB, col0, kh * 256, kh * 256 + 256, acc);
        const float alpha = FIRST ? -scal[z] : 1.0f;
        float* O = kh ? O1 : O0;
        const int gr = wave * 16 + quad * 4;
#pragma unroll
        for (int nt = 0; nt < 4; ++nt) {
            const int gc = col0 + nt * 16 + ln;
#pragma unroll
            for (int r = 0; r < 4; ++r) {
                const long idx = zA + (long)(gr + r) * Ss + gc;
                float val = alpha * acc[nt][r];
                if (kh == 0) {
                    if (FIRST) val += 2.0f * Y0[idx];
                    else       val += 2.0f * (Y0[idx] + Y1[idx]);
                }
                O[idx] = val;
            }
        }
    }
}

// ============ yk_k: y' = 2*y + y x T, split-K=2, fp32 half-buffers ============
__global__ __launch_bounds__(256) void yk_k(const float* __restrict__ A0,
                                            const float* __restrict__ A1,
                                            const _Float16* __restrict__ T,
                                            float* __restrict__ O0,
                                            float* __restrict__ O1)
{
    __shared__ __align__(16) char sm[10240];
    const int z = blockIdx.y;
    const int cc = blockIdx.x & 7, kh = blockIdx.x >> 3;
    const int col0 = cc * 64;
    const long zA = (long)z * (HD * Ss);
    const long zB = (long)z * Ss * Ss;
    const int t = threadIdx.x;
    const int wave = t >> 6, lane = t & 63;
    const int ln = lane & 15, quad = lane >> 4;

    f32x4 acc[4];
#pragma unroll
    for (int i = 0; i < 4; ++i) acc[i] = (f32x4){0.f, 0.f, 0.f, 0.f};
    wk_core32<1>(sm, A0, A1, T, zA, zB, col0, kh * 256, kh * 256 + 256, acc);

    float* O = kh ? O1 : O0;
    const int gr = wave * 16 + quad * 4;
#pragma unroll
    for (int nt = 0; nt < 4; ++nt) {
        const int gc = col0 + nt * 16 + ln;
#pragma unroll
        for (int r = 0; r < 4; ++r) {
            const long idx = zA + (long)(gr + r) * Ss + gc;
            float val = acc[nt][r];
            if (kh == 0) val += 2.0f * (A0[idx] + A1[idx]);
            O[idx] = val;
        }
    }
}

// ============ c2s_k: c2sT = inv_sig[n]*s*(y x Wt) + negoff partials ============
__global__ __launch_bounds__(256) void c2s_k(const float* __restrict__ A0,
                                             const float* __restrict__ A1,
                                             const _Float16* __restrict__ Wt,
                                             _Float16* __restrict__ c2sT,
                                             const float* __restrict__ scal,
                                             const float* __restrict__ inv_sig,
                                             const float* __restrict__ mu,
                                             float* __restrict__ negopart)
{
    __shared__ __align__(16) char sm[10240];
    __shared__ float red[64];
    const int z = blockIdx.y;
    const int h = z & 7;
    const int col0 = blockIdx.x * 64;
    const long zA = (long)z * (HD * Ss);
    const long zB = (long)z * Ss * Ss;
    const int t = threadIdx.x;
    const int wave = t >> 6, lane = t & 63;
    const int ln = lane & 15, quad = lane >> 4;

    f32x4 acc[4];
#pragma unroll
    for (int i = 0; i < 4; ++i) acc[i] = (f32x4){0.f, 0.f, 0.f, 0.f};
    wk_core32<1>(sm, A0, A1, Wt, zA, zB, col0, col0, Ss, acc);

    if (t < 64) red[t] = 0.f;
    __syncthreads();
    const int gr = wave * 16 + quad * 4;
    float pr[4] = {0.f, 0.f, 0.f, 0.f};
    float s = scal[z];
#pragma unroll
    for (int nt = 0; nt < 4; ++nt) {
        const int gc = col0 + nt * 16 + ln;
#pragma unroll
        for (int r = 0; r < 4; ++r) {
            float val = inv_sig[h * 512 + gc] * (s * acc[nt][r]);
            pr[r] += mu[h * 512 + gc] * val;
            c2sT[zA + (long)(gr + r) * Ss + gc] = (_Float16)val;
        }
    }
#pragma unroll
    for (int r = 0; r < 4; ++r)
        atomicAdd(&red[gr + r], pr[r]);
    __syncthreads();
    if (t < 64)
        negopart[(z * 8 + blockIdx.x) * 64 + t] = red[t];
}

// ============ ga_k: gat = Wh @ c2s - neg, fp32 out in [B,S,DIM] ============
__global__ __launch_bounds__(256) void ga_k(const _Float16* __restrict__ Wh,
                                            const _Float16* __restrict__ c2sT,
                                            const float* __restrict__ negopart,
                                            float* __restrict__ gat)
{
    __shared__ __align__(16) char sm[10240];
    __shared__ float neg[64];
    const int z = blockIdx.y;
    const int b = z >> 3, h = z & 7;
    const int m0 = blockIdx.x * 64;
    const long zA = (long)z * Ss * Ss;
    const long zB = (long)z * (HD * Ss);
    const int t = threadIdx.x;
    const int wave = t >> 6, lane = t & 63;
    const int ln = lane & 15, quad = lane >> 4;

    if (t < 64) {
        float s = 0.f;
#pragma unroll
        for (int k = 0; k < 8; ++k) s += negopart[(z * 8 + k) * 64 + t];
        neg[t] = s;
    }
    __syncthreads();

    f32x4 acc[4];
#pragma unroll
    for (int i = 0; i < 4; ++i) acc[i] = (f32x4){0.f, 0.f, 0.f, 0.f};
    wk_core(sm, c2sT, Wh, zB, zA, m0, 0, m0 + 64, acc);

    const int gr = wave * 16 + quad * 4;   // d index
#pragma unroll
    for (int nt = 0; nt < 4; ++nt) {
        const int m = m0 + nt * 16 + ln;
#pragma unroll
        for (int r = 0; r < 4; ++r) {
            const int d = gr + r;
            gat[(long)b * (Ss * DIM) + (long)m * DIM + h * HD + d] = acc[nt][r] - neg[d];
        }
    }
}

extern "C" void kernel_launch(void* const* d_in, const int* in_sizes, int n_in,
                              void* d_out, int out_size, void* d_ws, size_t ws_size,
                              hipStream_t stream)
{
    const float* x      = (const float*)d_in[0];
    const float* qkv_w  = (const float*)d_in[1];
    const float* qkv_b  = (const float*)d_in[2];
    const float* proj_w = (const float*)d_in[3];
    const float* proj_b = (const float*)d_in[4];
    float* out = (float*)d_out;
    float* ws  = (float*)d_ws;

    float* qkv     = ws;
    _Float16* Wh   = (_Float16*)(ws + 1572864);
    _Float16* Wt   = (_Float16*)(ws + 3670016);
    _Float16* vT   = (_Float16*)(ws + 5767168);
    _Float16* T[5];
    for (int i = 0; i < 5; ++i) T[i] = (_Float16*)(ws + 6029312 + (long)i * 2097152);
    float* Ya0 = ws + 16515072;   // fp32 y half-buffers, 524288 f each
    float* Ya1 = ws + 17039360;
    float* Yb0 = ws + 17563648;
    float* Yb1 = ws + 18087936;
    _Float16* c2sT = (_Float16*)(ws + 19136512);
    float* rsum    = ws + 19398656;   // 65536
    float* rsq     = ws + 19464192;   // 65536
    float* csum    = ws + 19529728;   // 65536
    float* scal    = ws + 19595264;   // 16
    float* mu      = ws + 19595280;   // 4096
    float* inv_sig = ws + 19599376;   // 4096
    float* negp    = ws + 19603472;   // 8192
    float* gat     = ws + 19611664;   // 524288

    dim3 blk(256);

    // 1. qkv = x @ qkv_w^T + qkv_b
    mm_k<<<dim3(12, 8), blk, 0, stream>>>(x, qkv_w, qkv_b, qkv, DIM, 3 * DIM);

    // 2. W fp16 (both layouts, 64-tiles) + reduction partials + vT
    wt_fused<<<dim3(66, 16), blk, 0, stream>>>(qkv, Wh, Wt, vT, rsum, rsq, csum);

    // 3. y0 = vT x Wt || scale || whitening stats || U = W W^T (unscaled)
    mid_k<<<dim3(728), blk, 0, stream>>>(vT, Wt, Ya0, rsum, rsq, csum, scal, mu, inv_sig,
                                         Wh, T[0]);

    // 4-7. fused NS steps (ascending k; factors commute):
    //      T1 = s^2 U U - 2 s U   || y1 = 2 y0 - s y0 U
    //      T_{k+1} = 2 T_k + T_k^2 || y_{k+1} = 2 y_k + y_k T_k
    sq_k<1><<<dim3(52, 16), blk, 0, stream>>>(T[0], T[1], Ya0, nullptr, Yb0, Yb1, scal);
    sq_k<0><<<dim3(52, 16), blk, 0, stream>>>(T[1], T[2], Yb0, Yb1,     Ya0, Ya1, scal);
    sq_k<0><<<dim3(52, 16), blk, 0, stream>>>(T[2], T[3], Ya0, Ya1,     Yb0, Yb1, scal);
    sq_k<0><<<dim3(52, 16), blk, 0, stream>>>(T[3], T[4], Yb0, Yb1,     Ya0, Ya1, scal);

    // 8. final y update with T4
    yk_k<<<dim3(16, 16), blk, 0, stream>>>(Ya0, Ya1, T[4], Yb0, Yb1);

    // 9. c2sT = inv_sig * s * (y W) + negoff partials
    c2s_k<<<dim3(8, 16), blk, 0, stream>>>(Yb0, Yb1, Wt, c2sT, scal, inv_sig, mu, negp);

    // 10. gat = W @ c2s - neg
    ga_k<<<dim3(8, 16), blk, 0, stream>>>(Wh, c2sT, negp, gat);

    // 11. out = gat @ proj_w^T + proj_b
    mm_k<<<dim3(4, 8), blk, 0, stream>>>(gat, proj_w, proj_b, out, DIM, DIM);
}

// Round 8
// 270.677 us; speedup vs baseline: 1.0892x; 1.0892x over previous
//
#include <hip/hip_runtime.h>

#define Bq 2
#define Hh 8
#define Ss 512
#define HD 64
#define DIM 512

using f32x4   = __attribute__((ext_vector_type(4))) float;
using bf16x8s = __attribute__((ext_vector_type(8))) short;
typedef _Float16 f16x8 __attribute__((ext_vector_type(8)));

__constant__ int d_tIs[36] = {0,1,1,2,2,2,3,3,3,3,4,4,4,4,4,5,5,5,5,5,5,6,6,6,6,6,6,6,7,7,7,7,7,7,7,7};
__constant__ int d_tJs[36] = {0,0,1,0,1,2,0,1,2,3,0,1,2,3,4,0,1,2,3,4,5,0,1,2,3,4,5,6,0,1,2,3,4,5,6,7};

__device__ __forceinline__ float bf2f(unsigned short u) {
    return __uint_as_float(((unsigned int)u) << 16);
}
__device__ __forceinline__ unsigned short f2bf(float f) {
    unsigned int u = __float_as_uint(f);
    u = (u + 0x7FFFu + ((u >> 16) & 1u)) >> 16;   // RNE
    return (unsigned short)u;
}

// ============ mm_k: C = A @ B^T + bias (fp32 io, split bf16x2 MFMA, 128x128) ============
__global__ __launch_bounds__(256) void mm_k(
    const float* __restrict__ A, const float* __restrict__ B,
    const float* __restrict__ bias, float* __restrict__ C,
    int K, int ldc)
{
    const int row0 = blockIdx.y * 128, col0 = blockIdx.x * 128;
    __shared__ unsigned short AsH[128][40], AsL[128][40];
    __shared__ unsigned short BsH[128][40], BsL[128][40];
    const int t = threadIdx.x;
    const int wave = t >> 6, lane = t & 63;
    const int ln = lane & 15, quad = lane >> 4;
    const int wm = (wave & 1) * 64, wn = (wave >> 1) * 64;

    f32x4 acc[4][4];
#pragma unroll
    for (int i = 0; i < 4; ++i)
#pragma unroll
        for (int j = 0; j < 4; ++j)
            acc[i][j] = (f32x4){0.f, 0.f, 0.f, 0.f};

    const int sr = t >> 2, sg = (t & 3) * 8;

    for (int k0 = 0; k0 < K; k0 += 32) {
        __syncthreads();
#pragma unroll
        for (int half = 0; half < 4; ++half) {
            const float* src = (half < 2) ? A : B;
            int base = (half < 2) ? row0 : col0;
            int row = sr + ((half & 1) ? 64 : 0);
            const float* p = &src[(long)(base + row) * K + k0 + sg];
            float4 f0 = *(const float4*)p;
            float4 f1 = *(const float4*)(p + 4);
            float fv[8] = {f0.x, f0.y, f0.z, f0.w, f1.x, f1.y, f1.z, f1.w};
            unsigned short hv[8], lv[8];
#pragma unroll
            for (int e = 0; e < 8; ++e) {
                hv[e] = f2bf(fv[e]);
                lv[e] = f2bf(fv[e] - bf2f(hv[e]));
            }
            uint4 H, L;
            H.x = hv[0] | (hv[1] << 16); H.y = hv[2] | (hv[3] << 16);
            H.z = hv[4] | (hv[5] << 16); H.w = hv[6] | (hv[7] << 16);
            L.x = lv[0] | (lv[1] << 16); L.y = lv[2] | (lv[3] << 16);
            L.z = lv[4] | (lv[5] << 16); L.w = lv[6] | (lv[7] << 16);
            if (half < 2) { *(uint4*)&AsH[row][sg] = H; *(uint4*)&AsL[row][sg] = L; }
            else          { *(uint4*)&BsH[row][sg] = H; *(uint4*)&BsL[row][sg] = L; }
        }
        __syncthreads();

        bf16x8s afH[4], afL[4], bfH[4], bfL[4];
#pragma unroll
        for (int mt = 0; mt < 4; ++mt) {
            afH[mt] = *(const bf16x8s*)&AsH[wm + mt * 16 + ln][quad * 8];
            afL[mt] = *(const bf16x8s*)&AsL[wm + mt * 16 + ln][quad * 8];
        }
#pragma unroll
        for (int nt = 0; nt < 4; ++nt) {
            bfH[nt] = *(const bf16x8s*)&BsH[wn + nt * 16 + ln][quad * 8];
            bfL[nt] = *(const bf16x8s*)&BsL[wn + nt * 16 + ln][quad * 8];
        }
#pragma unroll
        for (int mt = 0; mt < 4; ++mt)
#pragma unroll
            for (int nt = 0; nt < 4; ++nt) {
                acc[mt][nt] = __builtin_amdgcn_mfma_f32_16x16x32_bf16(afH[mt], bfH[nt], acc[mt][nt], 0, 0, 0);
                acc[mt][nt] = __builtin_amdgcn_mfma_f32_16x16x32_bf16(afH[mt], bfL[nt], acc[mt][nt], 0, 0, 0);
                acc[mt][nt] = __builtin_amdgcn_mfma_f32_16x16x32_bf16(afL[mt], bfH[nt], acc[mt][nt], 0, 0, 0);
            }
    }

#pragma unroll
    for (int mt = 0; mt < 4; ++mt) {
        const int gr0 = row0 + wm + mt * 16 + quad * 4;
#pragma unroll
        for (int nt = 0; nt < 4; ++nt) {
            const int gc = col0 + wn + nt * 16 + ln;
            float bb = bias[gc];
#pragma unroll
            for (int r = 0; r < 4; ++r)
                C[(long)(gr0 + r) * ldc + gc] = acc[mt][nt][r] + bb;
        }
    }
}

// ============ wt_fused: 64x64 tiles, W fp16 (both layouts) + partials + vT ============
__global__ __launch_bounds__(256) void wt_fused(const float* __restrict__ qkv,
                                                _Float16* __restrict__ Wh,
                                                _Float16* __restrict__ Wt,
                                                _Float16* __restrict__ vT,
                                                float* __restrict__ rsum,
                                                float* __restrict__ rsq,
                                                float* __restrict__ csum)
{
    __shared__ float qs[32][64];
    __shared__ float ks[32][64];
    __shared__ float colacc[64];
    int z = blockIdx.y;
    int b = z >> 3, h = z & 7;
    int t = threadIdx.x;
    int bx = blockIdx.x;
    long zo = (long)z * Ss * Ss;

    if (bx >= 64) {            // vT pack: half dh (d 32-chunk), all k
        float (*sT)[33] = (float(*)[33])qs;
        int dt = (bx - 64) * 32;
        int d = t & 31, kr = t >> 5;
        for (int kt = 0; kt < Ss; kt += 32) {
            __syncthreads();
#pragma unroll
            for (int p = 0; p < 4; ++p) {
                int kk = kr + p * 8;
                sT[kk][d] = qkv[(long)b * (Ss * 3 * DIM) + (long)(kt + kk) * (3 * DIM) + 2 * DIM + h * HD + dt + d];
            }
            __syncthreads();
#pragma unroll
            for (int p = 0; p < 4; ++p) {
                int dd = kr + p * 8;
                vT[(long)z * (HD * Ss) + (long)(dt + dd) * Ss + kt + d] = (_Float16)sT[d][dd];
            }
        }
        return;
    }

    int ti = bx >> 3, tj = bx & 7;
    int i0 = ti * 64, j0 = tj * 64;

    if (tj > ti) {             // fully-masked: zero only the partial slots
        if (t < 64) {
            rsum[((z * 8 + ti) * 512) + j0 + t] = 0.f;
            rsq [((z * 8 + ti) * 512) + j0 + t] = 0.f;
            csum[((z * 8 + tj) * 512) + i0 + t] = 0.f;
        }
        return;
    }

    int ia = (t & 15) * 4;
    int ja = (t >> 4) * 4;
    const float* qb = qkv + (long)b * Ss * (3 * DIM) + h * HD;
    const float* kb = qb + DIM;
    float acc[4][4] = {};

    for (int d0 = 0; d0 < 64; d0 += 32) {
        __syncthreads();
        int row = t & 63, dg = (t >> 6) * 8;
        float4 qv  = *(const float4*)&qb[(long)(i0 + row) * (3 * DIM) + d0 + dg];
        float4 qv2 = *(const float4*)&qb[(long)(i0 + row) * (3 * DIM) + d0 + dg + 4];
        float4 kv  = *(const float4*)&kb[(long)(j0 + row) * (3 * DIM) + d0 + dg];
        float4 kv2 = *(const float4*)&kb[(long)(j0 + row) * (3 * DIM) + d0 + dg + 4];
        qs[dg+0][row] = qv.x;  qs[dg+1][row] = qv.y;  qs[dg+2][row] = qv.z;  qs[dg+3][row] = qv.w;
        qs[dg+4][row] = qv2.x; qs[dg+5][row] = qv2.y; qs[dg+6][row] = qv2.z; qs[dg+7][row] = qv2.w;
        ks[dg+0][row] = kv.x;  ks[dg+1][row] = kv.y;  ks[dg+2][row] = kv.z;  ks[dg+3][row] = kv.w;
        ks[dg+4][row] = kv2.x; ks[dg+5][row] = kv2.y; ks[dg+6][row] = kv2.z; ks[dg+7][row] = kv2.w;
        __syncthreads();
#pragma unroll
        for (int d = 0; d < 32; ++d) {
            float4 q0 = *(const float4*)&qs[d][ia];
            float4 k0 = *(const float4*)&ks[d][ja];
            float qv_[4] = {q0.x, q0.y, q0.z, q0.w};
            float kv_[4] = {k0.x, k0.y, k0.z, k0.w};
#pragma unroll
            for (int aa = 0; aa < 4; ++aa)
#pragma unroll
                for (int c = 0; c < 4; ++c)
                    acc[aa][c] += fabsf(qv_[aa] - kv_[c]);
        }
    }

#pragma unroll
    for (int aa = 0; aa < 4; ++aa) {
        int i = i0 + ia + aa;
#pragma unroll
        for (int c = 0; c < 4; ++c) {
            int j = j0 + ja + c;
            float e = expf(-acc[aa][c] * 0.25f);
            acc[aa][c] = (j <= i) ? e : 0.0f;
        }
    }
    // Wt rows + per-j partials
#pragma unroll
    for (int c = 0; c < 4; ++c) {
        int j = j0 + ja + c;
        float rs = 0.f, rq = 0.f;
#pragma unroll
        for (int aa = 0; aa < 4; ++aa) { rs += acc[aa][c]; rq += acc[aa][c] * acc[aa][c]; }
        _Float16 ha[4] __attribute__((aligned(8))) = {(_Float16)acc[0][c], (_Float16)acc[1][c], (_Float16)acc[2][c], (_Float16)acc[3][c]};
        *(uint2*)&Wt[zo + (long)j * Ss + i0 + ia] = *(const uint2*)ha;
#pragma unroll
        for (int off = 8; off > 0; off >>= 1) {
            rs += __shfl_down(rs, off, 16);
            rq += __shfl_down(rq, off, 16);
        }
        if ((t & 15) == 0) {
            rsum[((z * 8 + ti) * 512) + j] = rs;
            rsq [((z * 8 + ti) * 512) + j] = rq;
        }
    }
    // Wh rows
#pragma unroll
    for (int aa = 0; aa < 4; ++aa) {
        int i = i0 + ia + aa;
        _Float16 hb[4] __attribute__((aligned(8))) = {(_Float16)acc[aa][0], (_Float16)acc[aa][1], (_Float16)acc[aa][2], (_Float16)acc[aa][3]};
        *(uint2*)&Wh[zo + (long)i * Ss + j0 + ja] = *(const uint2*)hb;
    }
    // per-i partials via LDS
    __syncthreads();
    if (t < 64) colacc[t] = 0.f;
    __syncthreads();
#pragma unroll
    for (int aa = 0; aa < 4; ++aa) {
        float cs = acc[aa][0] + acc[aa][1] + acc[aa][2] + acc[aa][3];
        atomicAdd(&colacc[ia + aa], cs);
    }
    __syncthreads();
    if (t < 64) csum[((z * 8 + tj) * 512) + i0 + t] = colacc[t];
}

// ============ fp16-A wide core, LDS double-buffered (1 barrier / K-step) ============
__device__ __forceinline__ void wk_core(char* smc, const _Float16* A, const _Float16* B,
                                        long zA, long zB, int col0, int kbeg, int kend,
                                        f32x4* acc)
{
    _Float16 (*As0)[40] = (_Float16(*)[40])smc;
    _Float16 (*Bs0)[40] = (_Float16(*)[40])(smc + 5120);
    _Float16 (*As1)[40] = (_Float16(*)[40])(smc + 10240);
    _Float16 (*Bs1)[40] = (_Float16(*)[40])(smc + 15360);
    const int t = threadIdx.x;
    const int wave = t >> 6, lane = t & 63;
    const int ln = lane & 15, quad = lane >> 4;
    const int r4 = t >> 2, c4 = (t & 3) * 8;
    const long aoff = zA + (long)r4 * Ss;
    const long boff = zB + (long)(col0 + r4) * Ss;

    uint4 ua = *(const uint4*)&A[aoff + kbeg + c4];
    uint4 ub = *(const uint4*)&B[boff + kbeg + c4];
    *(uint4*)&As0[r4][c4] = ua;
    *(uint4*)&Bs0[r4][c4] = ub;
    int cur = 0;
    for (int k0 = kbeg; k0 < kend; k0 += 32) {
        int kn = k0 + 32;
        if (kn < kend) {
            ua = *(const uint4*)&A[aoff + kn + c4];
            ub = *(const uint4*)&B[boff + kn + c4];
        }
        __syncthreads();                 // buf[cur] complete (prev writes drained)
        _Float16 (*As)[40] = cur ? As1 : As0;
        _Float16 (*Bs)[40] = cur ? Bs1 : Bs0;
        f16x8 af = *(const f16x8*)&As[wave * 16 + ln][quad * 8];
#pragma unroll
        for (int nt = 0; nt < 4; ++nt) {
            f16x8 bf = *(const f16x8*)&Bs[nt * 16 + ln][quad * 8];
            acc[nt] = __builtin_amdgcn_mfma_f32_16x16x32_f16(af, bf, acc[nt], 0, 0, 0);
        }
        if (kn < kend) {
            _Float16 (*An)[40] = cur ? As0 : As1;
            _Float16 (*Bn)[40] = cur ? Bs0 : Bs1;
            *(uint4*)&An[r4][c4] = ua;
            *(uint4*)&Bn[r4][c4] = ub;
        }
        cur ^= 1;
    }
}

// ============ fp32-halves-A wide core, double-buffered ============
template<int HASA1>
__device__ __forceinline__ void wk_core32(char* smc, const float* A0, const float* A1,
                                          const _Float16* B, long zA, long zB, int col0,
                                          int kbeg, int kend, f32x4* acc)
{
    _Float16 (*As0)[40] = (_Float16(*)[40])smc;
    _Float16 (*Bs0)[40] = (_Float16(*)[40])(smc + 5120);
    _Float16 (*As1)[40] = (_Float16(*)[40])(smc + 10240);
    _Float16 (*Bs1)[40] = (_Float16(*)[40])(smc + 15360);
    const int t = threadIdx.x;
    const int wave = t >> 6, lane = t & 63;
    const int ln = lane & 15, quad = lane >> 4;
    const int r4 = t >> 2, c4 = (t & 3) * 8;
    const long aoff = zA + (long)r4 * Ss;
    const long boff = zB + (long)(col0 + r4) * Ss;

    float4 p0 = *(const float4*)&A0[aoff + kbeg + c4];
    float4 p1 = *(const float4*)&A0[aoff + kbeg + c4 + 4];
    float4 q0, q1;
    if constexpr (HASA1) {
        q0 = *(const float4*)&A1[aoff + kbeg + c4];
        q1 = *(const float4*)&A1[aoff + kbeg + c4 + 4];
    }
    uint4 ub = *(const uint4*)&B[boff + kbeg + c4];
    {
        _Float16 hv[8] __attribute__((aligned(16)));
        if constexpr (HASA1) {
            hv[0] = (_Float16)(p0.x + q0.x); hv[1] = (_Float16)(p0.y + q0.y);
            hv[2] = (_Float16)(p0.z + q0.z); hv[3] = (_Float16)(p0.w + q0.w);
            hv[4] = (_Float16)(p1.x + q1.x); hv[5] = (_Float16)(p1.y + q1.y);
            hv[6] = (_Float16)(p1.z + q1.z); hv[7] = (_Float16)(p1.w + q1.w);
        } else {
            hv[0] = (_Float16)p0.x; hv[1] = (_Float16)p0.y;
            hv[2] = (_Float16)p0.z; hv[3] = (_Float16)p0.w;
            hv[4] = (_Float16)p1.x; hv[5] = (_Float16)p1.y;
            hv[6] = (_Float16)p1.z; hv[7] = (_Float16)p1.w;
        }
        *(uint4*)&As0[r4][c4] = *(const uint4*)hv;
        *(uint4*)&Bs0[r4][c4] = ub;
    }
    int cur = 0;
    for (int k0 = kbeg; k0 < kend; k0 += 32) {
        int kn = k0 + 32;
        if (kn < kend) {
            p0 = *(const float4*)&A0[aoff + kn + c4];
            p1 = *(const float4*)&A0[aoff + kn + c4 + 4];
            if constexpr (HASA1) {
                q0 = *(const float4*)&A1[aoff + kn + c4];
                q1 = *(const float4*)&A1[aoff + kn + c4 + 4];
            }
            ub = *(const uint4*)&B[boff + kn + c4];
        }
        __syncthreads();
        _Float16 (*As)[40] = cur ? As1 : As0;
        _Float16 (*Bs)[40] = cur ? Bs1 : Bs0;
        f16x8 af = *(const f16x8*)&As[wave * 16 + ln][quad * 8];
#pragma unroll
        for (int nt = 0; nt < 4; ++nt) {
            f16x8 bf = *(const f16x8*)&Bs[nt * 16 + ln][quad * 8];
            acc[nt] = __builtin_amdgcn_mfma_f32_16x16x32_f16(af, bf, acc[nt], 0, 0, 0);
        }
        if (kn < kend) {
            _Float16 hv[8] __attribute__((aligned(16)));
            if constexpr (HASA1) {
                hv[0] = (_Float16)(p0.x + q0.x); hv[1] = (_Float16)(p0.y + q0.y);
                hv[2] = (_Float16)(p0.z + q0.z); hv[3] = (_Float16)(p0.w + q0.w);
                hv[4] = (_Float16)(p1.x + q1.x); hv[5] = (_Float16)(p1.y + q1.y);
                hv[6] = (_Float16)(p1.z + q1.z); hv[7] = (_Float16)(p1.w + q1.w);
            } else {
                hv[0] = (_Float16)p0.x; hv[1] = (_Float16)p0.y;
                hv[2] = (_Float16)p0.z; hv[3] = (_Float16)p0.w;
                hv[4] = (_Float16)p1.x; hv[5] = (_Float16)p1.y;
                hv[6] = (_Float16)p1.z; hv[7] = (_Float16)p1.w;
            }
            _Float16 (*An)[40] = cur ? As0 : As1;
            _Float16 (*Bn)[40] = cur ? Bs0 : Bs1;
            *(uint4*)&An[r4][c4] = *(const uint4*)hv;
            *(uint4*)&Bn[r4][c4] = ub;
        }
        cur ^= 1;
    }
}

// ============ sym_core: 64x64 tile of A @ A^T over k < kend, double-buffered ============
__device__ __forceinline__ void sym_core(char* smc, const _Float16* A, long zo,
                                         int row0, int col0, int kend, f32x4* acc)
{
    _Float16 (*As0)[40] = (_Float16(*)[40])smc;
    _Float16 (*Bs0)[40] = (_Float16(*)[40])(smc + 5120);
    _Float16 (*As1)[40] = (_Float16(*)[40])(smc + 10240);
    _Float16 (*Bs1)[40] = (_Float16(*)[40])(smc + 15360);
    const int t = threadIdx.x;
    const int wave = t >> 6, lane = t & 63;
    const int ln = lane & 15, quad = lane >> 4;
    const int r4 = t >> 2, c4 = (t & 3) * 8;
    const long aoff = zo + (long)(row0 + r4) * Ss;
    const long boff = zo + (long)(col0 + r4) * Ss;
    uint4 ua = *(const uint4*)&A[aoff + c4];
    uint4 ub = *(const uint4*)&A[boff + c4];
    *(uint4*)&As0[r4][c4] = ua;
    *(uint4*)&Bs0[r4][c4] = ub;
    int cur = 0;
    for (int k0 = 0; k0 < kend; k0 += 32) {
        int kn = k0 + 32;
        if (kn < kend) {
            ua = *(const uint4*)&A[aoff + kn + c4];
            ub = *(const uint4*)&A[boff + kn + c4];
        }
        __syncthreads();
        _Float16 (*As)[40] = cur ? As1 : As0;
        _Float16 (*Bs)[40] = cur ? Bs1 : Bs0;
        f16x8 af = *(const f16x8*)&As[wave * 16 + ln][quad * 8];
#pragma unroll
        for (int nt = 0; nt < 4; ++nt) {
            f16x8 bf = *(const f16x8*)&Bs[nt * 16 + ln][quad * 8];
            acc[nt] = __builtin_amdgcn_mfma_f32_16x16x32_f16(af, bf, acc[nt], 0, 0, 0);
        }
        if (kn < kend) {
            _Float16 (*An)[40] = cur ? As0 : As1;
            _Float16 (*Bn)[40] = cur ? Bs0 : Bs1;
            *(uint4*)&An[r4][c4] = ua;
            *(uint4*)&Bn[r4][c4] = ub;
        }
        cur ^= 1;
    }
}

// ============ sym_epilogue: coalesced dual-layout store of a 64x64 fp16 tile ============
// ov[nt][r] holds the tile fragment values. Stages row-order and transposed copies in
// LDS (stride 72 halfs: 16B-aligned rows, spread banks), then writes both the direct
// rows [row0..][col0..] and the mirror rows [col0..][row0..] as uint4 row stores.
__device__ __forceinline__ void sym_store_offdiag(char* smc, _Float16* T, long zo,
                                                  int row0, int col0,
                                                  const _Float16 (*ov)[4])
{
    _Float16 (*ltR)[72] = (_Float16(*)[72])smc;            // 64x72x2 = 9216 B
    _Float16 (*ltT)[72] = (_Float16(*)[72])(smc + 9216);   // 9216 B (total 18432 <= 20480)
    const int t = threadIdx.x;
    const int wave = t >> 6, lane = t & 63;
    const int ln = lane & 15, quad = lane >> 4;
    const int lr0 = wave * 16 + quad * 4;
    __syncthreads();                       // sym_core LDS reads complete
#pragma unroll
    for (int nt = 0; nt < 4; ++nt) {
        const int lc = nt * 16 + ln;
        *(uint2*)&ltT[lc][lr0] = *(const uint2*)ov[nt];
#pragma unroll
        for (int r = 0; r < 4; ++r)
            ltR[lr0 + r][lc] = ov[nt][r];
    }
    __syncthreads();
    const int tr = t >> 2, tcg = (t & 3) * 16;
    uint4 a0 = *(const uint4*)&ltR[tr][tcg];
    uint4 a1 = *(const uint4*)&ltR[tr][tcg + 8];
    _Float16* d0 = &T[zo + (long)(row0 + tr) * Ss + col0 + tcg];
    *(uint4*)&d0[0] = a0;
    *(uint4*)&d0[8] = a1;
    uint4 b0 = *(const uint4*)&ltT[tr][tcg];
    uint4 b1 = *(const uint4*)&ltT[tr][tcg + 8];
    _Float16* d1 = &T[zo + (long)(col0 + tr) * Ss + row0 + tcg];
    *(uint4*)&d1[0] = b0;
    *(uint4*)&d1[8] = b1;
}

// ============ mid_k: 0..127 y0 = vT x Wt; 128..143 scal; 144..151 stats; 152..727 U ============
__global__ __launch_bounds__(256) void mid_k(const _Float16* __restrict__ vT,
                                             const _Float16* __restrict__ Wt,
                                             float* __restrict__ y0,
                                             const float* __restrict__ rsum,
                                             const float* __restrict__ rsq,
                                             const float* __restrict__ csum,
                                             float* __restrict__ scal,
                                             float* __restrict__ mu,
                                             float* __restrict__ inv_sig,
                                             const _Float16* __restrict__ Wh,
                                             _Float16* __restrict__ U)
{
    __shared__ __align__(16) char sm[20480];
    int bx = blockIdx.x, t = threadIdx.x;
    if (bx < 128) {
        int z = bx >> 3, cc = bx & 7;
        int col0 = cc * 64;
        long zA = (long)z * (HD * Ss), zB = (long)z * Ss * Ss;
        f32x4 acc[4];
#pragma unroll
        for (int i = 0; i < 4; ++i) acc[i] = (f32x4){0.f, 0.f, 0.f, 0.f};
        wk_core(sm, vT, Wt, zA, zB, col0, col0, Ss, acc);
        const int wave = t >> 6, lane = t & 63;
        const int ln = lane & 15, quad = lane >> 4;
        const int gr = wave * 16 + quad * 4;
#pragma unroll
        for (int nt = 0; nt < 4; ++nt) {
            const int gc = col0 + nt * 16 + ln;
#pragma unroll
            for (int r = 0; r < 4; ++r)
                y0[zA + (long)(gr + r) * Ss + gc] = acc[nt][r];
        }
    } else if (bx < 144) {
        int z = bx - 128;
        float* s1 = (float*)sm;
        float* s2 = s1 + 256;
        float mx1 = 0.f, mx2 = 0.f;
        for (int jj = t; jj < 512; jj += 256) {
            float rs = 0.f, cs = 0.f;
#pragma unroll
            for (int ti = 0; ti < 8; ++ti) {
                rs += rsum[(z * 8 + ti) * 512 + jj];
                cs += csum[(z * 8 + ti) * 512 + jj];
            }
            mx1 = fmaxf(mx1, rs);
            mx2 = fmaxf(mx2, cs);
        }
        s1[t] = mx1; s2[t] = mx2;
        __syncthreads();
        for (int off = 128; off > 0; off >>= 1) {
            if (t < off) {
                s1[t] = fmaxf(s1[t], s1[t + off]);
                s2[t] = fmaxf(s2[t], s2[t + off]);
            }
            __syncthreads();
        }
        if (t == 0) scal[z] = 1.0f / (s1[0] * s2[0]);
    } else if (bx < 152) {
        int h = bx - 144;
        for (int jj = t; jj < 512; jj += 256) {
            float s = 0.f, q = 0.f;
#pragma unroll
            for (int b = 0; b < 2; ++b)
#pragma unroll
                for (int ti = 0; ti < 8; ++ti) {
                    int zz = b * 8 + h;
                    s += rsum[(zz * 8 + ti) * 512 + jj];
                    q += rsq [(zz * 8 + ti) * 512 + jj];
                }
            float m_ = s / 1024.f;
            float var = (q - s * s / 1024.f) / 1023.f;
            inv_sig[h * 512 + jj] = 1.0f / sqrtf(var + 1e-5f);
            mu[h * 512 + jj] = m_;
        }
    } else {
        // U = W @ W^T (unscaled, fp16), 36 lower 64-tiles + mirror per z
        int u = bx - 152;
        int z = u / 36;
        int tile = u - z * 36;
        const long zo = (long)z * Ss * Ss;
        const int ti = d_tIs[tile], tj = d_tJs[tile];
        const int row0 = ti * 64, col0 = tj * 64;
        f32x4 acc[4];
#pragma unroll
        for (int i = 0; i < 4; ++i) acc[i] = (f32x4){0.f, 0.f, 0.f, 0.f};
        sym_core(sm, Wh, zo, row0, col0, col0 + 64, acc);   // K truncated: W lower-tri
        const int wave = t >> 6, lane = t & 63;
        const int ln = lane & 15, quad = lane >> 4;
        _Float16 ov[4][4] __attribute__((aligned(8)));
#pragma unroll
        for (int nt = 0; nt < 4; ++nt)
#pragma unroll
            for (int r = 0; r < 4; ++r)
                ov[nt][r] = (_Float16)acc[nt][r];
        if (ti == tj) {
            const int gr0 = row0 + wave * 16 + quad * 4;
#pragma unroll
            for (int nt = 0; nt < 4; ++nt) {
                const int gc = col0 + nt * 16 + ln;
#pragma unroll
                for (int r = 0; r < 4; ++r)
                    U[zo + (long)(gr0 + r) * Ss + gc] = ov[nt][r];
            }
        } else {
            sym_store_offdiag(sm, U, zo, row0, col0, ov);
        }
    }
}

// ============ sq_k<FIRST>: fused T-squaring + y-update (commuting NS factors) ============
template<int FIRST>
__global__ __launch_bounds__(256) void sq_k(const _Float16* __restrict__ Tc,
                                            _Float16* __restrict__ Tn,
                                            const float* __restrict__ Y0,
                                            const float* __restrict__ Y1,
                                            float* __restrict__ O0,
                                            float* __restrict__ O1,
                                            const float* __restrict__ scal)
{
    __shared__ __align__(16) char sm[20480];
    const int z = blockIdx.y;
    const int t = threadIdx.x;
    const int wave = t >> 6, lane = t & 63;
    const int ln = lane & 15, quad = lane >> 4;

    if (blockIdx.x < 36) {
        const long zo = (long)z * Ss * Ss;
        const int ti = d_tIs[blockIdx.x], tj = d_tJs[blockIdx.x];
        const int row0 = ti * 64, col0 = tj * 64;
        f32x4 acc[4];
#pragma unroll
        for (int i = 0; i < 4; ++i) acc[i] = (f32x4){0.f, 0.f, 0.f, 0.f};
        sym_core(sm, Tc, zo, row0, col0, Ss, acc);
        const float s = FIRST ? scal[z] : 0.f;
        const int gr0 = row0 + wave * 16 + quad * 4;
        _Float16 ov[4][4] __attribute__((aligned(8)));
#pragma unroll
        for (int nt = 0; nt < 4; ++nt) {
            const int gc = col0 + nt * 16 + ln;
#pragma unroll
            for (int r = 0; r < 4; ++r) {
                const long gi = zo + (long)(gr0 + r) * Ss + gc;
                float val;
                if (FIRST) val = s * s * acc[nt][r] - 2.0f * s * (float)Tc[gi];
                else       val = 2.0f * (float)Tc[gi] + acc[nt][r];
                ov[nt][r] = (_Float16)val;
            }
        }
        if (ti == tj) {
#pragma unroll
            for (int nt = 0; nt < 4; ++nt) {
                const int gc = col0 + nt * 16 + ln;
#pragma unroll
                for (int r = 0; r < 4; ++r)
                    Tn[zo + (long)(gr0 + r) * Ss + gc] = ov[nt][r];
            }
        } else {
            sym_store_offdiag(sm, Tn, zo, row0, col0, ov);
        }
    } else {
        const int bx = blockIdx.x - 36;
        const int cc = bx & 7, kh = bx >> 3;
        const int col0 = cc * 64;
        const long zA = (long)z * (HD * Ss);
        const long zB = (long)z * Ss * Ss;
        f32x4 acc[4];
#pragma unroll
        for (int i = 0; i < 4; ++i) acc[i] = (f32x4){0.f, 0.f, 0.f, 0.f};
        wk_core32<FIRST ? 0 : 1>(sm, Y0, Y1, Tc, zA, zB, col0, kh * 256, kh * 256 + 256, acc);
        const float alpha = FIRST ? -scal[z] : 1.0f;
        float* O = kh ? O1 : O0;
        const int gr = wave * 16 + quad * 4;
#pragma unroll
        for (int nt = 0; nt < 4; ++nt) {
            const int gc = col0 + nt * 16 + ln;
#pragma unroll
            for (int r = 0; r < 4; ++r) {
                const long idx = zA + (long)(gr + r) * Ss + gc;
                float val = alpha * acc[nt][r];
                if (kh == 0) {
                    if (FIRST) val += 2.0f * Y0[idx];
                    else       val += 2.0f * (Y0[idx] + Y1[idx]);
                }
                O[idx] = val;
            }
        }
    }
}

// ============ yk_k: y' = 2*y + y x T, split-K=2, fp32 half-buffers ============
__global__ __launch_bounds__(256) void yk_k(const float* __restrict__ A0,
                                            const float* __restrict__ A1,
                                            const _Float16* __restrict__ T,
                                            float* __restrict__ O0,
                                            float* __restrict__ O1)
{
    __shared__ __align__(16) char sm[20480];
    const int z = blockIdx.y;
    const int cc = blockIdx.x & 7, kh = blockIdx.x >> 3;
    const int col0 = cc * 64;
    const long zA = (long)z * (HD * Ss);
    const long zB = (long)z * Ss * Ss;
    const int t = threadIdx.x;
    const int wave = t >> 6, lane = t & 63;
    const int ln = lane & 15, quad = lane >> 4;

    f32x4 acc[4];
#pragma unroll
    for (int i = 0; i < 4; ++i) acc[i] = (f32x4){0.f, 0.f, 0.f, 0.f};
    wk_core32<1>(sm, A0, A1, T, zA, zB, col0, kh * 256, kh * 256 + 256, acc);

    float* O = kh ? O1 : O0;
    const int gr = wave * 16 + quad * 4;
#pragma unroll
    for (int nt = 0; nt < 4; ++nt) {
        const int gc = col0 + nt * 16 + ln;
#pragma unroll
        for (int r = 0; r < 4; ++r) {
            const long idx = zA + (long)(gr + r) * Ss + gc;
            float val = acc[nt][r];
            if (kh == 0) val += 2.0f * (A0[idx] + A1[idx]);
            O[idx] = val;
        }
    }
}

// ============ c2s_k: c2sT = inv_sig[n]*s*(y x Wt) + negoff partials ============
__global__ __launch_bounds__(256) void c2s_k(const float* __restrict__ A0,
                                             const float* __restrict__ A1,
                                             const _Float16* __restrict__ Wt,
                                             _Float16* __restrict__ c2sT,
                                             const float* __restrict__ scal,
                                             const float* __restrict__ inv_sig,
                                             const float* __restrict__ mu,
                                             float* __restrict__ negopart)
{
    __shared__ __align__(16) char sm[20480];
    __shared__ float red[64];
    const int z = blockIdx.y;
    const int h = z & 7;
    const int col0 = blockIdx.x * 64;
    const long zA = (long)z * (HD * Ss);
    const long zB = (long)z * Ss * Ss;
    const int t = threadIdx.x;
    const int wave = t >> 6, lane = t & 63;
    const int ln = lane & 15, quad = lane >> 4;

    f32x4 acc[4];
#pragma unroll
    for (int i = 0; i < 4; ++i) acc[i] = (f32x4){0.f, 0.f, 0.f, 0.f};
    wk_core32<1>(sm, A0, A1, Wt, zA, zB, col0, col0, Ss, acc);

    if (t < 64) red[t] = 0.f;
    __syncthreads();
    const int gr = wave * 16 + quad * 4;
    float pr[4] = {0.f, 0.f, 0.f, 0.f};
    float s = scal[z];
#pragma unroll
    for (int nt = 0; nt < 4; ++nt) {
        const int gc = col0 + nt * 16 + ln;
#pragma unroll
        for (int r = 0; r < 4; ++r) {
            float val = inv_sig[h * 512 + gc] * (s * acc[nt][r]);
            pr[r] += mu[h * 512 + gc] * val;
            c2sT[zA + (long)(gr + r) * Ss + gc] = (_Float16)val;
        }
    }
#pragma unroll
    for (int r = 0; r < 4; ++r)
        atomicAdd(&red[gr + r], pr[r]);
    __syncthreads();
    if (t < 64)
        negopart[(z * 8 + blockIdx.x) * 64 + t] = red[t];
}

// ============ ga_k: gat = Wh @ c2s - neg, fp32 out in [B,S,DIM] ============
__global__ __launch_bounds__(256) void ga_k(const _Float16* __restrict__ Wh,
                                            const _Float16* __restrict__ c2sT,
                                            const float* __restrict__ negopart,
                                            float* __restrict__ gat)
{
    __shared__ __align__(16) char sm[20480];
    __shared__ float neg[64];
    const int z = blockIdx.y;
    const int b = z >> 3, h = z & 7;
    const int m0 = blockIdx.x * 64;
    const long zA = (long)z * Ss * Ss;
    const long zB = (long)z * (HD * Ss);
    const int t = threadIdx.x;
    const int wave = t >> 6, lane = t & 63;
    const int ln = lane & 15, quad = lane >> 4;

    if (t < 64) {
        float s = 0.f;
#pragma unroll
        for (int k = 0; k < 8; ++k) s += negopart[(z * 8 + k) * 64 + t];
        neg[t] = s;
    }
    __syncthreads();

    f32x4 acc[4];
#pragma unroll
    for (int i = 0; i < 4; ++i) acc[i] = (f32x4){0.f, 0.f, 0.f, 0.f};
    wk_core(sm, c2sT, Wh, zB, zA, m0, 0, m0 + 64, acc);

    const int gr = wave * 16 + quad * 4;   // d index
#pragma unroll
    for (int nt = 0; nt < 4; ++nt) {
        const int m = m0 + nt * 16 + ln;
#pragma unroll
        for (int r = 0; r < 4; ++r) {
            const int d = gr + r;
            gat[(long)b * (Ss * DIM) + (long)m * DIM + h * HD + d] = acc[nt][r] - neg[d];
        }
    }
}

extern "C" void kernel_launch(void* const* d_in, const int* in_sizes, int n_in,
                              void* d_out, int out_size, void* d_ws, size_t ws_size,
                              hipStream_t stream)
{
    const float* x      = (const float*)d_in[0];
    const float* qkv_w  = (const float*)d_in[1];
    const float* qkv_b  = (const float*)d_in[2];
    const float* proj_w = (const float*)d_in[3];
    const float* proj_b = (const float*)d_in[4];
    float* out = (float*)d_out;
    float* ws  = (float*)d_ws;

    float* qkv     = ws;
    _Float16* Wh   = (_Float16*)(ws + 1572864);
    _Float16* Wt   = (_Float16*)(ws + 3670016);
    _Float16* vT   = (_Float16*)(ws + 5767168);
    _Float16* T[5];
    for (int i = 0; i < 5; ++i) T[i] = (_Float16*)(ws + 6029312 + (long)i * 2097152);
    float* Ya0 = ws + 16515072;   // fp32 y half-buffers, 524288 f each
    float* Ya1 = ws + 17039360;
    float* Yb0 = ws + 17563648;
    float* Yb1 = ws + 18087936;
    _Float16* c2sT = (_Float16*)(ws + 19136512);
    float* rsum    = ws + 19398656;   // 65536
    float* rsq     = ws + 19464192;   // 65536
    float* csum    = ws + 19529728;   // 65536
    float* scal    = ws + 19595264;   // 16
    float* mu      = ws + 19595280;   // 4096
    float* inv_sig = ws + 19599376;   // 4096
    float* negp    = ws + 19603472;   // 8192
    float* gat     = ws + 19611664;   // 524288

    dim3 blk(256);

    // 1. qkv = x @ qkv_w^T + qkv_b
    mm_k<<<dim3(12, 8), blk, 0, stream>>>(x, qkv_w, qkv_b, qkv, DIM, 3 * DIM);

    // 2. W fp16 (both layouts, 64-tiles) + reduction partials + vT
    wt_fused<<<dim3(66, 16), blk, 0, stream>>>(qkv, Wh, Wt, vT, rsum, rsq, csum);

    // 3. y0 = vT x Wt || scale || whitening stats || U = W W^T (unscaled)
    mid_k<<<dim3(728), blk, 0, stream>>>(vT, Wt, Ya0, rsum, rsq, csum, scal, mu, inv_sig,
                                         Wh, T[0]);

    // 4-7. fused NS steps (ascending k; factors commute):
    //      T1 = s^2 U U - 2 s U   || y1 = 2 y0 - s y0 U
    //      T_{k+1} = 2 T_k + T_k^2 || y_{k+1} = 2 y_k + y_k T_k
    sq_k<1><<<dim3(52, 16), blk, 0, stream>>>(T[0], T[1], Ya0, nullptr, Yb0, Yb1, scal);
    sq_k<0><<<dim3(52, 16), blk, 0, stream>>>(T[1], T[2], Yb0, Yb1,     Ya0, Ya1, scal);
    sq_k<0><<<dim3(52, 16), blk, 0, stream>>>(T[2], T[3], Ya0, Ya1,     Yb0, Yb1, scal);
    sq_k<0><<<dim3(52, 16), blk, 0, stream>>>(T[3], T[4], Yb0, Yb1,     Ya0, Ya1, scal);

    // 8. final y update with T4
    yk_k<<<dim3(16, 16), blk, 0, stream>>>(Ya0, Ya1, T[4], Yb0, Yb1);

    // 9. c2sT = inv_sig * s * (y W) + negoff partials
    c2s_k<<<dim3(8, 16), blk, 0, stream>>>(Yb0, Yb1, Wt, c2sT, scal, inv_sig, mu, negp);

    // 10. gat = W @ c2s - neg
    ga_k<<<dim3(8, 16), blk, 0, stream>>>(Wh, c2sT, negp, gat);

    // 11. out = gat @ proj_w^T + proj_b
    mm_k<<<dim3(4, 8), blk, 0, stream>>>(gat, proj_w, proj_b, out, DIM, DIM);
}

// Round 9
// 267.863 us; speedup vs baseline: 1.1007x; 1.0105x over previous
//
#include <hip/hip_runtime.h>

#define Bq 2
#define Hh 8
#define Ss 512
#define HD 64
#define DIM 512

using f32x4   = __attribute__((ext_vector_type(4))) float;
using bf16x8s = __attribute__((ext_vector_type(8))) short;
typedef _Float16 f16x8 __attribute__((ext_vector_type(8)));

__constant__ int d_tIs[36] = {0,1,1,2,2,2,3,3,3,3,4,4,4,4,4,5,5,5,5,5,5,6,6,6,6,6,6,6,7,7,7,7,7,7,7,7};
__constant__ int d_tJs[36] = {0,0,1,0,1,2,0,1,2,3,0,1,2,3,4,0,1,2,3,4,5,0,1,2,3,4,5,6,0,1,2,3,4,5,6,7};

__device__ __forceinline__ float bf2f(unsigned short u) {
    return __uint_as_float(((unsigned int)u) << 16);
}
__device__ __forceinline__ unsigned short f2bf(float f) {
    unsigned int u = __float_as_uint(f);
    u = (u + 0x7FFFu + ((u >> 16) & 1u)) >> 16;   // RNE
    return (unsigned short)u;
}

// ============ mm_k: C = A @ B^T + bias (fp32 io, split bf16x2 MFMA, 128x128) ============
__global__ __launch_bounds__(256) void mm_k(
    const float* __restrict__ A, const float* __restrict__ B,
    const float* __restrict__ bias, float* __restrict__ C,
    int K, int ldc)
{
    const int row0 = blockIdx.y * 128, col0 = blockIdx.x * 128;
    __shared__ unsigned short AsH[128][40], AsL[128][40];
    __shared__ unsigned short BsH[128][40], BsL[128][40];
    const int t = threadIdx.x;
    const int wave = t >> 6, lane = t & 63;
    const int ln = lane & 15, quad = lane >> 4;
    const int wm = (wave & 1) * 64, wn = (wave >> 1) * 64;

    f32x4 acc[4][4];
#pragma unroll
    for (int i = 0; i < 4; ++i)
#pragma unroll
        for (int j = 0; j < 4; ++j)
            acc[i][j] = (f32x4){0.f, 0.f, 0.f, 0.f};

    const int sr = t >> 2, sg = (t & 3) * 8;

    for (int k0 = 0; k0 < K; k0 += 32) {
        __syncthreads();
#pragma unroll
        for (int half = 0; half < 4; ++half) {
            const float* src = (half < 2) ? A : B;
            int base = (half < 2) ? row0 : col0;
            int row = sr + ((half & 1) ? 64 : 0);
            const float* p = &src[(long)(base + row) * K + k0 + sg];
            float4 f0 = *(const float4*)p;
            float4 f1 = *(const float4*)(p + 4);
            float fv[8] = {f0.x, f0.y, f0.z, f0.w, f1.x, f1.y, f1.z, f1.w};
            unsigned short hv[8], lv[8];
#pragma unroll
            for (int e = 0; e < 8; ++e) {
                hv[e] = f2bf(fv[e]);
                lv[e] = f2bf(fv[e] - bf2f(hv[e]));
            }
            uint4 H, L;
            H.x = hv[0] | (hv[1] << 16); H.y = hv[2] | (hv[3] << 16);
            H.z = hv[4] | (hv[5] << 16); H.w = hv[6] | (hv[7] << 16);
            L.x = lv[0] | (lv[1] << 16); L.y = lv[2] | (lv[3] << 16);
            L.z = lv[4] | (lv[5] << 16); L.w = lv[6] | (lv[7] << 16);
            if (half < 2) { *(uint4*)&AsH[row][sg] = H; *(uint4*)&AsL[row][sg] = L; }
            else          { *(uint4*)&BsH[row][sg] = H; *(uint4*)&BsL[row][sg] = L; }
        }
        __syncthreads();

        bf16x8s afH[4], afL[4], bfH[4], bfL[4];
#pragma unroll
        for (int mt = 0; mt < 4; ++mt) {
            afH[mt] = *(const bf16x8s*)&AsH[wm + mt * 16 + ln][quad * 8];
            afL[mt] = *(const bf16x8s*)&AsL[wm + mt * 16 + ln][quad * 8];
        }
#pragma unroll
        for (int nt = 0; nt < 4; ++nt) {
            bfH[nt] = *(const bf16x8s*)&BsH[wn + nt * 16 + ln][quad * 8];
            bfL[nt] = *(const bf16x8s*)&BsL[wn + nt * 16 + ln][quad * 8];
        }
#pragma unroll
        for (int mt = 0; mt < 4; ++mt)
#pragma unroll
            for (int nt = 0; nt < 4; ++nt) {
                acc[mt][nt] = __builtin_amdgcn_mfma_f32_16x16x32_bf16(afH[mt], bfH[nt], acc[mt][nt], 0, 0, 0);
                acc[mt][nt] = __builtin_amdgcn_mfma_f32_16x16x32_bf16(afH[mt], bfL[nt], acc[mt][nt], 0, 0, 0);
                acc[mt][nt] = __builtin_amdgcn_mfma_f32_16x16x32_bf16(afL[mt], bfH[nt], acc[mt][nt], 0, 0, 0);
            }
    }

#pragma unroll
    for (int mt = 0; mt < 4; ++mt) {
        const int gr0 = row0 + wm + mt * 16 + quad * 4;
#pragma unroll
        for (int nt = 0; nt < 4; ++nt) {
            const int gc = col0 + wn + nt * 16 + ln;
            float bb = bias[gc];
#pragma unroll
            for (int r = 0; r < 4; ++r)
                C[(long)(gr0 + r) * ldc + gc] = acc[mt][nt][r] + bb;
        }
    }
}

// ============ wt_fused: 64x64 tiles, W fp16 (both layouts) + partials + vT ============
__global__ __launch_bounds__(256) void wt_fused(const float* __restrict__ qkv,
                                                _Float16* __restrict__ Wh,
                                                _Float16* __restrict__ Wt,
                                                _Float16* __restrict__ vT,
                                                float* __restrict__ rsum,
                                                float* __restrict__ rsq,
                                                float* __restrict__ csum)
{
    __shared__ float qs[32][64];
    __shared__ float ks[32][64];
    __shared__ float colacc[64];
    int z = blockIdx.y;
    int b = z >> 3, h = z & 7;
    int t = threadIdx.x;
    int bx = blockIdx.x;
    long zo = (long)z * Ss * Ss;

    if (bx >= 64) {            // vT pack: half dh (d 32-chunk), all k
        float (*sT)[33] = (float(*)[33])qs;
        int dt = (bx - 64) * 32;
        int d = t & 31, kr = t >> 5;
        for (int kt = 0; kt < Ss; kt += 32) {
            __syncthreads();
#pragma unroll
            for (int p = 0; p < 4; ++p) {
                int kk = kr + p * 8;
                sT[kk][d] = qkv[(long)b * (Ss * 3 * DIM) + (long)(kt + kk) * (3 * DIM) + 2 * DIM + h * HD + dt + d];
            }
            __syncthreads();
#pragma unroll
            for (int p = 0; p < 4; ++p) {
                int dd = kr + p * 8;
                vT[(long)z * (HD * Ss) + (long)(dt + dd) * Ss + kt + d] = (_Float16)sT[d][dd];
            }
        }
        return;
    }

    int ti = bx >> 3, tj = bx & 7;
    int i0 = ti * 64, j0 = tj * 64;

    if (tj > ti) {             // fully-masked: zero only the partial slots
        if (t < 64) {
            rsum[((z * 8 + ti) * 512) + j0 + t] = 0.f;
            rsq [((z * 8 + ti) * 512) + j0 + t] = 0.f;
            csum[((z * 8 + tj) * 512) + i0 + t] = 0.f;
        }
        return;
    }

    int ia = (t & 15) * 4;
    int ja = (t >> 4) * 4;
    const float* qb = qkv + (long)b * Ss * (3 * DIM) + h * HD;
    const float* kb = qb + DIM;
    float acc[4][4] = {};

    for (int d0 = 0; d0 < 64; d0 += 32) {
        __syncthreads();
        int row = t & 63, dg = (t >> 6) * 8;
        float4 qv  = *(const float4*)&qb[(long)(i0 + row) * (3 * DIM) + d0 + dg];
        float4 qv2 = *(const float4*)&qb[(long)(i0 + row) * (3 * DIM) + d0 + dg + 4];
        float4 kv  = *(const float4*)&kb[(long)(j0 + row) * (3 * DIM) + d0 + dg];
        float4 kv2 = *(const float4*)&kb[(long)(j0 + row) * (3 * DIM) + d0 + dg + 4];
        qs[dg+0][row] = qv.x;  qs[dg+1][row] = qv.y;  qs[dg+2][row] = qv.z;  qs[dg+3][row] = qv.w;
        qs[dg+4][row] = qv2.x; qs[dg+5][row] = qv2.y; qs[dg+6][row] = qv2.z; qs[dg+7][row] = qv2.w;
        ks[dg+0][row] = kv.x;  ks[dg+1][row] = kv.y;  ks[dg+2][row] = kv.z;  ks[dg+3][row] = kv.w;
        ks[dg+4][row] = kv2.x; ks[dg+5][row] = kv2.y; ks[dg+6][row] = kv2.z; ks[dg+7][row] = kv2.w;
        __syncthreads();
#pragma unroll
        for (int d = 0; d < 32; ++d) {
            float4 q0 = *(const float4*)&qs[d][ia];
            float4 k0 = *(const float4*)&ks[d][ja];
            float qv_[4] = {q0.x, q0.y, q0.z, q0.w};
            float kv_[4] = {k0.x, k0.y, k0.z, k0.w};
#pragma unroll
            for (int aa = 0; aa < 4; ++aa)
#pragma unroll
                for (int c = 0; c < 4; ++c)
                    acc[aa][c] += fabsf(qv_[aa] - kv_[c]);
        }
    }

#pragma unroll
    for (int aa = 0; aa < 4; ++aa) {
        int i = i0 + ia + aa;
#pragma unroll
        for (int c = 0; c < 4; ++c) {
            int j = j0 + ja + c;
            float e = expf(-acc[aa][c] * 0.25f);
            acc[aa][c] = (j <= i) ? e : 0.0f;
        }
    }
    // Wt rows + per-j partials
#pragma unroll
    for (int c = 0; c < 4; ++c) {
        int j = j0 + ja + c;
        float rs = 0.f, rq = 0.f;
#pragma unroll
        for (int aa = 0; aa < 4; ++aa) { rs += acc[aa][c]; rq += acc[aa][c] * acc[aa][c]; }
        _Float16 ha[4] __attribute__((aligned(8))) = {(_Float16)acc[0][c], (_Float16)acc[1][c], (_Float16)acc[2][c], (_Float16)acc[3][c]};
        *(uint2*)&Wt[zo + (long)j * Ss + i0 + ia] = *(const uint2*)ha;
#pragma unroll
        for (int off = 8; off > 0; off >>= 1) {
            rs += __shfl_down(rs, off, 16);
            rq += __shfl_down(rq, off, 16);
        }
        if ((t & 15) == 0) {
            rsum[((z * 8 + ti) * 512) + j] = rs;
            rsq [((z * 8 + ti) * 512) + j] = rq;
        }
    }
    // Wh rows
#pragma unroll
    for (int aa = 0; aa < 4; ++aa) {
        int i = i0 + ia + aa;
        _Float16 hb[4] __attribute__((aligned(8))) = {(_Float16)acc[aa][0], (_Float16)acc[aa][1], (_Float16)acc[aa][2], (_Float16)acc[aa][3]};
        *(uint2*)&Wh[zo + (long)i * Ss + j0 + ja] = *(const uint2*)hb;
    }
    // per-i partials via LDS
    __syncthreads();
    if (t < 64) colacc[t] = 0.f;
    __syncthreads();
#pragma unroll
    for (int aa = 0; aa < 4; ++aa) {
        float cs = acc[aa][0] + acc[aa][1] + acc[aa][2] + acc[aa][3];
        atomicAdd(&colacc[ia + aa], cs);
    }
    __syncthreads();
    if (t < 64) csum[((z * 8 + tj) * 512) + i0 + t] = colacc[t];
}

// ============ fp16-A wide core, BK=64, LDS double-buffered (1 barrier / 64-K step) ============
// As/Bs [64][72] halfs per buffer; 36864 B total. kbeg/kend multiples of 64.
__device__ __forceinline__ void wk_core(char* smc, const _Float16* A, const _Float16* B,
                                        long zA, long zB, int col0, int kbeg, int kend,
                                        f32x4* acc)
{
    _Float16 (*As0)[72] = (_Float16(*)[72])smc;
    _Float16 (*Bs0)[72] = (_Float16(*)[72])(smc + 9216);
    _Float16 (*As1)[72] = (_Float16(*)[72])(smc + 18432);
    _Float16 (*Bs1)[72] = (_Float16(*)[72])(smc + 27648);
    const int t = threadIdx.x;
    const int wave = t >> 6, lane = t & 63;
    const int ln = lane & 15, quad = lane >> 4;
    const int r2 = t >> 2, c2 = (t & 3) * 16;
    const long aoff = zA + (long)r2 * Ss;
    const long boff = zB + (long)(col0 + r2) * Ss;

    uint4 ua0 = *(const uint4*)&A[aoff + kbeg + c2];
    uint4 ua1 = *(const uint4*)&A[aoff + kbeg + c2 + 8];
    uint4 ub0 = *(const uint4*)&B[boff + kbeg + c2];
    uint4 ub1 = *(const uint4*)&B[boff + kbeg + c2 + 8];
    *(uint4*)&As0[r2][c2]     = ua0;
    *(uint4*)&As0[r2][c2 + 8] = ua1;
    *(uint4*)&Bs0[r2][c2]     = ub0;
    *(uint4*)&Bs0[r2][c2 + 8] = ub1;
    int cur = 0;
    for (int k0 = kbeg; k0 < kend; k0 += 64) {
        int kn = k0 + 64;
        if (kn < kend) {
            ua0 = *(const uint4*)&A[aoff + kn + c2];
            ua1 = *(const uint4*)&A[aoff + kn + c2 + 8];
            ub0 = *(const uint4*)&B[boff + kn + c2];
            ub1 = *(const uint4*)&B[boff + kn + c2 + 8];
        }
        __syncthreads();
        _Float16 (*As)[72] = cur ? As1 : As0;
        _Float16 (*Bs)[72] = cur ? Bs1 : Bs0;
#pragma unroll
        for (int kk = 0; kk < 64; kk += 32) {
            f16x8 af = *(const f16x8*)&As[wave * 16 + ln][quad * 8 + kk];
#pragma unroll
            for (int nt = 0; nt < 4; ++nt) {
                f16x8 bf = *(const f16x8*)&Bs[nt * 16 + ln][quad * 8 + kk];
                acc[nt] = __builtin_amdgcn_mfma_f32_16x16x32_f16(af, bf, acc[nt], 0, 0, 0);
            }
        }
        if (kn < kend) {
            _Float16 (*An)[72] = cur ? As0 : As1;
            _Float16 (*Bn)[72] = cur ? Bs0 : Bs1;
            *(uint4*)&An[r2][c2]     = ua0;
            *(uint4*)&An[r2][c2 + 8] = ua1;
            *(uint4*)&Bn[r2][c2]     = ub0;
            *(uint4*)&Bn[r2][c2 + 8] = ub1;
        }
        cur ^= 1;
    }
}

// ============ fp32-halves-A wide core, BK=32, double-buffered (VGPR-bounded) ============
template<int HASA1>
__device__ __forceinline__ void wk_core32(char* smc, const float* A0, const float* A1,
                                          const _Float16* B, long zA, long zB, int col0,
                                          int kbeg, int kend, f32x4* acc)
{
    _Float16 (*As0)[40] = (_Float16(*)[40])smc;
    _Float16 (*Bs0)[40] = (_Float16(*)[40])(smc + 5120);
    _Float16 (*As1)[40] = (_Float16(*)[40])(smc + 10240);
    _Float16 (*Bs1)[40] = (_Float16(*)[40])(smc + 15360);
    const int t = threadIdx.x;
    const int wave = t >> 6, lane = t & 63;
    const int ln = lane & 15, quad = lane >> 4;
    const int r4 = t >> 2, c4 = (t & 3) * 8;
    const long aoff = zA + (long)r4 * Ss;
    const long boff = zB + (long)(col0 + r4) * Ss;

    float4 p0 = *(const float4*)&A0[aoff + kbeg + c4];
    float4 p1 = *(const float4*)&A0[aoff + kbeg + c4 + 4];
    float4 q0, q1;
    if constexpr (HASA1) {
        q0 = *(const float4*)&A1[aoff + kbeg + c4];
        q1 = *(const float4*)&A1[aoff + kbeg + c4 + 4];
    }
    uint4 ub = *(const uint4*)&B[boff + kbeg + c4];
    {
        _Float16 hv[8] __attribute__((aligned(16)));
        if constexpr (HASA1) {
            hv[0] = (_Float16)(p0.x + q0.x); hv[1] = (_Float16)(p0.y + q0.y);
            hv[2] = (_Float16)(p0.z + q0.z); hv[3] = (_Float16)(p0.w + q0.w);
            hv[4] = (_Float16)(p1.x + q1.x); hv[5] = (_Float16)(p1.y + q1.y);
            hv[6] = (_Float16)(p1.z + q1.z); hv[7] = (_Float16)(p1.w + q1.w);
        } else {
            hv[0] = (_Float16)p0.x; hv[1] = (_Float16)p0.y;
            hv[2] = (_Float16)p0.z; hv[3] = (_Float16)p0.w;
            hv[4] = (_Float16)p1.x; hv[5] = (_Float16)p1.y;
            hv[6] = (_Float16)p1.z; hv[7] = (_Float16)p1.w;
        }
        *(uint4*)&As0[r4][c4] = *(const uint4*)hv;
        *(uint4*)&Bs0[r4][c4] = ub;
    }
    int cur = 0;
    for (int k0 = kbeg; k0 < kend; k0 += 32) {
        int kn = k0 + 32;
        if (kn < kend) {
            p0 = *(const float4*)&A0[aoff + kn + c4];
            p1 = *(const float4*)&A0[aoff + kn + c4 + 4];
            if constexpr (HASA1) {
                q0 = *(const float4*)&A1[aoff + kn + c4];
                q1 = *(const float4*)&A1[aoff + kn + c4 + 4];
            }
            ub = *(const uint4*)&B[boff + kn + c4];
        }
        __syncthreads();
        _Float16 (*As)[40] = cur ? As1 : As0;
        _Float16 (*Bs)[40] = cur ? Bs1 : Bs0;
        f16x8 af = *(const f16x8*)&As[wave * 16 + ln][quad * 8];
#pragma unroll
        for (int nt = 0; nt < 4; ++nt) {
            f16x8 bf = *(const f16x8*)&Bs[nt * 16 + ln][quad * 8];
            acc[nt] = __builtin_amdgcn_mfma_f32_16x16x32_f16(af, bf, acc[nt], 0, 0, 0);
        }
        if (kn < kend) {
            _Float16 hv[8] __attribute__((aligned(16)));
            if constexpr (HASA1) {
                hv[0] = (_Float16)(p0.x + q0.x); hv[1] = (_Float16)(p0.y + q0.y);
                hv[2] = (_Float16)(p0.z + q0.z); hv[3] = (_Float16)(p0.w + q0.w);
                hv[4] = (_Float16)(p1.x + q1.x); hv[5] = (_Float16)(p1.y + q1.y);
                hv[6] = (_Float16)(p1.z + q1.z); hv[7] = (_Float16)(p1.w + q1.w);
            } else {
                hv[0] = (_Float16)p0.x; hv[1] = (_Float16)p0.y;
                hv[2] = (_Float16)p0.z; hv[3] = (_Float16)p0.w;
                hv[4] = (_Float16)p1.x; hv[5] = (_Float16)p1.y;
                hv[6] = (_Float16)p1.z; hv[7] = (_Float16)p1.w;
            }
            _Float16 (*An)[40] = cur ? As0 : As1;
            _Float16 (*Bn)[40] = cur ? Bs0 : Bs1;
            *(uint4*)&An[r4][c4] = *(const uint4*)hv;
            *(uint4*)&Bn[r4][c4] = ub;
        }
        cur ^= 1;
    }
}

// ============ sym_core: 64x64 tile of A @ A^T, BK=64, double-buffered ============
__device__ __forceinline__ void sym_core(char* smc, const _Float16* A, long zo,
                                         int row0, int col0, int kend, f32x4* acc)
{
    _Float16 (*As0)[72] = (_Float16(*)[72])smc;
    _Float16 (*Bs0)[72] = (_Float16(*)[72])(smc + 9216);
    _Float16 (*As1)[72] = (_Float16(*)[72])(smc + 18432);
    _Float16 (*Bs1)[72] = (_Float16(*)[72])(smc + 27648);
    const int t = threadIdx.x;
    const int wave = t >> 6, lane = t & 63;
    const int ln = lane & 15, quad = lane >> 4;
    const int r2 = t >> 2, c2 = (t & 3) * 16;
    const long aoff = zo + (long)(row0 + r2) * Ss;
    const long boff = zo + (long)(col0 + r2) * Ss;
    uint4 ua0 = *(const uint4*)&A[aoff + c2];
    uint4 ua1 = *(const uint4*)&A[aoff + c2 + 8];
    uint4 ub0 = *(const uint4*)&A[boff + c2];
    uint4 ub1 = *(const uint4*)&A[boff + c2 + 8];
    *(uint4*)&As0[r2][c2]     = ua0;
    *(uint4*)&As0[r2][c2 + 8] = ua1;
    *(uint4*)&Bs0[r2][c2]     = ub0;
    *(uint4*)&Bs0[r2][c2 + 8] = ub1;
    int cur = 0;
    for (int k0 = 0; k0 < kend; k0 += 64) {
        int kn = k0 + 64;
        if (kn < kend) {
            ua0 = *(const uint4*)&A[aoff + kn + c2];
            ua1 = *(const uint4*)&A[aoff + kn + c2 + 8];
            ub0 = *(const uint4*)&A[boff + kn + c2];
            ub1 = *(const uint4*)&A[boff + kn + c2 + 8];
        }
        __syncthreads();
        _Float16 (*As)[72] = cur ? As1 : As0;
        _Float16 (*Bs)[72] = cur ? Bs1 : Bs0;
#pragma unroll
        for (int kk = 0; kk < 64; kk += 32) {
            f16x8 af = *(const f16x8*)&As[wave * 16 + ln][quad * 8 + kk];
#pragma unroll
            for (int nt = 0; nt < 4; ++nt) {
                f16x8 bf = *(const f16x8*)&Bs[nt * 16 + ln][quad * 8 + kk];
                acc[nt] = __builtin_amdgcn_mfma_f32_16x16x32_f16(af, bf, acc[nt], 0, 0, 0);
            }
        }
        if (kn < kend) {
            _Float16 (*An)[72] = cur ? As0 : As1;
            _Float16 (*Bn)[72] = cur ? Bs0 : Bs1;
            *(uint4*)&An[r2][c2]     = ua0;
            *(uint4*)&An[r2][c2 + 8] = ua1;
            *(uint4*)&Bn[r2][c2]     = ub0;
            *(uint4*)&Bn[r2][c2 + 8] = ub1;
        }
        cur ^= 1;
    }
}

// ============ sym_epilogue: coalesced dual-layout store of a 64x64 fp16 tile ============
__device__ __forceinline__ void sym_store_offdiag(char* smc, _Float16* T, long zo,
                                                  int row0, int col0,
                                                  const _Float16 (*ov)[4])
{
    _Float16 (*ltR)[72] = (_Float16(*)[72])smc;            // 9216 B
    _Float16 (*ltT)[72] = (_Float16(*)[72])(smc + 9216);   // 9216 B
    const int t = threadIdx.x;
    const int wave = t >> 6, lane = t & 63;
    const int ln = lane & 15, quad = lane >> 4;
    const int lr0 = wave * 16 + quad * 4;
    __syncthreads();                       // sym_core LDS reads complete
#pragma unroll
    for (int nt = 0; nt < 4; ++nt) {
        const int lc = nt * 16 + ln;
        *(uint2*)&ltT[lc][lr0] = *(const uint2*)ov[nt];
#pragma unroll
        for (int r = 0; r < 4; ++r)
            ltR[lr0 + r][lc] = ov[nt][r];
    }
    __syncthreads();
    const int tr = t >> 2, tcg = (t & 3) * 16;
    uint4 a0 = *(const uint4*)&ltR[tr][tcg];
    uint4 a1 = *(const uint4*)&ltR[tr][tcg + 8];
    _Float16* d0 = &T[zo + (long)(row0 + tr) * Ss + col0 + tcg];
    *(uint4*)&d0[0] = a0;
    *(uint4*)&d0[8] = a1;
    uint4 b0 = *(const uint4*)&ltT[tr][tcg];
    uint4 b1 = *(const uint4*)&ltT[tr][tcg + 8];
    _Float16* d1 = &T[zo + (long)(col0 + tr) * Ss + row0 + tcg];
    *(uint4*)&d1[0] = b0;
    *(uint4*)&d1[8] = b1;
}

// ============ mid_k: 0..127 y0 = vT x Wt; 128..143 scal; 144..151 stats; 152..727 U ============
__global__ __launch_bounds__(256) void mid_k(const _Float16* __restrict__ vT,
                                             const _Float16* __restrict__ Wt,
                                             float* __restrict__ y0,
                                             const float* __restrict__ rsum,
                                             const float* __restrict__ rsq,
                                             const float* __restrict__ csum,
                                             float* __restrict__ scal,
                                             float* __restrict__ mu,
                                             float* __restrict__ inv_sig,
                                             const _Float16* __restrict__ Wh,
                                             _Float16* __restrict__ U)
{
    __shared__ __align__(16) char sm[36864];
    int bx = blockIdx.x, t = threadIdx.x;
    if (bx < 128) {
        int z = bx >> 3, cc = bx & 7;
        int col0 = cc * 64;
        long zA = (long)z * (HD * Ss), zB = (long)z * Ss * Ss;
        f32x4 acc[4];
#pragma unroll
        for (int i = 0; i < 4; ++i) acc[i] = (f32x4){0.f, 0.f, 0.f, 0.f};
        wk_core(sm, vT, Wt, zA, zB, col0, col0, Ss, acc);
        const int wave = t >> 6, lane = t & 63;
        const int ln = lane & 15, quad = lane >> 4;
        const int gr = wave * 16 + quad * 4;
#pragma unroll
        for (int nt = 0; nt < 4; ++nt) {
            const int gc = col0 + nt * 16 + ln;
#pragma unroll
            for (int r = 0; r < 4; ++r)
                y0[zA + (long)(gr + r) * Ss + gc] = acc[nt][r];
        }
    } else if (bx < 144) {
        int z = bx - 128;
        float* s1 = (float*)sm;
        float* s2 = s1 + 256;
        float mx1 = 0.f, mx2 = 0.f;
        for (int jj = t; jj < 512; jj += 256) {
            float rs = 0.f, cs = 0.f;
#pragma unroll
            for (int ti = 0; ti < 8; ++ti) {
                rs += rsum[(z * 8 + ti) * 512 + jj];
                cs += csum[(z * 8 + ti) * 512 + jj];
            }
            mx1 = fmaxf(mx1, rs);
            mx2 = fmaxf(mx2, cs);
        }
        s1[t] = mx1; s2[t] = mx2;
        __syncthreads();
        for (int off = 128; off > 0; off >>= 1) {
            if (t < off) {
                s1[t] = fmaxf(s1[t], s1[t + off]);
                s2[t] = fmaxf(s2[t], s2[t + off]);
            }
            __syncthreads();
        }
        if (t == 0) scal[z] = 1.0f / (s1[0] * s2[0]);
    } else if (bx < 152) {
        int h = bx - 144;
        for (int jj = t; jj < 512; jj += 256) {
            float s = 0.f, q = 0.f;
#pragma unroll
            for (int b = 0; b < 2; ++b)
#pragma unroll
                for (int ti = 0; ti < 8; ++ti) {
                    int zz = b * 8 + h;
                    s += rsum[(zz * 8 + ti) * 512 + jj];
                    q += rsq [(zz * 8 + ti) * 512 + jj];
                }
            float m_ = s / 1024.f;
            float var = (q - s * s / 1024.f) / 1023.f;
            inv_sig[h * 512 + jj] = 1.0f / sqrtf(var + 1e-5f);
            mu[h * 512 + jj] = m_;
        }
    } else {
        // U = W @ W^T (unscaled, fp16), 36 lower 64-tiles + mirror per z
        int u = bx - 152;
        int z = u / 36;
        int tile = u - z * 36;
        const long zo = (long)z * Ss * Ss;
        const int ti = d_tIs[tile], tj = d_tJs[tile];
        const int row0 = ti * 64, col0 = tj * 64;
        f32x4 acc[4];
#pragma unroll
        for (int i = 0; i < 4; ++i) acc[i] = (f32x4){0.f, 0.f, 0.f, 0.f};
        sym_core(sm, Wh, zo, row0, col0, col0 + 64, acc);   // K truncated: W lower-tri
        const int wave = t >> 6, lane = t & 63;
        const int ln = lane & 15, quad = lane >> 4;
        _Float16 ov[4][4] __attribute__((aligned(8)));
#pragma unroll
        for (int nt = 0; nt < 4; ++nt)
#pragma unroll
            for (int r = 0; r < 4; ++r)
                ov[nt][r] = (_Float16)acc[nt][r];
        if (ti == tj) {
            const int gr0 = row0 + wave * 16 + quad * 4;
#pragma unroll
            for (int nt = 0; nt < 4; ++nt) {
                const int gc = col0 + nt * 16 + ln;
#pragma unroll
                for (int r = 0; r < 4; ++r)
                    U[zo + (long)(gr0 + r) * Ss + gc] = ov[nt][r];
            }
        } else {
            sym_store_offdiag(sm, U, zo, row0, col0, ov);
        }
    }
}

// ============ sq_k<FIRST>: fused T-squaring + y-update (commuting NS factors) ============
template<int FIRST>
__global__ __launch_bounds__(256) void sq_k(const _Float16* __restrict__ Tc,
                                            _Float16* __restrict__ Tn,
                                            const float* __restrict__ Y0,
                                            const float* __restrict__ Y1,
                                            float* __restrict__ O0,
                                            float* __restrict__ O1,
                                            const float* __restrict__ scal)
{
    __shared__ __align__(16) char sm[36864];
    const int z = blockIdx.y;
    const int t = threadIdx.x;
    const int wave = t >> 6, lane = t & 63;
    const int ln = lane & 15, quad = lane >> 4;

    if (blockIdx.x < 36) {
        const long zo = (long)z * Ss * Ss;
        const int ti = d_tIs[blockIdx.x], tj = d_tJs[blockIdx.x];
        const int row0 = ti * 64, col0 = tj * 64;
        f32x4 acc[4];
#pragma unroll
        for (int i = 0; i < 4; ++i) acc[i] = (f32x4){0.f, 0.f, 0.f, 0.f};
        sym_core(sm, Tc, zo, row0, col0, Ss, acc);
        const float s = FIRST ? scal[z] : 0.f;
        const int gr0 = row0 + wave * 16 + quad * 4;
        _Float16 ov[4][4] __attribute__((aligned(8)));
#pragma unroll
        for (int nt = 0; nt < 4; ++nt) {
            const int gc = col0 + nt * 16 + ln;
#pragma unroll
            for (int r = 0; r < 4; ++r) {
                const long gi = zo + (long)(gr0 + r) * Ss + gc;
                float val;
                if (FIRST) val = s * s * acc[nt][r] - 2.0f * s * (float)Tc[gi];
                else       val = 2.0f * (float)Tc[gi] + acc[nt][r];
                ov[nt][r] = (_Float16)val;
            }
        }
        if (ti == tj) {
#pragma unroll
            for (int nt = 0; nt < 4; ++nt) {
                const int gc = col0 + nt * 16 + ln;
#pragma unroll
                for (int r = 0; r < 4; ++r)
                    Tn[zo + (long)(gr0 + r) * Ss + gc] = ov[nt][r];
            }
        } else {
            sym_store_offdiag(sm, Tn, zo, row0, col0, ov);
        }
    } else {
        const int bx = blockIdx.x - 36;
        const int cc = bx & 7, kh = bx >> 3;
        const int col0 = cc * 64;
        const long zA = (long)z * (HD * Ss);
        const long zB = (long)z * Ss * Ss;
        f32x4 acc[4];
#pragma unroll
        for (int i = 0; i < 4; ++i) acc[i] = (f32x4){0.f, 0.f, 0.f, 0.f};
        wk_core32<FIRST ? 0 : 1>(sm, Y0, Y1, Tc, zA, zB, col0, kh * 256, kh * 256 + 256, acc);
        const float alpha = FIRST ? -scal[z] : 1.0f;
        float* O = kh ? O1 : O0;
        const int gr = wave * 16 + quad * 4;
#pragma unroll
        for (int nt = 0; nt < 4; ++nt) {
            const int gc = col0 + nt * 16 + ln;
#pragma unroll
            for (int r = 0; r < 4; ++r) {
                const long idx = zA + (long)(gr + r) * Ss + gc;
                float val = alpha * acc[nt][r];
                if (kh == 0) {
                    if (FIRST) val += 2.0f * Y0[idx];
                    else       val += 2.0f * (Y0[idx] + Y1[idx]);
                }
                O[idx] = val;
            }
        }
    }
}

// ============ yk_k: y' = 2*y + y x T, split-K=2, fp32 half-buffers ============
__global__ __launch_bounds__(256) void yk_k(const float* __restrict__ A0,
                                            const float* __restrict__ A1,
                                            const _Float16* __restrict__ T,
                                            float* __restrict__ O0,
                                            float* __restrict__ O1)
{
    __shared__ __align__(16) char sm[20480];
    const int z = blockIdx.y;
    const int cc = blockIdx.x & 7, kh = blockIdx.x >> 3;
    const int col0 = cc * 64;
    const long zA = (long)z * (HD * Ss);
    const long zB = (long)z * Ss * Ss;
    const int t = threadIdx.x;
    const int wave = t >> 6, lane = t & 63;
    const int ln = lane & 15, quad = lane >> 4;

    f32x4 acc[4];
#pragma unroll
    for (int i = 0; i < 4; ++i) acc[i] = (f32x4){0.f, 0.f, 0.f, 0.f};
    wk_core32<1>(sm, A0, A1, T, zA, zB, col0, kh * 256, kh * 256 + 256, acc);

    float* O = kh ? O1 : O0;
    const int gr = wave * 16 + quad * 4;
#pragma unroll
    for (int nt = 0; nt < 4; ++nt) {
        const int gc = col0 + nt * 16 + ln;
#pragma unroll
        for (int r = 0; r < 4; ++r) {
            const long idx = zA + (long)(gr + r) * Ss + gc;
            float val = acc[nt][r];
            if (kh == 0) val += 2.0f * (A0[idx] + A1[idx]);
            O[idx] = val;
        }
    }
}

// ============ c2s_k: c2sT = inv_sig[n]*s*(y x Wt) + negoff partials ============
__global__ __launch_bounds__(256) void c2s_k(const float* __restrict__ A0,
                                             const float* __restrict__ A1,
                                             const _Float16* __restrict__ Wt,
                                             _Float16* __restrict__ c2sT,
                                             const float* __restrict__ scal,
                                             const float* __restrict__ inv_sig,
                                             const float* __restrict__ mu,
                                             float* __restrict__ negopart)
{
    __shared__ __align__(16) char sm[20480];
    __shared__ float red[64];
    const int z = blockIdx.y;
    const int h = z & 7;
    const int col0 = blockIdx.x * 64;
    const long zA = (long)z * (HD * Ss);
    const long zB = (long)z * Ss * Ss;
    const int t = threadIdx.x;
    const int wave = t >> 6, lane = t & 63;
    const int ln = lane & 15, quad = lane >> 4;

    f32x4 acc[4];
#pragma unroll
    for (int i = 0; i < 4; ++i) acc[i] = (f32x4){0.f, 0.f, 0.f, 0.f};
    wk_core32<1>(sm, A0, A1, Wt, zA, zB, col0, col0, Ss, acc);

    if (t < 64) red[t] = 0.f;
    __syncthreads();
    const int gr = wave * 16 + quad * 4;
    float pr[4] = {0.f, 0.f, 0.f, 0.f};
    float s = scal[z];
#pragma unroll
    for (int nt = 0; nt < 4; ++nt) {
        const int gc = col0 + nt * 16 + ln;
#pragma unroll
        for (int r = 0; r < 4; ++r) {
            float val = inv_sig[h * 512 + gc] * (s * acc[nt][r]);
            pr[r] += mu[h * 512 + gc] * val;
            c2sT[zA + (long)(gr + r) * Ss + gc] = (_Float16)val;
        }
    }
#pragma unroll
    for (int r = 0; r < 4; ++r)
        atomicAdd(&red[gr + r], pr[r]);
    __syncthreads();
    if (t < 64)
        negopart[(z * 8 + blockIdx.x) * 64 + t] = red[t];
}

// ============ ga_k: gat = Wh @ c2s - neg, fp32 out in [B,S,DIM] ============
__global__ __launch_bounds__(256) void ga_k(const _Float16* __restrict__ Wh,
                                            const _Float16* __restrict__ c2sT,
                                            const float* __restrict__ negopart,
                                            float* __restrict__ gat)
{
    __shared__ __align__(16) char sm[36864];
    __shared__ float neg[64];
    const int z = blockIdx.y;
    const int b = z >> 3, h = z & 7;
    const int m0 = blockIdx.x * 64;
    const long zA = (long)z * Ss * Ss;
    const long zB = (long)z * (HD * Ss);
    const int t = threadIdx.x;
    const int wave = t >> 6, lane = t & 63;
    const int ln = lane & 15, quad = lane >> 4;

    if (t < 64) {
        float s = 0.f;
#pragma unroll
        for (int k = 0; k < 8; ++k) s += negopart[(z * 8 + k) * 64 + t];
        neg[t] = s;
    }
    __syncthreads();

    f32x4 acc[4];
#pragma unroll
    for (int i = 0; i < 4; ++i) acc[i] = (f32x4){0.f, 0.f, 0.f, 0.f};
    wk_core(sm, c2sT, Wh, zB, zA, m0, 0, m0 + 64, acc);

    const int gr = wave * 16 + quad * 4;   // d index
#pragma unroll
    for (int nt = 0; nt < 4; ++nt) {
        const int m = m0 + nt * 16 + ln;
#pragma unroll
        for (int r = 0; r < 4; ++r) {
            const int d = gr + r;
            gat[(long)b * (Ss * DIM) + (long)m * DIM + h * HD + d] = acc[nt][r] - neg[d];
        }
    }
}

extern "C" void kernel_launch(void* const* d_in, const int* in_sizes, int n_in,
                              void* d_out, int out_size, void* d_ws, size_t ws_size,
                              hipStream_t stream)
{
    const float* x      = (const float*)d_in[0];
    const float* qkv_w  = (const float*)d_in[1];
    const float* qkv_b  = (const float*)d_in[2];
    const float* proj_w = (const float*)d_in[3];
    const float* proj_b = (const float*)d_in[4];
    float* out = (float*)d_out;
    float* ws  = (float*)d_ws;

    float* qkv     = ws;
    _Float16* Wh   = (_Float16*)(ws + 1572864);
    _Float16* Wt   = (_Float16*)(ws + 3670016);
    _Float16* vT   = (_Float16*)(ws + 5767168);
    _Float16* T[5];
    for (int i = 0; i < 5; ++i) T[i] = (_Float16*)(ws + 6029312 + (long)i * 2097152);
    float* Ya0 = ws + 16515072;   // fp32 y half-buffers, 524288 f each
    float* Ya1 = ws + 17039360;
    float* Yb0 = ws + 17563648;
    float* Yb1 = ws + 18087936;
    _Float16* c2sT = (_Float16*)(ws + 19136512);
    float* rsum    = ws + 19398656;   // 65536
    float* rsq     = ws + 19464192;   // 65536
    float* csum    = ws + 19529728;   // 65536
    float* scal    = ws + 19595264;   // 16
    float* mu      = ws + 19595280;   // 4096
    float* inv_sig = ws + 19599376;   // 4096
    float* negp    = ws + 19603472;   // 8192
    float* gat     = ws + 19611664;   // 524288

    dim3 blk(256);

    // 1. qkv = x @ qkv_w^T + qkv_b
    mm_k<<<dim3(12, 8), blk, 0, stream>>>(x, qkv_w, qkv_b, qkv, DIM, 3 * DIM);

    // 2. W fp16 (both layouts, 64-tiles) + reduction partials + vT
    wt_fused<<<dim3(66, 16), blk, 0, stream>>>(qkv, Wh, Wt, vT, rsum, rsq, csum);

    // 3. y0 = vT x Wt || scale || whitening stats || U = W W^T (unscaled)
    mid_k<<<dim3(728), blk, 0, stream>>>(vT, Wt, Ya0, rsum, rsq, csum, scal, mu, inv_sig,
                                         Wh, T[0]);

    // 4-7. fused NS steps (ascending k; factors commute):
    //      T1 = s^2 U U - 2 s U   || y1 = 2 y0 - s y0 U
    //      T_{k+1} = 2 T_k + T_k^2 || y_{k+1} = 2 y_k + y_k T_k
    sq_k<1><<<dim3(52, 16), blk, 0, stream>>>(T[0], T[1], Ya0, nullptr, Yb0, Yb1, scal);
    sq_k<0><<<dim3(52, 16), blk, 0, stream>>>(T[1], T[2], Yb0, Yb1,     Ya0, Ya1, scal);
    sq_k<0><<<dim3(52, 16), blk, 0, stream>>>(T[2], T[3], Ya0, Ya1,     Yb0, Yb1, scal);
    sq_k<0><<<dim3(52, 16), blk, 0, stream>>>(T[3], T[4], Yb0, Yb1,     Ya0, Ya1, scal);

    // 8. final y update with T4
    yk_k<<<dim3(16, 16), blk, 0, stream>>>(Ya0, Ya1, T[4], Yb0, Yb1);

    // 9. c2sT = inv_sig * s * (y W) + negoff partials
    c2s_k<<<dim3(8, 16), blk, 0, stream>>>(Yb0, Yb1, Wt, c2sT, scal, inv_sig, mu, negp);

    // 10. gat = W @ c2s - neg
    ga_k<<<dim3(8, 16), blk, 0, stream>>>(Wh, c2sT, negp, gat);

    // 11. out = gat @ proj_w^T + proj_b
    mm_k<<<dim3(4, 8), blk, 0, stream>>>(gat, proj_w, proj_b, out, DIM, DIM);
}

// Round 10
// 242.161 us; speedup vs baseline: 1.2175x; 1.1061x over previous
//
#include <hip/hip_runtime.h>

#define Bq 2
#define Hh 8
#define Ss 512
#define HD 64
#define DIM 512

using f32x4   = __attribute__((ext_vector_type(4))) float;
using bf16x8s = __attribute__((ext_vector_type(8))) short;
typedef _Float16 f16x8 __attribute__((ext_vector_type(8)));

__constant__ int d_tIs[36] = {0,1,1,2,2,2,3,3,3,3,4,4,4,4,4,5,5,5,5,5,5,6,6,6,6,6,6,6,7,7,7,7,7,7,7,7};
__constant__ int d_tJs[36] = {0,0,1,0,1,2,0,1,2,3,0,1,2,3,4,0,1,2,3,4,5,0,1,2,3,4,5,6,0,1,2,3,4,5,6,7};

__device__ __forceinline__ float bf2f(unsigned short u) {
    return __uint_as_float(((unsigned int)u) << 16);
}
__device__ __forceinline__ unsigned short f2bf(float f) {
    unsigned int u = __float_as_uint(f);
    u = (u + 0x7FFFu + ((u >> 16) & 1u)) >> 16;   // RNE
    return (unsigned short)u;
}

// ============ mm64_k: C = A @ B^T + bias (fp32 io, split bf16x2 MFMA, 64x64 tiles) ============
// Same split-bf16 3-MFMA arithmetic and K-order as the old 128x128 mm_k -> bit-identical C,
// but 4x the block-parallelism (these GEMMs were at 0.12-0.37 blocks/CU).
__global__ __launch_bounds__(256) void mm64_k(
    const float* __restrict__ A, const float* __restrict__ B,
    const float* __restrict__ bias, float* __restrict__ C,
    int K, int ldc)
{
    const int row0 = blockIdx.y * 64, col0 = blockIdx.x * 64;
    __shared__ unsigned short AsH[64][40], AsL[64][40];
    __shared__ unsigned short BsH[64][40], BsL[64][40];
    const int t = threadIdx.x;
    const int wave = t >> 6, lane = t & 63;
    const int ln = lane & 15, quad = lane >> 4;

    f32x4 acc[4];
#pragma unroll
    for (int i = 0; i < 4; ++i) acc[i] = (f32x4){0.f, 0.f, 0.f, 0.f};

    const int sr = t >> 2, sg = (t & 3) * 8;

    for (int k0 = 0; k0 < K; k0 += 32) {
        __syncthreads();
#pragma unroll
        for (int half = 0; half < 2; ++half) {
            const float* src = half ? B : A;
            int base = half ? col0 : row0;
            const float* p = &src[(long)(base + sr) * K + k0 + sg];
            float4 f0 = *(const float4*)p;
            float4 f1 = *(const float4*)(p + 4);
            float fv[8] = {f0.x, f0.y, f0.z, f0.w, f1.x, f1.y, f1.z, f1.w};
            unsigned short hv[8], lv[8];
#pragma unroll
            for (int e = 0; e < 8; ++e) {
                hv[e] = f2bf(fv[e]);
                lv[e] = f2bf(fv[e] - bf2f(hv[e]));
            }
            uint4 H, L;
            H.x = hv[0] | (hv[1] << 16); H.y = hv[2] | (hv[3] << 16);
            H.z = hv[4] | (hv[5] << 16); H.w = hv[6] | (hv[7] << 16);
            L.x = lv[0] | (lv[1] << 16); L.y = lv[2] | (lv[3] << 16);
            L.z = lv[4] | (lv[5] << 16); L.w = lv[6] | (lv[7] << 16);
            if (!half) { *(uint4*)&AsH[sr][sg] = H; *(uint4*)&AsL[sr][sg] = L; }
            else       { *(uint4*)&BsH[sr][sg] = H; *(uint4*)&BsL[sr][sg] = L; }
        }
        __syncthreads();

        bf16x8s afH, afL, bfH[4], bfL[4];
        afH = *(const bf16x8s*)&AsH[wave * 16 + ln][quad * 8];
        afL = *(const bf16x8s*)&AsL[wave * 16 + ln][quad * 8];
#pragma unroll
        for (int nt = 0; nt < 4; ++nt) {
            bfH[nt] = *(const bf16x8s*)&BsH[nt * 16 + ln][quad * 8];
            bfL[nt] = *(const bf16x8s*)&BsL[nt * 16 + ln][quad * 8];
        }
#pragma unroll
        for (int nt = 0; nt < 4; ++nt) {
            acc[nt] = __builtin_amdgcn_mfma_f32_16x16x32_bf16(afH, bfH[nt], acc[nt], 0, 0, 0);
            acc[nt] = __builtin_amdgcn_mfma_f32_16x16x32_bf16(afH, bfL[nt], acc[nt], 0, 0, 0);
            acc[nt] = __builtin_amdgcn_mfma_f32_16x16x32_bf16(afL, bfH[nt], acc[nt], 0, 0, 0);
        }
    }

    const int gr0 = row0 + wave * 16 + quad * 4;
#pragma unroll
    for (int nt = 0; nt < 4; ++nt) {
        const int gc = col0 + nt * 16 + ln;
        float bb = bias[gc];
#pragma unroll
        for (int r = 0; r < 4; ++r)
            C[(long)(gr0 + r) * ldc + gc] = acc[nt][r] + bb;
    }
}

// ============ wt_fused: 64x64 tiles, W fp16 (both layouts) + partials + vT ============
__global__ __launch_bounds__(256) void wt_fused(const float* __restrict__ qkv,
                                                _Float16* __restrict__ Wh,
                                                _Float16* __restrict__ Wt,
                                                _Float16* __restrict__ vT,
                                                float* __restrict__ rsum,
                                                float* __restrict__ rsq,
                                                float* __restrict__ csum)
{
    __shared__ float qs[32][64];
    __shared__ float ks[32][64];
    __shared__ float colacc[64];
    int z = blockIdx.y;
    int b = z >> 3, h = z & 7;
    int t = threadIdx.x;
    int bx = blockIdx.x;
    long zo = (long)z * Ss * Ss;

    if (bx >= 64) {            // vT pack: half dh (d 32-chunk), all k
        float (*sT)[33] = (float(*)[33])qs;
        int dt = (bx - 64) * 32;
        int d = t & 31, kr = t >> 5;
        for (int kt = 0; kt < Ss; kt += 32) {
            __syncthreads();
#pragma unroll
            for (int p = 0; p < 4; ++p) {
                int kk = kr + p * 8;
                sT[kk][d] = qkv[(long)b * (Ss * 3 * DIM) + (long)(kt + kk) * (3 * DIM) + 2 * DIM + h * HD + dt + d];
            }
            __syncthreads();
#pragma unroll
            for (int p = 0; p < 4; ++p) {
                int dd = kr + p * 8;
                vT[(long)z * (HD * Ss) + (long)(dt + dd) * Ss + kt + d] = (_Float16)sT[d][dd];
            }
        }
        return;
    }

    int ti = bx >> 3, tj = bx & 7;
    int i0 = ti * 64, j0 = tj * 64;

    if (tj > ti) {             // fully-masked: zero only the partial slots
        if (t < 64) {
            rsum[((z * 8 + ti) * 512) + j0 + t] = 0.f;
            rsq [((z * 8 + ti) * 512) + j0 + t] = 0.f;
            csum[((z * 8 + tj) * 512) + i0 + t] = 0.f;
        }
        return;
    }

    int ia = (t & 15) * 4;
    int ja = (t >> 4) * 4;
    const float* qb = qkv + (long)b * Ss * (3 * DIM) + h * HD;
    const float* kb = qb + DIM;
    float acc[4][4] = {};

    for (int d0 = 0; d0 < 64; d0 += 32) {
        __syncthreads();
        int row = t & 63, dg = (t >> 6) * 8;
        float4 qv  = *(const float4*)&qb[(long)(i0 + row) * (3 * DIM) + d0 + dg];
        float4 qv2 = *(const float4*)&qb[(long)(i0 + row) * (3 * DIM) + d0 + dg + 4];
        float4 kv  = *(const float4*)&kb[(long)(j0 + row) * (3 * DIM) + d0 + dg];
        float4 kv2 = *(const float4*)&kb[(long)(j0 + row) * (3 * DIM) + d0 + dg + 4];
        qs[dg+0][row] = qv.x;  qs[dg+1][row] = qv.y;  qs[dg+2][row] = qv.z;  qs[dg+3][row] = qv.w;
        qs[dg+4][row] = qv2.x; qs[dg+5][row] = qv2.y; qs[dg+6][row] = qv2.z; qs[dg+7][row] = qv2.w;
        ks[dg+0][row] = kv.x;  ks[dg+1][row] = kv.y;  ks[dg+2][row] = kv.z;  ks[dg+3][row] = kv.w;
        ks[dg+4][row] = kv2.x; ks[dg+5][row] = kv2.y; ks[dg+6][row] = kv2.z; ks[dg+7][row] = kv2.w;
        __syncthreads();
#pragma unroll
        for (int d = 0; d < 32; ++d) {
            float4 q0 = *(const float4*)&qs[d][ia];
            float4 k0 = *(const float4*)&ks[d][ja];
            float qv_[4] = {q0.x, q0.y, q0.z, q0.w};
            float kv_[4] = {k0.x, k0.y, k0.z, k0.w};
#pragma unroll
            for (int aa = 0; aa < 4; ++aa)
#pragma unroll
                for (int c = 0; c < 4; ++c)
                    acc[aa][c] += fabsf(qv_[aa] - kv_[c]);
        }
    }

#pragma unroll
    for (int aa = 0; aa < 4; ++aa) {
        int i = i0 + ia + aa;
#pragma unroll
        for (int c = 0; c < 4; ++c) {
            int j = j0 + ja + c;
            float e = expf(-acc[aa][c] * 0.25f);
            acc[aa][c] = (j <= i) ? e : 0.0f;
        }
    }
    // Wt rows + per-j partials
#pragma unroll
    for (int c = 0; c < 4; ++c) {
        int j = j0 + ja + c;
        float rs = 0.f, rq = 0.f;
#pragma unroll
        for (int aa = 0; aa < 4; ++aa) { rs += acc[aa][c]; rq += acc[aa][c] * acc[aa][c]; }
        _Float16 ha[4] __attribute__((aligned(8))) = {(_Float16)acc[0][c], (_Float16)acc[1][c], (_Float16)acc[2][c], (_Float16)acc[3][c]};
        *(uint2*)&Wt[zo + (long)j * Ss + i0 + ia] = *(const uint2*)ha;
#pragma unroll
        for (int off = 8; off > 0; off >>= 1) {
            rs += __shfl_down(rs, off, 16);
            rq += __shfl_down(rq, off, 16);
        }
        if ((t & 15) == 0) {
            rsum[((z * 8 + ti) * 512) + j] = rs;
            rsq [((z * 8 + ti) * 512) + j] = rq;
        }
    }
    // Wh rows
#pragma unroll
    for (int aa = 0; aa < 4; ++aa) {
        int i = i0 + ia + aa;
        _Float16 hb[4] __attribute__((aligned(8))) = {(_Float16)acc[aa][0], (_Float16)acc[aa][1], (_Float16)acc[aa][2], (_Float16)acc[aa][3]};
        *(uint2*)&Wh[zo + (long)i * Ss + j0 + ja] = *(const uint2*)hb;
    }
    // per-i partials via LDS
    __syncthreads();
    if (t < 64) colacc[t] = 0.f;
    __syncthreads();
#pragma unroll
    for (int aa = 0; aa < 4; ++aa) {
        float cs = acc[aa][0] + acc[aa][1] + acc[aa][2] + acc[aa][3];
        atomicAdd(&colacc[ia + aa], cs);
    }
    __syncthreads();
    if (t < 64) csum[((z * 8 + tj) * 512) + i0 + t] = colacc[t];
}

// ============ fp16-A wide core, BK=64, LDS double-buffered (1 barrier / 64-K step) ============
__device__ __forceinline__ void wk_core(char* smc, const _Float16* A, const _Float16* B,
                                        long zA, long zB, int col0, int kbeg, int kend,
                                        f32x4* acc)
{
    _Float16 (*As0)[72] = (_Float16(*)[72])smc;
    _Float16 (*Bs0)[72] = (_Float16(*)[72])(smc + 9216);
    _Float16 (*As1)[72] = (_Float16(*)[72])(smc + 18432);
    _Float16 (*Bs1)[72] = (_Float16(*)[72])(smc + 27648);
    const int t = threadIdx.x;
    const int wave = t >> 6, lane = t & 63;
    const int ln = lane & 15, quad = lane >> 4;
    const int r2 = t >> 2, c2 = (t & 3) * 16;
    const long aoff = zA + (long)r2 * Ss;
    const long boff = zB + (long)(col0 + r2) * Ss;

    uint4 ua0 = *(const uint4*)&A[aoff + kbeg + c2];
    uint4 ua1 = *(const uint4*)&A[aoff + kbeg + c2 + 8];
    uint4 ub0 = *(const uint4*)&B[boff + kbeg + c2];
    uint4 ub1 = *(const uint4*)&B[boff + kbeg + c2 + 8];
    *(uint4*)&As0[r2][c2]     = ua0;
    *(uint4*)&As0[r2][c2 + 8] = ua1;
    *(uint4*)&Bs0[r2][c2]     = ub0;
    *(uint4*)&Bs0[r2][c2 + 8] = ub1;
    int cur = 0;
    for (int k0 = kbeg; k0 < kend; k0 += 64) {
        int kn = k0 + 64;
        if (kn < kend) {
            ua0 = *(const uint4*)&A[aoff + kn + c2];
            ua1 = *(const uint4*)&A[aoff + kn + c2 + 8];
            ub0 = *(const uint4*)&B[boff + kn + c2];
            ub1 = *(const uint4*)&B[boff + kn + c2 + 8];
        }
        __syncthreads();
        _Float16 (*As)[72] = cur ? As1 : As0;
        _Float16 (*Bs)[72] = cur ? Bs1 : Bs0;
#pragma unroll
        for (int kk = 0; kk < 64; kk += 32) {
            f16x8 af = *(const f16x8*)&As[wave * 16 + ln][quad * 8 + kk];
#pragma unroll
            for (int nt = 0; nt < 4; ++nt) {
                f16x8 bf = *(const f16x8*)&Bs[nt * 16 + ln][quad * 8 + kk];
                acc[nt] = __builtin_amdgcn_mfma_f32_16x16x32_f16(af, bf, acc[nt], 0, 0, 0);
            }
        }
        if (kn < kend) {
            _Float16 (*An)[72] = cur ? As0 : As1;
            _Float16 (*Bn)[72] = cur ? Bs0 : Bs1;
            *(uint4*)&An[r2][c2]     = ua0;
            *(uint4*)&An[r2][c2 + 8] = ua1;
            *(uint4*)&Bn[r2][c2]     = ub0;
            *(uint4*)&Bn[r2][c2 + 8] = ub1;
        }
        cur ^= 1;
    }
}

// ============ fp32-halves-A wide core, BK=32, double-buffered (VGPR-bounded) ============
template<int HASA1>
__device__ __forceinline__ void wk_core32(char* smc, const float* A0, const float* A1,
                                          const _Float16* B, long zA, long zB, int col0,
                                          int kbeg, int kend, f32x4* acc)
{
    _Float16 (*As0)[40] = (_Float16(*)[40])smc;
    _Float16 (*Bs0)[40] = (_Float16(*)[40])(smc + 5120);
    _Float16 (*As1)[40] = (_Float16(*)[40])(smc + 10240);
    _Float16 (*Bs1)[40] = (_Float16(*)[40])(smc + 15360);
    const int t = threadIdx.x;
    const int wave = t >> 6, lane = t & 63;
    const int ln = lane & 15, quad = lane >> 4;
    const int r4 = t >> 2, c4 = (t & 3) * 8;
    const long aoff = zA + (long)r4 * Ss;
    const long boff = zB + (long)(col0 + r4) * Ss;

    float4 p0 = *(const float4*)&A0[aoff + kbeg + c4];
    float4 p1 = *(const float4*)&A0[aoff + kbeg + c4 + 4];
    float4 q0, q1;
    if constexpr (HASA1) {
        q0 = *(const float4*)&A1[aoff + kbeg + c4];
        q1 = *(const float4*)&A1[aoff + kbeg + c4 + 4];
    }
    uint4 ub = *(const uint4*)&B[boff + kbeg + c4];
    {
        _Float16 hv[8] __attribute__((aligned(16)));
        if constexpr (HASA1) {
            hv[0] = (_Float16)(p0.x + q0.x); hv[1] = (_Float16)(p0.y + q0.y);
            hv[2] = (_Float16)(p0.z + q0.z); hv[3] = (_Float16)(p0.w + q0.w);
            hv[4] = (_Float16)(p1.x + q1.x); hv[5] = (_Float16)(p1.y + q1.y);
            hv[6] = (_Float16)(p1.z + q1.z); hv[7] = (_Float16)(p1.w + q1.w);
        } else {
            hv[0] = (_Float16)p0.x; hv[1] = (_Float16)p0.y;
            hv[2] = (_Float16)p0.z; hv[3] = (_Float16)p0.w;
            hv[4] = (_Float16)p1.x; hv[5] = (_Float16)p1.y;
            hv[6] = (_Float16)p1.z; hv[7] = (_Float16)p1.w;
        }
        *(uint4*)&As0[r4][c4] = *(const uint4*)hv;
        *(uint4*)&Bs0[r4][c4] = ub;
    }
    int cur = 0;
    for (int k0 = kbeg; k0 < kend; k0 += 32) {
        int kn = k0 + 32;
        if (kn < kend) {
            p0 = *(const float4*)&A0[aoff + kn + c4];
            p1 = *(const float4*)&A0[aoff + kn + c4 + 4];
            if constexpr (HASA1) {
                q0 = *(const float4*)&A1[aoff + kn + c4];
                q1 = *(const float4*)&A1[aoff + kn + c4 + 4];
            }
            ub = *(const uint4*)&B[boff + kn + c4];
        }
        __syncthreads();
        _Float16 (*As)[40] = cur ? As1 : As0;
        _Float16 (*Bs)[40] = cur ? Bs1 : Bs0;
        f16x8 af = *(const f16x8*)&As[wave * 16 + ln][quad * 8];
#pragma unroll
        for (int nt = 0; nt < 4; ++nt) {
            f16x8 bf = *(const f16x8*)&Bs[nt * 16 + ln][quad * 8];
            acc[nt] = __builtin_amdgcn_mfma_f32_16x16x32_f16(af, bf, acc[nt], 0, 0, 0);
        }
        if (kn < kend) {
            _Float16 hv[8] __attribute__((aligned(16)));
            if constexpr (HASA1) {
                hv[0] = (_Float16)(p0.x + q0.x); hv[1] = (_Float16)(p0.y + q0.y);
                hv[2] = (_Float16)(p0.z + q0.z); hv[3] = (_Float16)(p0.w + q0.w);
                hv[4] = (_Float16)(p1.x + q1.x); hv[5] = (_Float16)(p1.y + q1.y);
                hv[6] = (_Float16)(p1.z + q1.z); hv[7] = (_Float16)(p1.w + q1.w);
            } else {
                hv[0] = (_Float16)p0.x; hv[1] = (_Float16)p0.y;
                hv[2] = (_Float16)p0.z; hv[3] = (_Float16)p0.w;
                hv[4] = (_Float16)p1.x; hv[5] = (_Float16)p1.y;
                hv[6] = (_Float16)p1.z; hv[7] = (_Float16)p1.w;
            }
            _Float16 (*An)[40] = cur ? As0 : As1;
            _Float16 (*Bn)[40] = cur ? Bs0 : Bs1;
            *(uint4*)&An[r4][c4] = *(const uint4*)hv;
            *(uint4*)&Bn[r4][c4] = ub;
        }
        cur ^= 1;
    }
}

// ============ sym_core: 64x64 tile of A @ A^T, BK=64, double-buffered ============
__device__ __forceinline__ void sym_core(char* smc, const _Float16* A, long zo,
                                         int row0, int col0, int kend, f32x4* acc)
{
    _Float16 (*As0)[72] = (_Float16(*)[72])smc;
    _Float16 (*Bs0)[72] = (_Float16(*)[72])(smc + 9216);
    _Float16 (*As1)[72] = (_Float16(*)[72])(smc + 18432);
    _Float16 (*Bs1)[72] = (_Float16(*)[72])(smc + 27648);
    const int t = threadIdx.x;
    const int wave = t >> 6, lane = t & 63;
    const int ln = lane & 15, quad = lane >> 4;
    const int r2 = t >> 2, c2 = (t & 3) * 16;
    const long aoff = zo + (long)(row0 + r2) * Ss;
    const long boff = zo + (long)(col0 + r2) * Ss;
    uint4 ua0 = *(const uint4*)&A[aoff + c2];
    uint4 ua1 = *(const uint4*)&A[aoff + c2 + 8];
    uint4 ub0 = *(const uint4*)&A[boff + c2];
    uint4 ub1 = *(const uint4*)&A[boff + c2 + 8];
    *(uint4*)&As0[r2][c2]     = ua0;
    *(uint4*)&As0[r2][c2 + 8] = ua1;
    *(uint4*)&Bs0[r2][c2]     = ub0;
    *(uint4*)&Bs0[r2][c2 + 8] = ub1;
    int cur = 0;
    for (int k0 = 0; k0 < kend; k0 += 64) {
        int kn = k0 + 64;
        if (kn < kend) {
            ua0 = *(const uint4*)&A[aoff + kn + c2];
            ua1 = *(const uint4*)&A[aoff + kn + c2 + 8];
            ub0 = *(const uint4*)&A[boff + kn + c2];
            ub1 = *(const uint4*)&A[boff + kn + c2 + 8];
        }
        __syncthreads();
        _Float16 (*As)[72] = cur ? As1 : As0;
        _Float16 (*Bs)[72] = cur ? Bs1 : Bs0;
#pragma unroll
        for (int kk = 0; kk < 64; kk += 32) {
            f16x8 af = *(const f16x8*)&As[wave * 16 + ln][quad * 8 + kk];
#pragma unroll
            for (int nt = 0; nt < 4; ++nt) {
                f16x8 bf = *(const f16x8*)&Bs[nt * 16 + ln][quad * 8 + kk];
                acc[nt] = __builtin_amdgcn_mfma_f32_16x16x32_f16(af, bf, acc[nt], 0, 0, 0);
            }
        }
        if (kn < kend) {
            _Float16 (*An)[72] = cur ? As0 : As1;
            _Float16 (*Bn)[72] = cur ? Bs0 : Bs1;
            *(uint4*)&An[r2][c2]     = ua0;
            *(uint4*)&An[r2][c2 + 8] = ua1;
            *(uint4*)&Bn[r2][c2]     = ub0;
            *(uint4*)&Bn[r2][c2 + 8] = ub1;
        }
        cur ^= 1;
    }
}

// ============ sym_epilogue: coalesced dual-layout store of a 64x64 fp16 tile ============
__device__ __forceinline__ void sym_store_offdiag(char* smc, _Float16* T, long zo,
                                                  int row0, int col0,
                                                  const _Float16 (*ov)[4])
{
    _Float16 (*ltR)[72] = (_Float16(*)[72])smc;            // 9216 B
    _Float16 (*ltT)[72] = (_Float16(*)[72])(smc + 9216);   // 9216 B
    const int t = threadIdx.x;
    const int wave = t >> 6, lane = t & 63;
    const int ln = lane & 15, quad = lane >> 4;
    const int lr0 = wave * 16 + quad * 4;
    __syncthreads();                       // sym_core LDS reads complete
#pragma unroll
    for (int nt = 0; nt < 4; ++nt) {
        const int lc = nt * 16 + ln;
        *(uint2*)&ltT[lc][lr0] = *(const uint2*)ov[nt];
#pragma unroll
        for (int r = 0; r < 4; ++r)
            ltR[lr0 + r][lc] = ov[nt][r];
    }
    __syncthreads();
    const int tr = t >> 2, tcg = (t & 3) * 16;
    uint4 a0 = *(const uint4*)&ltR[tr][tcg];
    uint4 a1 = *(const uint4*)&ltR[tr][tcg + 8];
    _Float16* d0 = &T[zo + (long)(row0 + tr) * Ss + col0 + tcg];
    *(uint4*)&d0[0] = a0;
    *(uint4*)&d0[8] = a1;
    uint4 b0 = *(const uint4*)&ltT[tr][tcg];
    uint4 b1 = *(const uint4*)&ltT[tr][tcg + 8];
    _Float16* d1 = &T[zo + (long)(col0 + tr) * Ss + row0 + tcg];
    *(uint4*)&d1[0] = b0;
    *(uint4*)&d1[8] = b1;
}

// ============ mid_k: 0..127 y0 = vT x Wt; 128..143 scal; 144..151 stats; 152..727 U ============
__global__ __launch_bounds__(256) void mid_k(const _Float16* __restrict__ vT,
                                             const _Float16* __restrict__ Wt,
                                             float* __restrict__ y0,
                                             const float* __restrict__ rsum,
                                             const float* __restrict__ rsq,
                                             const float* __restrict__ csum,
                                             float* __restrict__ scal,
                                             float* __restrict__ mu,
                                             float* __restrict__ inv_sig,
                                             const _Float16* __restrict__ Wh,
                                             _Float16* __restrict__ U)
{
    __shared__ __align__(16) char sm[36864];
    int bx = blockIdx.x, t = threadIdx.x;
    if (bx < 128) {
        int z = bx >> 3, cc = bx & 7;
        int col0 = cc * 64;
        long zA = (long)z * (HD * Ss), zB = (long)z * Ss * Ss;
        f32x4 acc[4];
#pragma unroll
        for (int i = 0; i < 4; ++i) acc[i] = (f32x4){0.f, 0.f, 0.f, 0.f};
        wk_core(sm, vT, Wt, zA, zB, col0, col0, Ss, acc);
        const int wave = t >> 6, lane = t & 63;
        const int ln = lane & 15, quad = lane >> 4;
        const int gr = wave * 16 + quad * 4;
#pragma unroll
        for (int nt = 0; nt < 4; ++nt) {
            const int gc = col0 + nt * 16 + ln;
#pragma unroll
            for (int r = 0; r < 4; ++r)
                y0[zA + (long)(gr + r) * Ss + gc] = acc[nt][r];
        }
    } else if (bx < 144) {
        int z = bx - 128;
        float* s1 = (float*)sm;
        float* s2 = s1 + 256;
        float mx1 = 0.f, mx2 = 0.f;
        for (int jj = t; jj < 512; jj += 256) {
            float rs = 0.f, cs = 0.f;
#pragma unroll
            for (int ti = 0; ti < 8; ++ti) {
                rs += rsum[(z * 8 + ti) * 512 + jj];
                cs += csum[(z * 8 + ti) * 512 + jj];
            }
            mx1 = fmaxf(mx1, rs);
            mx2 = fmaxf(mx2, cs);
        }
        s1[t] = mx1; s2[t] = mx2;
        __syncthreads();
        for (int off = 128; off > 0; off >>= 1) {
            if (t < off) {
                s1[t] = fmaxf(s1[t], s1[t + off]);
                s2[t] = fmaxf(s2[t], s2[t + off]);
            }
            __syncthreads();
        }
        if (t == 0) scal[z] = 1.0f / (s1[0] * s2[0]);
    } else if (bx < 152) {
        int h = bx - 144;
        for (int jj = t; jj < 512; jj += 256) {
            float s = 0.f, q = 0.f;
#pragma unroll
            for (int b = 0; b < 2; ++b)
#pragma unroll
                for (int ti = 0; ti < 8; ++ti) {
                    int zz = b * 8 + h;
                    s += rsum[(zz * 8 + ti) * 512 + jj];
                    q += rsq [(zz * 8 + ti) * 512 + jj];
                }
            float m_ = s / 1024.f;
            float var = (q - s * s / 1024.f) / 1023.f;
            inv_sig[h * 512 + jj] = 1.0f / sqrtf(var + 1e-5f);
            mu[h * 512 + jj] = m_;
        }
    } else {
        // U = W @ W^T (unscaled, fp16), 36 lower 64-tiles + mirror per z
        int u = bx - 152;
        int z = u / 36;
        int tile = u - z * 36;
        const long zo = (long)z * Ss * Ss;
        const int ti = d_tIs[tile], tj = d_tJs[tile];
        const int row0 = ti * 64, col0 = tj * 64;
        f32x4 acc[4];
#pragma unroll
        for (int i = 0; i < 4; ++i) acc[i] = (f32x4){0.f, 0.f, 0.f, 0.f};
        sym_core(sm, Wh, zo, row0, col0, col0 + 64, acc);   // K truncated: W lower-tri
        const int wave = t >> 6, lane = t & 63;
        const int ln = lane & 15, quad = lane >> 4;
        _Float16 ov[4][4] __attribute__((aligned(8)));
#pragma unroll
        for (int nt = 0; nt < 4; ++nt)
#pragma unroll
            for (int r = 0; r < 4; ++r)
                ov[nt][r] = (_Float16)acc[nt][r];
        if (ti == tj) {
            const int gr0 = row0 + wave * 16 + quad * 4;
#pragma unroll
            for (int nt = 0; nt < 4; ++nt) {
                const int gc = col0 + nt * 16 + ln;
#pragma unroll
                for (int r = 0; r < 4; ++r)
                    U[zo + (long)(gr0 + r) * Ss + gc] = ov[nt][r];
            }
        } else {
            sym_store_offdiag(sm, U, zo, row0, col0, ov);
        }
    }
}

// ============ sq_k<FIRST>: fused T-squaring + y-update (commuting NS factors) ============
template<int FIRST>
__global__ __launch_bounds__(256) void sq_k(const _Float16* __restrict__ Tc,
                                            _Float16* __restrict__ Tn,
                                            const float* __restrict__ Y0,
                                            const float* __restrict__ Y1,
                                            float* __restrict__ O0,
                                            float* __restrict__ O1,
                                            const float* __restrict__ scal)
{
    __shared__ __align__(16) char sm[36864];
    const int z = blockIdx.y;
    const int t = threadIdx.x;
    const int wave = t >> 6, lane = t & 63;
    const int ln = lane & 15, quad = lane >> 4;

    if (blockIdx.x < 36) {
        const long zo = (long)z * Ss * Ss;
        const int ti = d_tIs[blockIdx.x], tj = d_tJs[blockIdx.x];
        const int row0 = ti * 64, col0 = tj * 64;
        f32x4 acc[4];
#pragma unroll
        for (int i = 0; i < 4; ++i) acc[i] = (f32x4){0.f, 0.f, 0.f, 0.f};
        sym_core(sm, Tc, zo, row0, col0, Ss, acc);
        const float s = FIRST ? scal[z] : 0.f;
        const int gr0 = row0 + wave * 16 + quad * 4;
        _Float16 ov[4][4] __attribute__((aligned(8)));
#pragma unroll
        for (int nt = 0; nt < 4; ++nt) {
            const int gc = col0 + nt * 16 + ln;
#pragma unroll
            for (int r = 0; r < 4; ++r) {
                const long gi = zo + (long)(gr0 + r) * Ss + gc;
                float val;
                if (FIRST) val = s * s * acc[nt][r] - 2.0f * s * (float)Tc[gi];
                else       val = 2.0f * (float)Tc[gi] + acc[nt][r];
                ov[nt][r] = (_Float16)val;
            }
        }
        if (ti == tj) {
#pragma unroll
            for (int nt = 0; nt < 4; ++nt) {
                const int gc = col0 + nt * 16 + ln;
#pragma unroll
                for (int r = 0; r < 4; ++r)
                    Tn[zo + (long)(gr0 + r) * Ss + gc] = ov[nt][r];
            }
        } else {
            sym_store_offdiag(sm, Tn, zo, row0, col0, ov);
        }
    } else {
        const int bx = blockIdx.x - 36;
        const int cc = bx & 7, kh = bx >> 3;
        const int col0 = cc * 64;
        const long zA = (long)z * (HD * Ss);
        const long zB = (long)z * Ss * Ss;
        f32x4 acc[4];
#pragma unroll
        for (int i = 0; i < 4; ++i) acc[i] = (f32x4){0.f, 0.f, 0.f, 0.f};
        wk_core32<FIRST ? 0 : 1>(sm, Y0, Y1, Tc, zA, zB, col0, kh * 256, kh * 256 + 256, acc);
        const float alpha = FIRST ? -scal[z] : 1.0f;
        float* O = kh ? O1 : O0;
        const int gr = wave * 16 + quad * 4;
#pragma unroll
        for (int nt = 0; nt < 4; ++nt) {
            const int gc = col0 + nt * 16 + ln;
#pragma unroll
            for (int r = 0; r < 4; ++r) {
                const long idx = zA + (long)(gr + r) * Ss + gc;
                float val = alpha * acc[nt][r];
                if (kh == 0) {
                    if (FIRST) val += 2.0f * Y0[idx];
                    else       val += 2.0f * (Y0[idx] + Y1[idx]);
                }
                O[idx] = val;
            }
        }
    }
}

// ============ yk_k: y' = 2*y + y x T, split-K=2, fp32 half-buffers ============
__global__ __launch_bounds__(256) void yk_k(const float* __restrict__ A0,
                                            const float* __restrict__ A1,
                                            const _Float16* __restrict__ T,
                                            float* __restrict__ O0,
                                            float* __restrict__ O1)
{
    __shared__ __align__(16) char sm[20480];
    const int z = blockIdx.y;
    const int cc = blockIdx.x & 7, kh = blockIdx.x >> 3;
    const int col0 = cc * 64;
    const long zA = (long)z * (HD * Ss);
    const long zB = (long)z * Ss * Ss;
    const int t = threadIdx.x;
    const int wave = t >> 6, lane = t & 63;
    const int ln = lane & 15, quad = lane >> 4;

    f32x4 acc[4];
#pragma unroll
    for (int i = 0; i < 4; ++i) acc[i] = (f32x4){0.f, 0.f, 0.f, 0.f};
    wk_core32<1>(sm, A0, A1, T, zA, zB, col0, kh * 256, kh * 256 + 256, acc);

    float* O = kh ? O1 : O0;
    const int gr = wave * 16 + quad * 4;
#pragma unroll
    for (int nt = 0; nt < 4; ++nt) {
        const int gc = col0 + nt * 16 + ln;
#pragma unroll
        for (int r = 0; r < 4; ++r) {
            const long idx = zA + (long)(gr + r) * Ss + gc;
            float val = acc[nt][r];
            if (kh == 0) val += 2.0f * (A0[idx] + A1[idx]);
            O[idx] = val;
        }
    }
}

// ============ c2s_k: c2sT = inv_sig[n]*s*(y x Wt) + negoff partials ============
__global__ __launch_bounds__(256) void c2s_k(const float* __restrict__ A0,
                                             const float* __restrict__ A1,
                                             const _Float16* __restrict__ Wt,
                                             _Float16* __restrict__ c2sT,
                                             const float* __restrict__ scal,
                                             const float* __restrict__ inv_sig,
                                             const float* __restrict__ mu,
                                             float* __restrict__ negopart)
{
    __shared__ __align__(16) char sm[20480];
    __shared__ float red[64];
    const int z = blockIdx.y;
    const int h = z & 7;
    const int col0 = blockIdx.x * 64;
    const long zA = (long)z * (HD * Ss);
    const long zB = (long)z * Ss * Ss;
    const int t = threadIdx.x;
    const int wave = t >> 6, lane = t & 63;
    const int ln = lane & 15, quad = lane >> 4;

    f32x4 acc[4];
#pragma unroll
    for (int i = 0; i < 4; ++i) acc[i] = (f32x4){0.f, 0.f, 0.f, 0.f};
    wk_core32<1>(sm, A0, A1, Wt, zA, zB, col0, col0, Ss, acc);

    if (t < 64) red[t] = 0.f;
    __syncthreads();
    const int gr = wave * 16 + quad * 4;
    float pr[4] = {0.f, 0.f, 0.f, 0.f};
    float s = scal[z];
#pragma unroll
    for (int nt = 0; nt < 4; ++nt) {
        const int gc = col0 + nt * 16 + ln;
#pragma unroll
        for (int r = 0; r < 4; ++r) {
            float val = inv_sig[h * 512 + gc] * (s * acc[nt][r]);
            pr[r] += mu[h * 512 + gc] * val;
            c2sT[zA + (long)(gr + r) * Ss + gc] = (_Float16)val;
        }
    }
#pragma unroll
    for (int r = 0; r < 4; ++r)
        atomicAdd(&red[gr + r], pr[r]);
    __syncthreads();
    if (t < 64)
        negopart[(z * 8 + blockIdx.x) * 64 + t] = red[t];
}

// ============ ga_k: gat = Wh @ c2s - neg, fp32 out in [B,S,DIM] ============
__global__ __launch_bounds__(256) void ga_k(const _Float16* __restrict__ Wh,
                                            const _Float16* __restrict__ c2sT,
                                            const float* __restrict__ negopart,
                                            float* __restrict__ gat)
{
    __shared__ __align__(16) char sm[36864];
    __shared__ float neg[64];
    const int z = blockIdx.y;
    const int b = z >> 3, h = z & 7;
    const int m0 = blockIdx.x * 64;
    const long zA = (long)z * Ss * Ss;
    const long zB = (long)z * (HD * Ss);
    const int t = threadIdx.x;
    const int wave = t >> 6, lane = t & 63;
    const int ln = lane & 15, quad = lane >> 4;

    if (t < 64) {
        float s = 0.f;
#pragma unroll
        for (int k = 0; k < 8; ++k) s += negopart[(z * 8 + k) * 64 + t];
        neg[t] = s;
    }
    __syncthreads();

    f32x4 acc[4];
#pragma unroll
    for (int i = 0; i < 4; ++i) acc[i] = (f32x4){0.f, 0.f, 0.f, 0.f};
    wk_core(sm, c2sT, Wh, zB, zA, m0, 0, m0 + 64, acc);

    const int gr = wave * 16 + quad * 4;   // d index
#pragma unroll
    for (int nt = 0; nt < 4; ++nt) {
        const int m = m0 + nt * 16 + ln;
#pragma unroll
        for (int r = 0; r < 4; ++r) {
            const int d = gr + r;
            gat[(long)b * (Ss * DIM) + (long)m * DIM + h * HD + d] = acc[nt][r] - neg[d];
        }
    }
}

extern "C" void kernel_launch(void* const* d_in, const int* in_sizes, int n_in,
                              void* d_out, int out_size, void* d_ws, size_t ws_size,
                              hipStream_t stream)
{
    const float* x      = (const float*)d_in[0];
    const float* qkv_w  = (const float*)d_in[1];
    const float* qkv_b  = (const float*)d_in[2];
    const float* proj_w = (const float*)d_in[3];
    const float* proj_b = (const float*)d_in[4];
    float* out = (float*)d_out;
    float* ws  = (float*)d_ws;

    float* qkv     = ws;
    _Float16* Wh   = (_Float16*)(ws + 1572864);
    _Float16* Wt   = (_Float16*)(ws + 3670016);
    _Float16* vT   = (_Float16*)(ws + 5767168);
    _Float16* T[5];
    for (int i = 0; i < 5; ++i) T[i] = (_Float16*)(ws + 6029312 + (long)i * 2097152);
    float* Ya0 = ws + 16515072;   // fp32 y half-buffers, 524288 f each
    float* Ya1 = ws + 17039360;
    float* Yb0 = ws + 17563648;
    float* Yb1 = ws + 18087936;
    _Float16* c2sT = (_Float16*)(ws + 19136512);
    float* rsum    = ws + 19398656;   // 65536
    float* rsq     = ws + 19464192;   // 65536
    float* csum    = ws + 19529728;   // 65536
    float* scal    = ws + 19595264;   // 16
    float* mu      = ws + 19595280;   // 4096
    float* inv_sig = ws + 19599376;   // 4096
    float* negp    = ws + 19603472;   // 8192
    float* gat     = ws + 19611664;   // 524288

    dim3 blk(256);

    // 1. qkv = x @ qkv_w^T + qkv_b  (64x64 tiles: 384 blocks)
    mm64_k<<<dim3(24, 16), blk, 0, stream>>>(x, qkv_w, qkv_b, qkv, DIM, 3 * DIM);

    // 2. W fp16 (both layouts, 64-tiles) + reduction partials + vT
    wt_fused<<<dim3(66, 16), blk, 0, stream>>>(qkv, Wh, Wt, vT, rsum, rsq, csum);

    // 3. y0 = vT x Wt || scale || whitening stats || U = W W^T (unscaled)
    mid_k<<<dim3(728), blk, 0, stream>>>(vT, Wt, Ya0, rsum, rsq, csum, scal, mu, inv_sig,
                                         Wh, T[0]);

    // 4-7. fused NS steps (ascending k; factors commute):
    //      T1 = s^2 U U - 2 s U   || y1 = 2 y0 - s y0 U
    //      T_{k+1} = 2 T_k + T_k^2 || y_{k+1} = 2 y_k + y_k T_k
    sq_k<1><<<dim3(52, 16), blk, 0, stream>>>(T[0], T[1], Ya0, nullptr, Yb0, Yb1, scal);
    sq_k<0><<<dim3(52, 16), blk, 0, stream>>>(T[1], T[2], Yb0, Yb1,     Ya0, Ya1, scal);
    sq_k<0><<<dim3(52, 16), blk, 0, stream>>>(T[2], T[3], Ya0, Ya1,     Yb0, Yb1, scal);
    sq_k<0><<<dim3(52, 16), blk, 0, stream>>>(T[3], T[4], Yb0, Yb1,     Ya0, Ya1, scal);

    // 8. final y update with T4
    yk_k<<<dim3(16, 16), blk, 0, stream>>>(Ya0, Ya1, T[4], Yb0, Yb1);

    // 9. c2sT = inv_sig * s * (y W) + negoff partials
    c2s_k<<<dim3(8, 16), blk, 0, stream>>>(Yb0, Yb1, Wt, c2sT, scal, inv_sig, mu, negp);

    // 10. gat = W @ c2s - neg
    ga_k<<<dim3(8, 16), blk, 0, stream>>>(Wh, c2sT, negp, gat);

    // 11. out = gat @ proj_w^T + proj_b  (64x64 tiles: 128 blocks)
    mm64_k<<<dim3(8, 16), blk, 0, stream>>>(gat, proj_w, proj_b, out, DIM, DIM);
}

// Round 11
// 202.078 us; speedup vs baseline: 1.4590x; 1.1984x over previous
//
#include <hip/hip_runtime.h>

#define Bq 2
#define Hh 8
#define Ss 512
#define HD 64
#define DIM 512

using f32x4   = __attribute__((ext_vector_type(4))) float;
using bf16x8s = __attribute__((ext_vector_type(8))) short;
typedef _Float16 f16x8 __attribute__((ext_vector_type(8)));

__constant__ int d_tIs[36] = {0,1,1,2,2,2,3,3,3,3,4,4,4,4,4,5,5,5,5,5,5,6,6,6,6,6,6,6,7,7,7,7,7,7,7,7};
__constant__ int d_tJs[36] = {0,0,1,0,1,2,0,1,2,3,0,1,2,3,4,0,1,2,3,4,5,0,1,2,3,4,5,6,0,1,2,3,4,5,6,7};

__device__ __forceinline__ float bf2f(unsigned short u) {
    return __uint_as_float(((unsigned int)u) << 16);
}
__device__ __forceinline__ unsigned short f2bf(float f) {
    unsigned int u = __float_as_uint(f);
    u = (u + 0x7FFFu + ((u >> 16) & 1u)) >> 16;   // RNE
    return (unsigned short)u;
}

// ============ mm64_k: C = A @ B^T + bias (fp32 io, split bf16x2 MFMA, 64x64 tiles) ============
__global__ __launch_bounds__(256) void mm64_k(
    const float* __restrict__ A, const float* __restrict__ B,
    const float* __restrict__ bias, float* __restrict__ C,
    int K, int ldc)
{
    const int row0 = blockIdx.y * 64, col0 = blockIdx.x * 64;
    __shared__ unsigned short AsH[64][40], AsL[64][40];
    __shared__ unsigned short BsH[64][40], BsL[64][40];
    const int t = threadIdx.x;
    const int wave = t >> 6, lane = t & 63;
    const int ln = lane & 15, quad = lane >> 4;

    f32x4 acc[4];
#pragma unroll
    for (int i = 0; i < 4; ++i) acc[i] = (f32x4){0.f, 0.f, 0.f, 0.f};

    const int sr = t >> 2, sg = (t & 3) * 8;

    for (int k0 = 0; k0 < K; k0 += 32) {
        __syncthreads();
#pragma unroll
        for (int half = 0; half < 2; ++half) {
            const float* src = half ? B : A;
            int base = half ? col0 : row0;
            const float* p = &src[(long)(base + sr) * K + k0 + sg];
            float4 f0 = *(const float4*)p;
            float4 f1 = *(const float4*)(p + 4);
            float fv[8] = {f0.x, f0.y, f0.z, f0.w, f1.x, f1.y, f1.z, f1.w};
            unsigned short hv[8], lv[8];
#pragma unroll
            for (int e = 0; e < 8; ++e) {
                hv[e] = f2bf(fv[e]);
                lv[e] = f2bf(fv[e] - bf2f(hv[e]));
            }
            uint4 H, L;
            H.x = hv[0] | (hv[1] << 16); H.y = hv[2] | (hv[3] << 16);
            H.z = hv[4] | (hv[5] << 16); H.w = hv[6] | (hv[7] << 16);
            L.x = lv[0] | (lv[1] << 16); L.y = lv[2] | (lv[3] << 16);
            L.z = lv[4] | (lv[5] << 16); L.w = lv[6] | (lv[7] << 16);
            if (!half) { *(uint4*)&AsH[sr][sg] = H; *(uint4*)&AsL[sr][sg] = L; }
            else       { *(uint4*)&BsH[sr][sg] = H; *(uint4*)&BsL[sr][sg] = L; }
        }
        __syncthreads();

        bf16x8s afH, afL, bfH[4], bfL[4];
        afH = *(const bf16x8s*)&AsH[wave * 16 + ln][quad * 8];
        afL = *(const bf16x8s*)&AsL[wave * 16 + ln][quad * 8];
#pragma unroll
        for (int nt = 0; nt < 4; ++nt) {
            bfH[nt] = *(const bf16x8s*)&BsH[nt * 16 + ln][quad * 8];
            bfL[nt] = *(const bf16x8s*)&BsL[nt * 16 + ln][quad * 8];
        }
#pragma unroll
        for (int nt = 0; nt < 4; ++nt) {
            acc[nt] = __builtin_amdgcn_mfma_f32_16x16x32_bf16(afH, bfH[nt], acc[nt], 0, 0, 0);
            acc[nt] = __builtin_amdgcn_mfma_f32_16x16x32_bf16(afH, bfL[nt], acc[nt], 0, 0, 0);
            acc[nt] = __builtin_amdgcn_mfma_f32_16x16x32_bf16(afL, bfH[nt], acc[nt], 0, 0, 0);
        }
    }

    const int gr0 = row0 + wave * 16 + quad * 4;
#pragma unroll
    for (int nt = 0; nt < 4; ++nt) {
        const int gc = col0 + nt * 16 + ln;
        float bb = bias[gc];
#pragma unroll
        for (int r = 0; r < 4; ++r)
            C[(long)(gr0 + r) * ldc + gc] = acc[nt][r] + bb;
    }
}

// ============ wt_fused: 64x64 tiles, W fp16 (both layouts) + partials + vT ============
__global__ __launch_bounds__(256) void wt_fused(const float* __restrict__ qkv,
                                                _Float16* __restrict__ Wh,
                                                _Float16* __restrict__ Wt,
                                                _Float16* __restrict__ vT,
                                                float* __restrict__ rsum,
                                                float* __restrict__ rsq,
                                                float* __restrict__ csum)
{
    __shared__ float qs[32][64];
    __shared__ float ks[32][64];
    __shared__ float colacc[64];
    int z = blockIdx.y;
    int b = z >> 3, h = z & 7;
    int t = threadIdx.x;
    int bx = blockIdx.x;
    long zo = (long)z * Ss * Ss;

    if (bx >= 64) {            // vT pack: half dh (d 32-chunk), all k
        float (*sT)[33] = (float(*)[33])qs;
        int dt = (bx - 64) * 32;
        int d = t & 31, kr = t >> 5;
        for (int kt = 0; kt < Ss; kt += 32) {
            __syncthreads();
#pragma unroll
            for (int p = 0; p < 4; ++p) {
                int kk = kr + p * 8;
                sT[kk][d] = qkv[(long)b * (Ss * 3 * DIM) + (long)(kt + kk) * (3 * DIM) + 2 * DIM + h * HD + dt + d];
            }
            __syncthreads();
#pragma unroll
            for (int p = 0; p < 4; ++p) {
                int dd = kr + p * 8;
                vT[(long)z * (HD * Ss) + (long)(dt + dd) * Ss + kt + d] = (_Float16)sT[d][dd];
            }
        }
        return;
    }

    int ti = bx >> 3, tj = bx & 7;
    int i0 = ti * 64, j0 = tj * 64;

    if (tj > ti) {             // fully-masked: zero only the partial slots
        if (t < 64) {
            rsum[((z * 8 + ti) * 512) + j0 + t] = 0.f;
            rsq [((z * 8 + ti) * 512) + j0 + t] = 0.f;
            csum[((z * 8 + tj) * 512) + i0 + t] = 0.f;
        }
        return;
    }

    int ia = (t & 15) * 4;
    int ja = (t >> 4) * 4;
    const float* qb = qkv + (long)b * Ss * (3 * DIM) + h * HD;
    const float* kb = qb + DIM;
    float acc[4][4] = {};

    for (int d0 = 0; d0 < 64; d0 += 32) {
        __syncthreads();
        int row = t & 63, dg = (t >> 6) * 8;
        float4 qv  = *(const float4*)&qb[(long)(i0 + row) * (3 * DIM) + d0 + dg];
        float4 qv2 = *(const float4*)&qb[(long)(i0 + row) * (3 * DIM) + d0 + dg + 4];
        float4 kv  = *(const float4*)&kb[(long)(j0 + row) * (3 * DIM) + d0 + dg];
        float4 kv2 = *(const float4*)&kb[(long)(j0 + row) * (3 * DIM) + d0 + dg + 4];
        qs[dg+0][row] = qv.x;  qs[dg+1][row] = qv.y;  qs[dg+2][row] = qv.z;  qs[dg+3][row] = qv.w;
        qs[dg+4][row] = qv2.x; qs[dg+5][row] = qv2.y; qs[dg+6][row] = qv2.z; qs[dg+7][row] = qv2.w;
        ks[dg+0][row] = kv.x;  ks[dg+1][row] = kv.y;  ks[dg+2][row] = kv.z;  ks[dg+3][row] = kv.w;
        ks[dg+4][row] = kv2.x; ks[dg+5][row] = kv2.y; ks[dg+6][row] = kv2.z; ks[dg+7][row] = kv2.w;
        __syncthreads();
#pragma unroll
        for (int d = 0; d < 32; ++d) {
            float4 q0 = *(const float4*)&qs[d][ia];
            float4 k0 = *(const float4*)&ks[d][ja];
            float qv_[4] = {q0.x, q0.y, q0.z, q0.w};
            float kv_[4] = {k0.x, k0.y, k0.z, k0.w};
#pragma unroll
            for (int aa = 0; aa < 4; ++aa)
#pragma unroll
                for (int c = 0; c < 4; ++c)
                    acc[aa][c] += fabsf(qv_[aa] - kv_[c]);
        }
    }

#pragma unroll
    for (int aa = 0; aa < 4; ++aa) {
        int i = i0 + ia + aa;
#pragma unroll
        for (int c = 0; c < 4; ++c) {
            int j = j0 + ja + c;
            float e = expf(-acc[aa][c] * 0.25f);
            acc[aa][c] = (j <= i) ? e : 0.0f;
        }
    }
    // Wt rows + per-j partials
#pragma unroll
    for (int c = 0; c < 4; ++c) {
        int j = j0 + ja + c;
        float rs = 0.f, rq = 0.f;
#pragma unroll
        for (int aa = 0; aa < 4; ++aa) { rs += acc[aa][c]; rq += acc[aa][c] * acc[aa][c]; }
        _Float16 ha[4] __attribute__((aligned(8))) = {(_Float16)acc[0][c], (_Float16)acc[1][c], (_Float16)acc[2][c], (_Float16)acc[3][c]};
        *(uint2*)&Wt[zo + (long)j * Ss + i0 + ia] = *(const uint2*)ha;
#pragma unroll
        for (int off = 8; off > 0; off >>= 1) {
            rs += __shfl_down(rs, off, 16);
            rq += __shfl_down(rq, off, 16);
        }
        if ((t & 15) == 0) {
            rsum[((z * 8 + ti) * 512) + j] = rs;
            rsq [((z * 8 + ti) * 512) + j] = rq;
        }
    }
    // Wh rows
#pragma unroll
    for (int aa = 0; aa < 4; ++aa) {
        int i = i0 + ia + aa;
        _Float16 hb[4] __attribute__((aligned(8))) = {(_Float16)acc[aa][0], (_Float16)acc[aa][1], (_Float16)acc[aa][2], (_Float16)acc[aa][3]};
        *(uint2*)&Wh[zo + (long)i * Ss + j0 + ja] = *(const uint2*)hb;
    }
    // per-i partials via LDS
    __syncthreads();
    if (t < 64) colacc[t] = 0.f;
    __syncthreads();
#pragma unroll
    for (int aa = 0; aa < 4; ++aa) {
        float cs = acc[aa][0] + acc[aa][1] + acc[aa][2] + acc[aa][3];
        atomicAdd(&colacc[ia + aa], cs);
    }
    __syncthreads();
    if (t < 64) csum[((z * 8 + tj) * 512) + i0 + t] = colacc[t];
}

// ============ fp16-A wide core, BK=64, LDS double-buffered (1 barrier / 64-K step) ============
__device__ __forceinline__ void wk_core(char* smc, const _Float16* A, const _Float16* B,
                                        long zA, long zB, int col0, int kbeg, int kend,
                                        f32x4* acc)
{
    _Float16 (*As0)[72] = (_Float16(*)[72])smc;
    _Float16 (*Bs0)[72] = (_Float16(*)[72])(smc + 9216);
    _Float16 (*As1)[72] = (_Float16(*)[72])(smc + 18432);
    _Float16 (*Bs1)[72] = (_Float16(*)[72])(smc + 27648);
    const int t = threadIdx.x;
    const int wave = t >> 6, lane = t & 63;
    const int ln = lane & 15, quad = lane >> 4;
    const int r2 = t >> 2, c2 = (t & 3) * 16;
    const long aoff = zA + (long)r2 * Ss;
    const long boff = zB + (long)(col0 + r2) * Ss;

    uint4 ua0 = *(const uint4*)&A[aoff + kbeg + c2];
    uint4 ua1 = *(const uint4*)&A[aoff + kbeg + c2 + 8];
    uint4 ub0 = *(const uint4*)&B[boff + kbeg + c2];
    uint4 ub1 = *(const uint4*)&B[boff + kbeg + c2 + 8];
    *(uint4*)&As0[r2][c2]     = ua0;
    *(uint4*)&As0[r2][c2 + 8] = ua1;
    *(uint4*)&Bs0[r2][c2]     = ub0;
    *(uint4*)&Bs0[r2][c2 + 8] = ub1;
    int cur = 0;
    for (int k0 = kbeg; k0 < kend; k0 += 64) {
        int kn = k0 + 64;
        if (kn < kend) {
            ua0 = *(const uint4*)&A[aoff + kn + c2];
            ua1 = *(const uint4*)&A[aoff + kn + c2 + 8];
            ub0 = *(const uint4*)&B[boff + kn + c2];
            ub1 = *(const uint4*)&B[boff + kn + c2 + 8];
        }
        __syncthreads();
        _Float16 (*As)[72] = cur ? As1 : As0;
        _Float16 (*Bs)[72] = cur ? Bs1 : Bs0;
#pragma unroll
        for (int kk = 0; kk < 64; kk += 32) {
            f16x8 af = *(const f16x8*)&As[wave * 16 + ln][quad * 8 + kk];
#pragma unroll
            for (int nt = 0; nt < 4; ++nt) {
                f16x8 bf = *(const f16x8*)&Bs[nt * 16 + ln][quad * 8 + kk];
                acc[nt] = __builtin_amdgcn_mfma_f32_16x16x32_f16(af, bf, acc[nt], 0, 0, 0);
            }
        }
        if (kn < kend) {
            _Float16 (*An)[72] = cur ? As0 : As1;
            _Float16 (*Bn)[72] = cur ? Bs0 : Bs1;
            *(uint4*)&An[r2][c2]     = ua0;
            *(uint4*)&An[r2][c2 + 8] = ua1;
            *(uint4*)&Bn[r2][c2]     = ub0;
            *(uint4*)&Bn[r2][c2 + 8] = ub1;
        }
        cur ^= 1;
    }
}

// ============ fp32-halves-A wide core, BK=32, double-buffered (VGPR-bounded) ============
template<int HASA1>
__device__ __forceinline__ void wk_core32(char* smc, const float* A0, const float* A1,
                                          const _Float16* B, long zA, long zB, int col0,
                                          int kbeg, int kend, f32x4* acc)
{
    _Float16 (*As0)[40] = (_Float16(*)[40])smc;
    _Float16 (*Bs0)[40] = (_Float16(*)[40])(smc + 5120);
    _Float16 (*As1)[40] = (_Float16(*)[40])(smc + 10240);
    _Float16 (*Bs1)[40] = (_Float16(*)[40])(smc + 15360);
    const int t = threadIdx.x;
    const int wave = t >> 6, lane = t & 63;
    const int ln = lane & 15, quad = lane >> 4;
    const int r4 = t >> 2, c4 = (t & 3) * 8;
    const long aoff = zA + (long)r4 * Ss;
    const long boff = zB + (long)(col0 + r4) * Ss;

    float4 p0 = *(const float4*)&A0[aoff + kbeg + c4];
    float4 p1 = *(const float4*)&A0[aoff + kbeg + c4 + 4];
    float4 q0, q1;
    if constexpr (HASA1) {
        q0 = *(const float4*)&A1[aoff + kbeg + c4];
        q1 = *(const float4*)&A1[aoff + kbeg + c4 + 4];
    }
    uint4 ub = *(const uint4*)&B[boff + kbeg + c4];
    {
        _Float16 hv[8] __attribute__((aligned(16)));
        if constexpr (HASA1) {
            hv[0] = (_Float16)(p0.x + q0.x); hv[1] = (_Float16)(p0.y + q0.y);
            hv[2] = (_Float16)(p0.z + q0.z); hv[3] = (_Float16)(p0.w + q0.w);
            hv[4] = (_Float16)(p1.x + q1.x); hv[5] = (_Float16)(p1.y + q1.y);
            hv[6] = (_Float16)(p1.z + q1.z); hv[7] = (_Float16)(p1.w + q1.w);
        } else {
            hv[0] = (_Float16)p0.x; hv[1] = (_Float16)p0.y;
            hv[2] = (_Float16)p0.z; hv[3] = (_Float16)p0.w;
            hv[4] = (_Float16)p1.x; hv[5] = (_Float16)p1.y;
            hv[6] = (_Float16)p1.z; hv[7] = (_Float16)p1.w;
        }
        *(uint4*)&As0[r4][c4] = *(const uint4*)hv;
        *(uint4*)&Bs0[r4][c4] = ub;
    }
    int cur = 0;
    for (int k0 = kbeg; k0 < kend; k0 += 32) {
        int kn = k0 + 32;
        if (kn < kend) {
            p0 = *(const float4*)&A0[aoff + kn + c4];
            p1 = *(const float4*)&A0[aoff + kn + c4 + 4];
            if constexpr (HASA1) {
                q0 = *(const float4*)&A1[aoff + kn + c4];
                q1 = *(const float4*)&A1[aoff + kn + c4 + 4];
            }
            ub = *(const uint4*)&B[boff + kn + c4];
        }
        __syncthreads();
        _Float16 (*As)[40] = cur ? As1 : As0;
        _Float16 (*Bs)[40] = cur ? Bs1 : Bs0;
        f16x8 af = *(const f16x8*)&As[wave * 16 + ln][quad * 8];
#pragma unroll
        for (int nt = 0; nt < 4; ++nt) {
            f16x8 bf = *(const f16x8*)&Bs[nt * 16 + ln][quad * 8];
            acc[nt] = __builtin_amdgcn_mfma_f32_16x16x32_f16(af, bf, acc[nt], 0, 0, 0);
        }
        if (kn < kend) {
            _Float16 hv[8] __attribute__((aligned(16)));
            if constexpr (HASA1) {
                hv[0] = (_Float16)(p0.x + q0.x); hv[1] = (_Float16)(p0.y + q0.y);
                hv[2] = (_Float16)(p0.z + q0.z); hv[3] = (_Float16)(p0.w + q0.w);
                hv[4] = (_Float16)(p1.x + q1.x); hv[5] = (_Float16)(p1.y + q1.y);
                hv[6] = (_Float16)(p1.z + q1.z); hv[7] = (_Float16)(p1.w + q1.w);
            } else {
                hv[0] = (_Float16)p0.x; hv[1] = (_Float16)p0.y;
                hv[2] = (_Float16)p0.z; hv[3] = (_Float16)p0.w;
                hv[4] = (_Float16)p1.x; hv[5] = (_Float16)p1.y;
                hv[6] = (_Float16)p1.z; hv[7] = (_Float16)p1.w;
            }
            _Float16 (*An)[40] = cur ? As0 : As1;
            _Float16 (*Bn)[40] = cur ? Bs0 : Bs1;
            *(uint4*)&An[r4][c4] = *(const uint4*)hv;
            *(uint4*)&Bn[r4][c4] = ub;
        }
        cur ^= 1;
    }
}

// ============ sym_core: 64x64 tile of A @ A^T, BK=64, double-buffered ============
__device__ __forceinline__ void sym_core(char* smc, const _Float16* A, long zo,
                                         int row0, int col0, int kend, f32x4* acc)
{
    _Float16 (*As0)[72] = (_Float16(*)[72])smc;
    _Float16 (*Bs0)[72] = (_Float16(*)[72])(smc + 9216);
    _Float16 (*As1)[72] = (_Float16(*)[72])(smc + 18432);
    _Float16 (*Bs1)[72] = (_Float16(*)[72])(smc + 27648);
    const int t = threadIdx.x;
    const int wave = t >> 6, lane = t & 63;
    const int ln = lane & 15, quad = lane >> 4;
    const int r2 = t >> 2, c2 = (t & 3) * 16;
    const long aoff = zo + (long)(row0 + r2) * Ss;
    const long boff = zo + (long)(col0 + r2) * Ss;
    uint4 ua0 = *(const uint4*)&A[aoff + c2];
    uint4 ua1 = *(const uint4*)&A[aoff + c2 + 8];
    uint4 ub0 = *(const uint4*)&A[boff + c2];
    uint4 ub1 = *(const uint4*)&A[boff + c2 + 8];
    *(uint4*)&As0[r2][c2]     = ua0;
    *(uint4*)&As0[r2][c2 + 8] = ua1;
    *(uint4*)&Bs0[r2][c2]     = ub0;
    *(uint4*)&Bs0[r2][c2 + 8] = ub1;
    int cur = 0;
    for (int k0 = 0; k0 < kend; k0 += 64) {
        int kn = k0 + 64;
        if (kn < kend) {
            ua0 = *(const uint4*)&A[aoff + kn + c2];
            ua1 = *(const uint4*)&A[aoff + kn + c2 + 8];
            ub0 = *(const uint4*)&A[boff + kn + c2];
            ub1 = *(const uint4*)&A[boff + kn + c2 + 8];
        }
        __syncthreads();
        _Float16 (*As)[72] = cur ? As1 : As0;
        _Float16 (*Bs)[72] = cur ? Bs1 : Bs0;
#pragma unroll
        for (int kk = 0; kk < 64; kk += 32) {
            f16x8 af = *(const f16x8*)&As[wave * 16 + ln][quad * 8 + kk];
#pragma unroll
            for (int nt = 0; nt < 4; ++nt) {
                f16x8 bf = *(const f16x8*)&Bs[nt * 16 + ln][quad * 8 + kk];
                acc[nt] = __builtin_amdgcn_mfma_f32_16x16x32_f16(af, bf, acc[nt], 0, 0, 0);
            }
        }
        if (kn < kend) {
            _Float16 (*An)[72] = cur ? As0 : As1;
            _Float16 (*Bn)[72] = cur ? Bs0 : Bs1;
            *(uint4*)&An[r2][c2]     = ua0;
            *(uint4*)&An[r2][c2 + 8] = ua1;
            *(uint4*)&Bn[r2][c2]     = ub0;
            *(uint4*)&Bn[r2][c2 + 8] = ub1;
        }
        cur ^= 1;
    }
}

// ============ sym_epilogue: coalesced dual-layout store of a 64x64 fp16 tile ============
__device__ __forceinline__ void sym_store_offdiag(char* smc, _Float16* T, long zo,
                                                  int row0, int col0,
                                                  const _Float16 (*ov)[4])
{
    _Float16 (*ltR)[72] = (_Float16(*)[72])smc;            // 9216 B
    _Float16 (*ltT)[72] = (_Float16(*)[72])(smc + 9216);   // 9216 B
    const int t = threadIdx.x;
    const int wave = t >> 6, lane = t & 63;
    const int ln = lane & 15, quad = lane >> 4;
    const int lr0 = wave * 16 + quad * 4;
    __syncthreads();                       // sym_core LDS reads complete
#pragma unroll
    for (int nt = 0; nt < 4; ++nt) {
        const int lc = nt * 16 + ln;
        *(uint2*)&ltT[lc][lr0] = *(const uint2*)ov[nt];
#pragma unroll
        for (int r = 0; r < 4; ++r)
            ltR[lr0 + r][lc] = ov[nt][r];
    }
    __syncthreads();
    const int tr = t >> 2, tcg = (t & 3) * 16;
    uint4 a0 = *(const uint4*)&ltR[tr][tcg];
    uint4 a1 = *(const uint4*)&ltR[tr][tcg + 8];
    _Float16* d0 = &T[zo + (long)(row0 + tr) * Ss + col0 + tcg];
    *(uint4*)&d0[0] = a0;
    *(uint4*)&d0[8] = a1;
    uint4 b0 = *(const uint4*)&ltT[tr][tcg];
    uint4 b1 = *(const uint4*)&ltT[tr][tcg + 8];
    _Float16* d1 = &T[zo + (long)(col0 + tr) * Ss + row0 + tcg];
    *(uint4*)&d1[0] = b0;
    *(uint4*)&d1[8] = b1;
}

// ============ mid_k: y0 (XCD-swz) | scal | stats | U = W W^T (XCD-swz) ============
__global__ __launch_bounds__(256) void mid_k(const _Float16* __restrict__ vT,
                                             const _Float16* __restrict__ Wt,
                                             float* __restrict__ y0,
                                             const float* __restrict__ rsum,
                                             const float* __restrict__ rsq,
                                             const float* __restrict__ csum,
                                             float* __restrict__ scal,
                                             float* __restrict__ mu,
                                             float* __restrict__ inv_sig,
                                             const _Float16* __restrict__ Wh,
                                             _Float16* __restrict__ U)
{
    __shared__ __align__(16) char sm[36864];
    int bx = blockIdx.x, t = threadIdx.x;
    if (bx < 128) {
        // XCD swizzle: q = bx&7 -> z in {2q, 2q+1}; Wt_z stays in one XCD's L2
        int q = bx & 7, s = bx >> 3;
        int z = 2 * q + (s >= 8 ? 1 : 0);
        int cc = s & 7;
        int col0 = cc * 64;
        long zA = (long)z * (HD * Ss), zB = (long)z * Ss * Ss;
        f32x4 acc[4];
#pragma unroll
        for (int i = 0; i < 4; ++i) acc[i] = (f32x4){0.f, 0.f, 0.f, 0.f};
        wk_core(sm, vT, Wt, zA, zB, col0, col0, Ss, acc);
        const int wave = t >> 6, lane = t & 63;
        const int ln = lane & 15, quad = lane >> 4;
        const int gr = wave * 16 + quad * 4;
#pragma unroll
        for (int nt = 0; nt < 4; ++nt) {
            const int gc = col0 + nt * 16 + ln;
#pragma unroll
            for (int r = 0; r < 4; ++r)
                y0[zA + (long)(gr + r) * Ss + gc] = acc[nt][r];
        }
    } else if (bx < 144) {
        int z = bx - 128;
        float* s1 = (float*)sm;
        float* s2 = s1 + 256;
        float mx1 = 0.f, mx2 = 0.f;
        for (int jj = t; jj < 512; jj += 256) {
            float rs = 0.f, cs = 0.f;
#pragma unroll
            for (int ti = 0; ti < 8; ++ti) {
                rs += rsum[(z * 8 + ti) * 512 + jj];
                cs += csum[(z * 8 + ti) * 512 + jj];
            }
            mx1 = fmaxf(mx1, rs);
            mx2 = fmaxf(mx2, cs);
        }
        s1[t] = mx1; s2[t] = mx2;
        __syncthreads();
        for (int off = 128; off > 0; off >>= 1) {
            if (t < off) {
                s1[t] = fmaxf(s1[t], s1[t + off]);
                s2[t] = fmaxf(s2[t], s2[t + off]);
            }
            __syncthreads();
        }
        if (t == 0) scal[z] = 1.0f / (s1[0] * s2[0]);
    } else if (bx < 152) {
        int h = bx - 144;
        for (int jj = t; jj < 512; jj += 256) {
            float s = 0.f, q = 0.f;
#pragma unroll
            for (int b = 0; b < 2; ++b)
#pragma unroll
                for (int ti = 0; ti < 8; ++ti) {
                    int zz = b * 8 + h;
                    s += rsum[(zz * 8 + ti) * 512 + jj];
                    q += rsq [(zz * 8 + ti) * 512 + jj];
                }
            float m_ = s / 1024.f;
            float var = (q - s * s / 1024.f) / 1023.f;
            inv_sig[h * 512 + jj] = 1.0f / sqrtf(var + 1e-5f);
            mu[h * 512 + jj] = m_;
        }
    } else {
        // U = W @ W^T: 576 blocks, XCD swizzle (q -> z pair, Wh_z L2-resident)
        int u = bx - 152;
        int q = u & 7, s = u >> 3;          // s in [0,72)
        int z = 2 * q + (s >= 36 ? 1 : 0);
        int tile = (s >= 36) ? s - 36 : s;
        const long zo = (long)z * Ss * Ss;
        const int ti = d_tIs[tile], tj = d_tJs[tile];
        const int row0 = ti * 64, col0 = tj * 64;
        f32x4 acc[4];
#pragma unroll
        for (int i = 0; i < 4; ++i) acc[i] = (f32x4){0.f, 0.f, 0.f, 0.f};
        sym_core(sm, Wh, zo, row0, col0, col0 + 64, acc);   // K truncated: W lower-tri
        const int wave = t >> 6, lane = t & 63;
        const int ln = lane & 15, quad = lane >> 4;
        _Float16 ov[4][4] __attribute__((aligned(8)));
#pragma unroll
        for (int nt = 0; nt < 4; ++nt)
#pragma unroll
            for (int r = 0; r < 4; ++r)
                ov[nt][r] = (_Float16)acc[nt][r];
        if (ti == tj) {
            const int gr0 = row0 + wave * 16 + quad * 4;
#pragma unroll
            for (int nt = 0; nt < 4; ++nt) {
                const int gc = col0 + nt * 16 + ln;
#pragma unroll
                for (int r = 0; r < 4; ++r)
                    U[zo + (long)(gr0 + r) * Ss + gc] = ov[nt][r];
            }
        } else {
            sym_store_offdiag(sm, U, zo, row0, col0, ov);
        }
    }
}

// ============ sq_k<FIRST>: fused T-squaring + y-update, XCD-swizzled 1D grid (832) ============
template<int FIRST>
__global__ __launch_bounds__(256) void sq_k(const _Float16* __restrict__ Tc,
                                            _Float16* __restrict__ Tn,
                                            const float* __restrict__ Y0,
                                            const float* __restrict__ Y1,
                                            float* __restrict__ O0,
                                            float* __restrict__ O1,
                                            const float* __restrict__ scal)
{
    __shared__ __align__(16) char sm[36864];
    // XCD swizzle: 832 = 8 XCDs x 104; XCD q owns z in {2q, 2q+1} -> T_z L2-resident
    const int L = blockIdx.x;
    const int q = L & 7, s = L >> 3;        // s in [0,104)
    const int z = 2 * q + (s >= 52 ? 1 : 0);
    const int x = (s >= 52) ? s - 52 : s;   // x in [0,52)
    const int t = threadIdx.x;
    const int wave = t >> 6, lane = t & 63;
    const int ln = lane & 15, quad = lane >> 4;

    if (x < 36) {
        const long zo = (long)z * Ss * Ss;
        const int ti = d_tIs[x], tj = d_tJs[x];
        const int row0 = ti * 64, col0 = tj * 64;
        f32x4 acc[4];
#pragma unroll
        for (int i = 0; i < 4; ++i) acc[i] = (f32x4){0.f, 0.f, 0.f, 0.f};
        sym_core(sm, Tc, zo, row0, col0, Ss, acc);
        const float sv = FIRST ? scal[z] : 0.f;
        const int gr0 = row0 + wave * 16 + quad * 4;
        _Float16 ov[4][4] __attribute__((aligned(8)));
#pragma unroll
        for (int nt = 0; nt < 4; ++nt) {
            const int gc = col0 + nt * 16 + ln;
#pragma unroll
            for (int r = 0; r < 4; ++r) {
                const long gi = zo + (long)(gr0 + r) * Ss + gc;
                float val;
                if (FIRST) val = sv * sv * acc[nt][r] - 2.0f * sv * (float)Tc[gi];
                else       val = 2.0f * (float)Tc[gi] + acc[nt][r];
                ov[nt][r] = (_Float16)val;
            }
        }
        if (ti == tj) {
#pragma unroll
            for (int nt = 0; nt < 4; ++nt) {
                const int gc = col0 + nt * 16 + ln;
#pragma unroll
                for (int r = 0; r < 4; ++r)
                    Tn[zo + (long)(gr0 + r) * Ss + gc] = ov[nt][r];
            }
        } else {
            sym_store_offdiag(sm, Tn, zo, row0, col0, ov);
        }
    } else {
        const int bx = x - 36;
        const int cc = bx & 7, kh = bx >> 3;
        const int col0 = cc * 64;
        const long zA = (long)z * (HD * Ss);
        const long zB = (long)z * Ss * Ss;
        f32x4 acc[4];
#pragma unroll
        for (int i = 0; i < 4; ++i) acc[i] = (f32x4){0.f, 0.f, 0.f, 0.f};
        wk_core32<FIRST ? 0 : 1>(sm, Y0, Y1, Tc, zA, zB, col0, kh * 256, kh * 256 + 256, acc);
        const float alpha = FIRST ? -scal[z] : 1.0f;
        float* O = kh ? O1 : O0;
        const int gr = wave * 16 + quad * 4;
#pragma unroll
        for (int nt = 0; nt < 4; ++nt) {
            const int gc = col0 + nt * 16 + ln;
#pragma unroll
            for (int r = 0; r < 4; ++r) {
                const long idx = zA + (long)(gr + r) * Ss + gc;
                float val = alpha * acc[nt][r];
                if (kh == 0) {
                    if (FIRST) val += 2.0f * Y0[idx];
                    else       val += 2.0f * (Y0[idx] + Y1[idx]);
                }
                O[idx] = val;
            }
        }
    }
}

// ============ yk_k: y' = 2*y + y x T, split-K=2, fp32 half-buffers ============
__global__ __launch_bounds__(256) void yk_k(const float* __restrict__ A0,
                                            const float* __restrict__ A1,
                                            const _Float16* __restrict__ T,
                                            float* __restrict__ O0,
                                            float* __restrict__ O1)
{
    __shared__ __align__(16) char sm[20480];
    const int z = blockIdx.y;
    const int cc = blockIdx.x & 7, kh = blockIdx.x >> 3;
    const int col0 = cc * 64;
    const long zA = (long)z * (HD * Ss);
    const long zB = (long)z * Ss * Ss;
    const int t = threadIdx.x;
    const int wave = t >> 6, lane = t & 63;
    const int ln = lane & 15, quad = lane >> 4;

    f32x4 acc[4];
#pragma unroll
    for (int i = 0; i < 4; ++i) acc[i] = (f32x4){0.f, 0.f, 0.f, 0.f};
    wk_core32<1>(sm, A0, A1, T, zA, zB, col0, kh * 256, kh * 256 + 256, acc);

    float* O = kh ? O1 : O0;
    const int gr = wave * 16 + quad * 4;
#pragma unroll
    for (int nt = 0; nt < 4; ++nt) {
        const int gc = col0 + nt * 16 + ln;
#pragma unroll
        for (int r = 0; r < 4; ++r) {
            const long idx = zA + (long)(gr + r) * Ss + gc;
            float val = acc[nt][r];
            if (kh == 0) val += 2.0f * (A0[idx] + A1[idx]);
            O[idx] = val;
        }
    }
}

// ============ c2s_k: c2sT = inv_sig[n]*s*(y x Wt) + negoff partials ============
__global__ __launch_bounds__(256) void c2s_k(const float* __restrict__ A0,
                                             const float* __restrict__ A1,
                                             const _Float16* __restrict__ Wt,
                                             _Float16* __restrict__ c2sT,
                                             const float* __restrict__ scal,
                                             const float* __restrict__ inv_sig,
                                             const float* __restrict__ mu,
                                             float* __restrict__ negopart)
{
    __shared__ __align__(16) char sm[20480];
    __shared__ float red[64];
    const int z = blockIdx.y;
    const int h = z & 7;
    const int col0 = blockIdx.x * 64;
    const long zA = (long)z * (HD * Ss);
    const long zB = (long)z * Ss * Ss;
    const int t = threadIdx.x;
    const int wave = t >> 6, lane = t & 63;
    const int ln = lane & 15, quad = lane >> 4;

    f32x4 acc[4];
#pragma unroll
    for (int i = 0; i < 4; ++i) acc[i] = (f32x4){0.f, 0.f, 0.f, 0.f};
    wk_core32<1>(sm, A0, A1, Wt, zA, zB, col0, col0, Ss, acc);

    if (t < 64) red[t] = 0.f;
    __syncthreads();
    const int gr = wave * 16 + quad * 4;
    float pr[4] = {0.f, 0.f, 0.f, 0.f};
    float s = scal[z];
#pragma unroll
    for (int nt = 0; nt < 4; ++nt) {
        const int gc = col0 + nt * 16 + ln;
#pragma unroll
        for (int r = 0; r < 4; ++r) {
            float val = inv_sig[h * 512 + gc] * (s * acc[nt][r]);
            pr[r] += mu[h * 512 + gc] * val;
            c2sT[zA + (long)(gr + r) * Ss + gc] = (_Float16)val;
        }
    }
#pragma unroll
    for (int r = 0; r < 4; ++r)
        atomicAdd(&red[gr + r], pr[r]);
    __syncthreads();
    if (t < 64)
        negopart[(z * 8 + blockIdx.x) * 64 + t] = red[t];
}

// ============ ga_k: gat = Wh @ c2s - neg, fp32 out in [B,S,DIM] ============
__global__ __launch_bounds__(256) void ga_k(const _Float16* __restrict__ Wh,
                                            const _Float16* __restrict__ c2sT,
                                            const float* __restrict__ negopart,
                                            float* __restrict__ gat)
{
    __shared__ __align__(16) char sm[36864];
    __shared__ float neg[64];
    const int z = blockIdx.y;
    const int b = z >> 3, h = z & 7;
    const int m0 = blockIdx.x * 64;
    const long zA = (long)z * Ss * Ss;
    const long zB = (long)z * (HD * Ss);
    const int t = threadIdx.x;
    const int wave = t >> 6, lane = t & 63;
    const int ln = lane & 15, quad = lane >> 4;

    if (t < 64) {
        float s = 0.f;
#pragma unroll
        for (int k = 0; k < 8; ++k) s += negopart[(z * 8 + k) * 64 + t];
        neg[t] = s;
    }
    __syncthreads();

    f32x4 acc[4];
#pragma unroll
    for (int i = 0; i < 4; ++i) acc[i] = (f32x4){0.f, 0.f, 0.f, 0.f};
    wk_core(sm, c2sT, Wh, zB, zA, m0, 0, m0 + 64, acc);

    const int gr = wave * 16 + quad * 4;   // d index
#pragma unroll
    for (int nt = 0; nt < 4; ++nt) {
        const int m = m0 + nt * 16 + ln;
#pragma unroll
        for (int r = 0; r < 4; ++r) {
            const int d = gr + r;
            gat[(long)b * (Ss * DIM) + (long)m * DIM + h * HD + d] = acc[nt][r] - neg[d];
        }
    }
}

extern "C" void kernel_launch(void* const* d_in, const int* in_sizes, int n_in,
                              void* d_out, int out_size, void* d_ws, size_t ws_size,
                              hipStream_t stream)
{
    const float* x      = (const float*)d_in[0];
    const float* qkv_w  = (const float*)d_in[1];
    const float* qkv_b  = (const float*)d_in[2];
    const float* proj_w = (const float*)d_in[3];
    const float* proj_b = (const float*)d_in[4];
    float* out = (float*)d_out;
    float* ws  = (float*)d_ws;

    float* qkv     = ws;
    _Float16* Wh   = (_Float16*)(ws + 1572864);
    _Float16* Wt   = (_Float16*)(ws + 3670016);
    _Float16* vT   = (_Float16*)(ws + 5767168);
    _Float16* T[5];
    for (int i = 0; i < 5; ++i) T[i] = (_Float16*)(ws + 6029312 + (long)i * 2097152);
    float* Ya0 = ws + 16515072;   // fp32 y half-buffers, 524288 f each
    float* Ya1 = ws + 17039360;
    float* Yb0 = ws + 17563648;
    float* Yb1 = ws + 18087936;
    _Float16* c2sT = (_Float16*)(ws + 19136512);
    float* rsum    = ws + 19398656;   // 65536
    float* rsq     = ws + 19464192;   // 65536
    float* csum    = ws + 19529728;   // 65536
    float* scal    = ws + 19595264;   // 16
    float* mu      = ws + 19595280;   // 4096
    float* inv_sig = ws + 19599376;   // 4096
    float* negp    = ws + 19603472;   // 8192
    float* gat     = ws + 19611664;   // 524288

    dim3 blk(256);

    // 1. qkv = x @ qkv_w^T + qkv_b  (64x64 tiles: 384 blocks)
    mm64_k<<<dim3(24, 16), blk, 0, stream>>>(x, qkv_w, qkv_b, qkv, DIM, 3 * DIM);

    // 2. W fp16 (both layouts, 64-tiles) + reduction partials + vT
    wt_fused<<<dim3(66, 16), blk, 0, stream>>>(qkv, Wh, Wt, vT, rsum, rsq, csum);

    // 3. y0 = vT x Wt || scale || whitening stats || U = W W^T (XCD-swizzled)
    mid_k<<<dim3(728), blk, 0, stream>>>(vT, Wt, Ya0, rsum, rsq, csum, scal, mu, inv_sig,
                                         Wh, T[0]);

    // 4-7. fused NS steps (ascending k; factors commute), XCD-swizzled 1D grids:
    //      T1 = s^2 U U - 2 s U   || y1 = 2 y0 - s y0 U
    //      T_{k+1} = 2 T_k + T_k^2 || y_{k+1} = 2 y_k + y_k T_k
    sq_k<1><<<dim3(832), blk, 0, stream>>>(T[0], T[1], Ya0, nullptr, Yb0, Yb1, scal);
    sq_k<0><<<dim3(832), blk, 0, stream>>>(T[1], T[2], Yb0, Yb1,     Ya0, Ya1, scal);
    sq_k<0><<<dim3(832), blk, 0, stream>>>(T[2], T[3], Ya0, Ya1,     Yb0, Yb1, scal);
    sq_k<0><<<dim3(832), blk, 0, stream>>>(T[3], T[4], Yb0, Yb1,     Ya0, Ya1, scal);

    // 8. final y update with T4
    yk_k<<<dim3(16, 16), blk, 0, stream>>>(Ya0, Ya1, T[4], Yb0, Yb1);

    // 9. c2sT = inv_sig * s * (y W) + negoff partials
    c2s_k<<<dim3(8, 16), blk, 0, stream>>>(Yb0, Yb1, Wt, c2sT, scal, inv_sig, mu, negp);

    // 10. gat = W @ c2s - neg
    ga_k<<<dim3(8, 16), blk, 0, stream>>>(Wh, c2sT, negp, gat);

    // 11. out = gat @ proj_w^T + proj_b  (64x64 tiles: 128 blocks)
    mm64_k<<<dim3(8, 16), blk, 0, stream>>>(gat, proj_w, proj_b, out, DIM, DIM);
}

// Round 12
// 198.551 us; speedup vs baseline: 1.4849x; 1.0178x over previous
//
#include <hip/hip_runtime.h>

#define Bq 2
#define Hh 8
#define Ss 512
#define HD 64
#define DIM 512

using f32x4   = __attribute__((ext_vector_type(4))) float;
using bf16x8s = __attribute__((ext_vector_type(8))) short;
typedef _Float16 f16x8 __attribute__((ext_vector_type(8)));

__constant__ int d_tIs[36] = {0,1,1,2,2,2,3,3,3,3,4,4,4,4,4,5,5,5,5,5,5,6,6,6,6,6,6,6,7,7,7,7,7,7,7,7};
__constant__ int d_tJs[36] = {0,0,1,0,1,2,0,1,2,3,0,1,2,3,4,0,1,2,3,4,5,0,1,2,3,4,5,6,0,1,2,3,4,5,6,7};

__device__ __forceinline__ float bf2f(unsigned short u) {
    return __uint_as_float(((unsigned int)u) << 16);
}
__device__ __forceinline__ unsigned short f2bf(float f) {
    unsigned int u = __float_as_uint(f);
    u = (u + 0x7FFFu + ((u >> 16) & 1u)) >> 16;   // RNE
    return (unsigned short)u;
}

// ============ mm64_k: C = A @ B^T + bias (fp32 io, split bf16x2 MFMA, 64x64 tiles) ============
__global__ __launch_bounds__(256) void mm64_k(
    const float* __restrict__ A, const float* __restrict__ B,
    const float* __restrict__ bias, float* __restrict__ C,
    int K, int ldc)
{
    const int row0 = blockIdx.y * 64, col0 = blockIdx.x * 64;
    __shared__ unsigned short AsH[64][40], AsL[64][40];
    __shared__ unsigned short BsH[64][40], BsL[64][40];
    const int t = threadIdx.x;
    const int wave = t >> 6, lane = t & 63;
    const int ln = lane & 15, quad = lane >> 4;

    f32x4 acc[4];
#pragma unroll
    for (int i = 0; i < 4; ++i) acc[i] = (f32x4){0.f, 0.f, 0.f, 0.f};

    const int sr = t >> 2, sg = (t & 3) * 8;

    for (int k0 = 0; k0 < K; k0 += 32) {
        __syncthreads();
#pragma unroll
        for (int half = 0; half < 2; ++half) {
            const float* src = half ? B : A;
            int base = half ? col0 : row0;
            const float* p = &src[(long)(base + sr) * K + k0 + sg];
            float4 f0 = *(const float4*)p;
            float4 f1 = *(const float4*)(p + 4);
            float fv[8] = {f0.x, f0.y, f0.z, f0.w, f1.x, f1.y, f1.z, f1.w};
            unsigned short hv[8], lv[8];
#pragma unroll
            for (int e = 0; e < 8; ++e) {
                hv[e] = f2bf(fv[e]);
                lv[e] = f2bf(fv[e] - bf2f(hv[e]));
            }
            uint4 H, L;
            H.x = hv[0] | (hv[1] << 16); H.y = hv[2] | (hv[3] << 16);
            H.z = hv[4] | (hv[5] << 16); H.w = hv[6] | (hv[7] << 16);
            L.x = lv[0] | (lv[1] << 16); L.y = lv[2] | (lv[3] << 16);
            L.z = lv[4] | (lv[5] << 16); L.w = lv[6] | (lv[7] << 16);
            if (!half) { *(uint4*)&AsH[sr][sg] = H; *(uint4*)&AsL[sr][sg] = L; }
            else       { *(uint4*)&BsH[sr][sg] = H; *(uint4*)&BsL[sr][sg] = L; }
        }
        __syncthreads();

        bf16x8s afH, afL, bfH[4], bfL[4];
        afH = *(const bf16x8s*)&AsH[wave * 16 + ln][quad * 8];
        afL = *(const bf16x8s*)&AsL[wave * 16 + ln][quad * 8];
#pragma unroll
        for (int nt = 0; nt < 4; ++nt) {
            bfH[nt] = *(const bf16x8s*)&BsH[nt * 16 + ln][quad * 8];
            bfL[nt] = *(const bf16x8s*)&BsL[nt * 16 + ln][quad * 8];
        }
#pragma unroll
        for (int nt = 0; nt < 4; ++nt) {
            acc[nt] = __builtin_amdgcn_mfma_f32_16x16x32_bf16(afH, bfH[nt], acc[nt], 0, 0, 0);
            acc[nt] = __builtin_amdgcn_mfma_f32_16x16x32_bf16(afH, bfL[nt], acc[nt], 0, 0, 0);
            acc[nt] = __builtin_amdgcn_mfma_f32_16x16x32_bf16(afL, bfH[nt], acc[nt], 0, 0, 0);
        }
    }

    const int gr0 = row0 + wave * 16 + quad * 4;
#pragma unroll
    for (int nt = 0; nt < 4; ++nt) {
        const int gc = col0 + nt * 16 + ln;
        float bb = bias[gc];
#pragma unroll
        for (int r = 0; r < 4; ++r)
            C[(long)(gr0 + r) * ldc + gc] = acc[nt][r] + bb;
    }
}

// ============ wt_fused: 64x64 tiles, XCD-swizzled 1D grid (1056 = 8 x 132) ============
__global__ __launch_bounds__(256) void wt_fused(const float* __restrict__ qkv,
                                                _Float16* __restrict__ Wh,
                                                _Float16* __restrict__ Wt,
                                                _Float16* __restrict__ vT,
                                                float* __restrict__ rsum,
                                                float* __restrict__ rsq,
                                                float* __restrict__ csum)
{
    __shared__ float qs[32][64];
    __shared__ float ks[32][64];
    __shared__ float colacc[64];
    // XCD swizzle: XCD q owns z in {2q, 2q+1}; qkv/W panels for z stay in one L2
    const int L = blockIdx.x;
    const int q = L & 7, s = L >> 3;      // s in [0,132)
    const int z = 2 * q + (s >= 66 ? 1 : 0);
    const int bx = (s >= 66) ? s - 66 : s;
    int b = z >> 3, h = z & 7;
    int t = threadIdx.x;
    long zo = (long)z * Ss * Ss;

    if (bx >= 64) {            // vT pack: half dh (d 32-chunk), all k
        float (*sT)[33] = (float(*)[33])qs;
        int dt = (bx - 64) * 32;
        int d = t & 31, kr = t >> 5;
        for (int kt = 0; kt < Ss; kt += 32) {
            __syncthreads();
#pragma unroll
            for (int p = 0; p < 4; ++p) {
                int kk = kr + p * 8;
                sT[kk][d] = qkv[(long)b * (Ss * 3 * DIM) + (long)(kt + kk) * (3 * DIM) + 2 * DIM + h * HD + dt + d];
            }
            __syncthreads();
#pragma unroll
            for (int p = 0; p < 4; ++p) {
                int dd = kr + p * 8;
                vT[(long)z * (HD * Ss) + (long)(dt + dd) * Ss + kt + d] = (_Float16)sT[d][dd];
            }
        }
        return;
    }

    int ti = bx >> 3, tj = bx & 7;
    int i0 = ti * 64, j0 = tj * 64;

    if (tj > ti) {             // fully-masked: zero only the partial slots
        if (t < 64) {
            rsum[((z * 8 + ti) * 512) + j0 + t] = 0.f;
            rsq [((z * 8 + ti) * 512) + j0 + t] = 0.f;
            csum[((z * 8 + tj) * 512) + i0 + t] = 0.f;
        }
        return;
    }

    int ia = (t & 15) * 4;
    int ja = (t >> 4) * 4;
    const float* qb = qkv + (long)b * Ss * (3 * DIM) + h * HD;
    const float* kb = qb + DIM;
    float acc[4][4] = {};

    for (int d0 = 0; d0 < 64; d0 += 32) {
        __syncthreads();
        int row = t & 63, dg = (t >> 6) * 8;
        float4 qv  = *(const float4*)&qb[(long)(i0 + row) * (3 * DIM) + d0 + dg];
        float4 qv2 = *(const float4*)&qb[(long)(i0 + row) * (3 * DIM) + d0 + dg + 4];
        float4 kv  = *(const float4*)&kb[(long)(j0 + row) * (3 * DIM) + d0 + dg];
        float4 kv2 = *(const float4*)&kb[(long)(j0 + row) * (3 * DIM) + d0 + dg + 4];
        qs[dg+0][row] = qv.x;  qs[dg+1][row] = qv.y;  qs[dg+2][row] = qv.z;  qs[dg+3][row] = qv.w;
        qs[dg+4][row] = qv2.x; qs[dg+5][row] = qv2.y; qs[dg+6][row] = qv2.z; qs[dg+7][row] = qv2.w;
        ks[dg+0][row] = kv.x;  ks[dg+1][row] = kv.y;  ks[dg+2][row] = kv.z;  ks[dg+3][row] = kv.w;
        ks[dg+4][row] = kv2.x; ks[dg+5][row] = kv2.y; ks[dg+6][row] = kv2.z; ks[dg+7][row] = kv2.w;
        __syncthreads();
#pragma unroll
        for (int d = 0; d < 32; ++d) {
            float4 q0 = *(const float4*)&qs[d][ia];
            float4 k0 = *(const float4*)&ks[d][ja];
            float qv_[4] = {q0.x, q0.y, q0.z, q0.w};
            float kv_[4] = {k0.x, k0.y, k0.z, k0.w};
#pragma unroll
            for (int aa = 0; aa < 4; ++aa)
#pragma unroll
                for (int c = 0; c < 4; ++c)
                    acc[aa][c] += fabsf(qv_[aa] - kv_[c]);
        }
    }

#pragma unroll
    for (int aa = 0; aa < 4; ++aa) {
        int i = i0 + ia + aa;
#pragma unroll
        for (int c = 0; c < 4; ++c) {
            int j = j0 + ja + c;
            float e = expf(-acc[aa][c] * 0.25f);
            acc[aa][c] = (j <= i) ? e : 0.0f;
        }
    }
    // Wt rows + per-j partials
#pragma unroll
    for (int c = 0; c < 4; ++c) {
        int j = j0 + ja + c;
        float rs = 0.f, rq = 0.f;
#pragma unroll
        for (int aa = 0; aa < 4; ++aa) { rs += acc[aa][c]; rq += acc[aa][c] * acc[aa][c]; }
        _Float16 ha[4] __attribute__((aligned(8))) = {(_Float16)acc[0][c], (_Float16)acc[1][c], (_Float16)acc[2][c], (_Float16)acc[3][c]};
        *(uint2*)&Wt[zo + (long)j * Ss + i0 + ia] = *(const uint2*)ha;
#pragma unroll
        for (int off = 8; off > 0; off >>= 1) {
            rs += __shfl_down(rs, off, 16);
            rq += __shfl_down(rq, off, 16);
        }
        if ((t & 15) == 0) {
            rsum[((z * 8 + ti) * 512) + j] = rs;
            rsq [((z * 8 + ti) * 512) + j] = rq;
        }
    }
    // Wh rows
#pragma unroll
    for (int aa = 0; aa < 4; ++aa) {
        int i = i0 + ia + aa;
        _Float16 hb[4] __attribute__((aligned(8))) = {(_Float16)acc[aa][0], (_Float16)acc[aa][1], (_Float16)acc[aa][2], (_Float16)acc[aa][3]};
        *(uint2*)&Wh[zo + (long)i * Ss + j0 + ja] = *(const uint2*)hb;
    }
    // per-i partials via LDS
    __syncthreads();
    if (t < 64) colacc[t] = 0.f;
    __syncthreads();
#pragma unroll
    for (int aa = 0; aa < 4; ++aa) {
        float cs = acc[aa][0] + acc[aa][1] + acc[aa][2] + acc[aa][3];
        atomicAdd(&colacc[ia + aa], cs);
    }
    __syncthreads();
    if (t < 64) csum[((z * 8 + tj) * 512) + i0 + t] = colacc[t];
}

// ============ fp16-A wide core, BK=64, LDS double-buffered (1 barrier / 64-K step) ============
__device__ __forceinline__ void wk_core(char* smc, const _Float16* A, const _Float16* B,
                                        long zA, long zB, int col0, int kbeg, int kend,
                                        f32x4* acc)
{
    _Float16 (*As0)[72] = (_Float16(*)[72])smc;
    _Float16 (*Bs0)[72] = (_Float16(*)[72])(smc + 9216);
    _Float16 (*As1)[72] = (_Float16(*)[72])(smc + 18432);
    _Float16 (*Bs1)[72] = (_Float16(*)[72])(smc + 27648);
    const int t = threadIdx.x;
    const int wave = t >> 6, lane = t & 63;
    const int ln = lane & 15, quad = lane >> 4;
    const int r2 = t >> 2, c2 = (t & 3) * 16;
    const long aoff = zA + (long)r2 * Ss;
    const long boff = zB + (long)(col0 + r2) * Ss;

    uint4 ua0 = *(const uint4*)&A[aoff + kbeg + c2];
    uint4 ua1 = *(const uint4*)&A[aoff + kbeg + c2 + 8];
    uint4 ub0 = *(const uint4*)&B[boff + kbeg + c2];
    uint4 ub1 = *(const uint4*)&B[boff + kbeg + c2 + 8];
    *(uint4*)&As0[r2][c2]     = ua0;
    *(uint4*)&As0[r2][c2 + 8] = ua1;
    *(uint4*)&Bs0[r2][c2]     = ub0;
    *(uint4*)&Bs0[r2][c2 + 8] = ub1;
    int cur = 0;
    for (int k0 = kbeg; k0 < kend; k0 += 64) {
        int kn = k0 + 64;
        if (kn < kend) {
            ua0 = *(const uint4*)&A[aoff + kn + c2];
            ua1 = *(const uint4*)&A[aoff + kn + c2 + 8];
            ub0 = *(const uint4*)&B[boff + kn + c2];
            ub1 = *(const uint4*)&B[boff + kn + c2 + 8];
        }
        __syncthreads();
        _Float16 (*As)[72] = cur ? As1 : As0;
        _Float16 (*Bs)[72] = cur ? Bs1 : Bs0;
#pragma unroll
        for (int kk = 0; kk < 64; kk += 32) {
            f16x8 af = *(const f16x8*)&As[wave * 16 + ln][quad * 8 + kk];
#pragma unroll
            for (int nt = 0; nt < 4; ++nt) {
                f16x8 bf = *(const f16x8*)&Bs[nt * 16 + ln][quad * 8 + kk];
                acc[nt] = __builtin_amdgcn_mfma_f32_16x16x32_f16(af, bf, acc[nt], 0, 0, 0);
            }
        }
        if (kn < kend) {
            _Float16 (*An)[72] = cur ? As0 : As1;
            _Float16 (*Bn)[72] = cur ? Bs0 : Bs1;
            *(uint4*)&An[r2][c2]     = ua0;
            *(uint4*)&An[r2][c2 + 8] = ua1;
            *(uint4*)&Bn[r2][c2]     = ub0;
            *(uint4*)&Bn[r2][c2 + 8] = ub1;
        }
        cur ^= 1;
    }
}

// ============ fp32-halves-A wide core, BK=32, double-buffered (VGPR-bounded) ============
template<int HASA1>
__device__ __forceinline__ void wk_core32(char* smc, const float* A0, const float* A1,
                                          const _Float16* B, long zA, long zB, int col0,
                                          int kbeg, int kend, f32x4* acc)
{
    _Float16 (*As0)[40] = (_Float16(*)[40])smc;
    _Float16 (*Bs0)[40] = (_Float16(*)[40])(smc + 5120);
    _Float16 (*As1)[40] = (_Float16(*)[40])(smc + 10240);
    _Float16 (*Bs1)[40] = (_Float16(*)[40])(smc + 15360);
    const int t = threadIdx.x;
    const int wave = t >> 6, lane = t & 63;
    const int ln = lane & 15, quad = lane >> 4;
    const int r4 = t >> 2, c4 = (t & 3) * 8;
    const long aoff = zA + (long)r4 * Ss;
    const long boff = zB + (long)(col0 + r4) * Ss;

    float4 p0 = *(const float4*)&A0[aoff + kbeg + c4];
    float4 p1 = *(const float4*)&A0[aoff + kbeg + c4 + 4];
    float4 q0, q1;
    if constexpr (HASA1) {
        q0 = *(const float4*)&A1[aoff + kbeg + c4];
        q1 = *(const float4*)&A1[aoff + kbeg + c4 + 4];
    }
    uint4 ub = *(const uint4*)&B[boff + kbeg + c4];
    {
        _Float16 hv[8] __attribute__((aligned(16)));
        if constexpr (HASA1) {
            hv[0] = (_Float16)(p0.x + q0.x); hv[1] = (_Float16)(p0.y + q0.y);
            hv[2] = (_Float16)(p0.z + q0.z); hv[3] = (_Float16)(p0.w + q0.w);
            hv[4] = (_Float16)(p1.x + q1.x); hv[5] = (_Float16)(p1.y + q1.y);
            hv[6] = (_Float16)(p1.z + q1.z); hv[7] = (_Float16)(p1.w + q1.w);
        } else {
            hv[0] = (_Float16)p0.x; hv[1] = (_Float16)p0.y;
            hv[2] = (_Float16)p0.z; hv[3] = (_Float16)p0.w;
            hv[4] = (_Float16)p1.x; hv[5] = (_Float16)p1.y;
            hv[6] = (_Float16)p1.z; hv[7] = (_Float16)p1.w;
        }
        *(uint4*)&As0[r4][c4] = *(const uint4*)hv;
        *(uint4*)&Bs0[r4][c4] = ub;
    }
    int cur = 0;
    for (int k0 = kbeg; k0 < kend; k0 += 32) {
        int kn = k0 + 32;
        if (kn < kend) {
            p0 = *(const float4*)&A0[aoff + kn + c4];
            p1 = *(const float4*)&A0[aoff + kn + c4 + 4];
            if constexpr (HASA1) {
                q0 = *(const float4*)&A1[aoff + kn + c4];
                q1 = *(const float4*)&A1[aoff + kn + c4 + 4];
            }
            ub = *(const uint4*)&B[boff + kn + c4];
        }
        __syncthreads();
        _Float16 (*As)[40] = cur ? As1 : As0;
        _Float16 (*Bs)[40] = cur ? Bs1 : Bs0;
        f16x8 af = *(const f16x8*)&As[wave * 16 + ln][quad * 8];
#pragma unroll
        for (int nt = 0; nt < 4; ++nt) {
            f16x8 bf = *(const f16x8*)&Bs[nt * 16 + ln][quad * 8];
            acc[nt] = __builtin_amdgcn_mfma_f32_16x16x32_f16(af, bf, acc[nt], 0, 0, 0);
        }
        if (kn < kend) {
            _Float16 hv[8] __attribute__((aligned(16)));
            if constexpr (HASA1) {
                hv[0] = (_Float16)(p0.x + q0.x); hv[1] = (_Float16)(p0.y + q0.y);
                hv[2] = (_Float16)(p0.z + q0.z); hv[3] = (_Float16)(p0.w + q0.w);
                hv[4] = (_Float16)(p1.x + q1.x); hv[5] = (_Float16)(p1.y + q1.y);
                hv[6] = (_Float16)(p1.z + q1.z); hv[7] = (_Float16)(p1.w + q1.w);
            } else {
                hv[0] = (_Float16)p0.x; hv[1] = (_Float16)p0.y;
                hv[2] = (_Float16)p0.z; hv[3] = (_Float16)p0.w;
                hv[4] = (_Float16)p1.x; hv[5] = (_Float16)p1.y;
                hv[6] = (_Float16)p1.z; hv[7] = (_Float16)p1.w;
            }
            _Float16 (*An)[40] = cur ? As0 : As1;
            _Float16 (*Bn)[40] = cur ? Bs0 : Bs1;
            *(uint4*)&An[r4][c4] = *(const uint4*)hv;
            *(uint4*)&Bn[r4][c4] = ub;
        }
        cur ^= 1;
    }
}

// ============ sym_core: 64x64 tile of A @ A^T, BK=64, double-buffered ============
__device__ __forceinline__ void sym_core(char* smc, const _Float16* A, long zo,
                                         int row0, int col0, int kend, f32x4* acc)
{
    _Float16 (*As0)[72] = (_Float16(*)[72])smc;
    _Float16 (*Bs0)[72] = (_Float16(*)[72])(smc + 9216);
    _Float16 (*As1)[72] = (_Float16(*)[72])(smc + 18432);
    _Float16 (*Bs1)[72] = (_Float16(*)[72])(smc + 27648);
    const int t = threadIdx.x;
    const int wave = t >> 6, lane = t & 63;
    const int ln = lane & 15, quad = lane >> 4;
    const int r2 = t >> 2, c2 = (t & 3) * 16;
    const long aoff = zo + (long)(row0 + r2) * Ss;
    const long boff = zo + (long)(col0 + r2) * Ss;
    uint4 ua0 = *(const uint4*)&A[aoff + c2];
    uint4 ua1 = *(const uint4*)&A[aoff + c2 + 8];
    uint4 ub0 = *(const uint4*)&A[boff + c2];
    uint4 ub1 = *(const uint4*)&A[boff + c2 + 8];
    *(uint4*)&As0[r2][c2]     = ua0;
    *(uint4*)&As0[r2][c2 + 8] = ua1;
    *(uint4*)&Bs0[r2][c2]     = ub0;
    *(uint4*)&Bs0[r2][c2 + 8] = ub1;
    int cur = 0;
    for (int k0 = 0; k0 < kend; k0 += 64) {
        int kn = k0 + 64;
        if (kn < kend) {
            ua0 = *(const uint4*)&A[aoff + kn + c2];
            ua1 = *(const uint4*)&A[aoff + kn + c2 + 8];
            ub0 = *(const uint4*)&A[boff + kn + c2];
            ub1 = *(const uint4*)&A[boff + kn + c2 + 8];
        }
        __syncthreads();
        _Float16 (*As)[72] = cur ? As1 : As0;
        _Float16 (*Bs)[72] = cur ? Bs1 : Bs0;
#pragma unroll
        for (int kk = 0; kk < 64; kk += 32) {
            f16x8 af = *(const f16x8*)&As[wave * 16 + ln][quad * 8 + kk];
#pragma unroll
            for (int nt = 0; nt < 4; ++nt) {
                f16x8 bf = *(const f16x8*)&Bs[nt * 16 + ln][quad * 8 + kk];
                acc[nt] = __builtin_amdgcn_mfma_f32_16x16x32_f16(af, bf, acc[nt], 0, 0, 0);
            }
        }
        if (kn < kend) {
            _Float16 (*An)[72] = cur ? As0 : As1;
            _Float16 (*Bn)[72] = cur ? Bs0 : Bs1;
            *(uint4*)&An[r2][c2]     = ua0;
            *(uint4*)&An[r2][c2 + 8] = ua1;
            *(uint4*)&Bn[r2][c2]     = ub0;
            *(uint4*)&Bn[r2][c2 + 8] = ub1;
        }
        cur ^= 1;
    }
}

// ============ sym_epilogue: coalesced dual-layout store of a 64x64 fp16 tile ============
__device__ __forceinline__ void sym_store_offdiag(char* smc, _Float16* T, long zo,
                                                  int row0, int col0,
                                                  const _Float16 (*ov)[4])
{
    _Float16 (*ltR)[72] = (_Float16(*)[72])smc;            // 9216 B
    _Float16 (*ltT)[72] = (_Float16(*)[72])(smc + 9216);   // 9216 B
    const int t = threadIdx.x;
    const int wave = t >> 6, lane = t & 63;
    const int ln = lane & 15, quad = lane >> 4;
    const int lr0 = wave * 16 + quad * 4;
    __syncthreads();                       // sym_core LDS reads complete
#pragma unroll
    for (int nt = 0; nt < 4; ++nt) {
        const int lc = nt * 16 + ln;
        *(uint2*)&ltT[lc][lr0] = *(const uint2*)ov[nt];
#pragma unroll
        for (int r = 0; r < 4; ++r)
            ltR[lr0 + r][lc] = ov[nt][r];
    }
    __syncthreads();
    const int tr = t >> 2, tcg = (t & 3) * 16;
    uint4 a0 = *(const uint4*)&ltR[tr][tcg];
    uint4 a1 = *(const uint4*)&ltR[tr][tcg + 8];
    _Float16* d0 = &T[zo + (long)(row0 + tr) * Ss + col0 + tcg];
    *(uint4*)&d0[0] = a0;
    *(uint4*)&d0[8] = a1;
    uint4 b0 = *(const uint4*)&ltT[tr][tcg];
    uint4 b1 = *(const uint4*)&ltT[tr][tcg + 8];
    _Float16* d1 = &T[zo + (long)(col0 + tr) * Ss + row0 + tcg];
    *(uint4*)&d1[0] = b0;
    *(uint4*)&d1[8] = b1;
}

// ============ mid_k: y0 (XCD-swz) | scal | stats | U = W W^T (XCD-swz) ============
__global__ __launch_bounds__(256) void mid_k(const _Float16* __restrict__ vT,
                                             const _Float16* __restrict__ Wt,
                                             float* __restrict__ y0,
                                             const float* __restrict__ rsum,
                                             const float* __restrict__ rsq,
                                             const float* __restrict__ csum,
                                             float* __restrict__ scal,
                                             float* __restrict__ mu,
                                             float* __restrict__ inv_sig,
                                             const _Float16* __restrict__ Wh,
                                             _Float16* __restrict__ U)
{
    __shared__ __align__(16) char sm[36864];
    int bx = blockIdx.x, t = threadIdx.x;
    if (bx < 128) {
        // XCD swizzle: q = bx&7 -> z in {2q, 2q+1}; Wt_z stays in one XCD's L2
        int q = bx & 7, s = bx >> 3;
        int z = 2 * q + (s >= 8 ? 1 : 0);
        int cc = s & 7;
        int col0 = cc * 64;
        long zA = (long)z * (HD * Ss), zB = (long)z * Ss * Ss;
        f32x4 acc[4];
#pragma unroll
        for (int i = 0; i < 4; ++i) acc[i] = (f32x4){0.f, 0.f, 0.f, 0.f};
        wk_core(sm, vT, Wt, zA, zB, col0, col0, Ss, acc);
        const int wave = t >> 6, lane = t & 63;
        const int ln = lane & 15, quad = lane >> 4;
        const int gr = wave * 16 + quad * 4;
#pragma unroll
        for (int nt = 0; nt < 4; ++nt) {
            const int gc = col0 + nt * 16 + ln;
#pragma unroll
            for (int r = 0; r < 4; ++r)
                y0[zA + (long)(gr + r) * Ss + gc] = acc[nt][r];
        }
    } else if (bx < 144) {
        int z = bx - 128;
        float* s1 = (float*)sm;
        float* s2 = s1 + 256;
        float mx1 = 0.f, mx2 = 0.f;
        for (int jj = t; jj < 512; jj += 256) {
            float rs = 0.f, cs = 0.f;
#pragma unroll
            for (int ti = 0; ti < 8; ++ti) {
                rs += rsum[(z * 8 + ti) * 512 + jj];
                cs += csum[(z * 8 + ti) * 512 + jj];
            }
            mx1 = fmaxf(mx1, rs);
            mx2 = fmaxf(mx2, cs);
        }
        s1[t] = mx1; s2[t] = mx2;
        __syncthreads();
        for (int off = 128; off > 0; off >>= 1) {
            if (t < off) {
                s1[t] = fmaxf(s1[t], s1[t + off]);
                s2[t] = fmaxf(s2[t], s2[t + off]);
            }
            __syncthreads();
        }
        if (t == 0) scal[z] = 1.0f / (s1[0] * s2[0]);
    } else if (bx < 152) {
        int h = bx - 144;
        for (int jj = t; jj < 512; jj += 256) {
            float s = 0.f, q = 0.f;
#pragma unroll
            for (int b = 0; b < 2; ++b)
#pragma unroll
                for (int ti = 0; ti < 8; ++ti) {
                    int zz = b * 8 + h;
                    s += rsum[(zz * 8 + ti) * 512 + jj];
                    q += rsq [(zz * 8 + ti) * 512 + jj];
                }
            float m_ = s / 1024.f;
            float var = (q - s * s / 1024.f) / 1023.f;
            inv_sig[h * 512 + jj] = 1.0f / sqrtf(var + 1e-5f);
            mu[h * 512 + jj] = m_;
        }
    } else {
        // U = W @ W^T: 576 blocks, XCD swizzle (q -> z pair, Wh_z L2-resident)
        int u = bx - 152;
        int q = u & 7, s = u >> 3;          // s in [0,72)
        int z = 2 * q + (s >= 36 ? 1 : 0);
        int tile = (s >= 36) ? s - 36 : s;
        const long zo = (long)z * Ss * Ss;
        const int ti = d_tIs[tile], tj = d_tJs[tile];
        const int row0 = ti * 64, col0 = tj * 64;
        f32x4 acc[4];
#pragma unroll
        for (int i = 0; i < 4; ++i) acc[i] = (f32x4){0.f, 0.f, 0.f, 0.f};
        sym_core(sm, Wh, zo, row0, col0, col0 + 64, acc);   // K truncated: W lower-tri
        const int wave = t >> 6, lane = t & 63;
        const int ln = lane & 15, quad = lane >> 4;
        _Float16 ov[4][4] __attribute__((aligned(8)));
#pragma unroll
        for (int nt = 0; nt < 4; ++nt)
#pragma unroll
            for (int r = 0; r < 4; ++r)
                ov[nt][r] = (_Float16)acc[nt][r];
        if (ti == tj) {
            const int gr0 = row0 + wave * 16 + quad * 4;
#pragma unroll
            for (int nt = 0; nt < 4; ++nt) {
                const int gc = col0 + nt * 16 + ln;
#pragma unroll
                for (int r = 0; r < 4; ++r)
                    U[zo + (long)(gr0 + r) * Ss + gc] = ov[nt][r];
            }
        } else {
            sym_store_offdiag(sm, U, zo, row0, col0, ov);
        }
    }
}

// ============ sq_k<FIRST>: fused T-squaring + y-update, XCD-swizzled 1D grid (832) ============
template<int FIRST>
__global__ __launch_bounds__(256) void sq_k(const _Float16* __restrict__ Tc,
                                            _Float16* __restrict__ Tn,
                                            const float* __restrict__ Y0,
                                            const float* __restrict__ Y1,
                                            float* __restrict__ O0,
                                            float* __restrict__ O1,
                                            const float* __restrict__ scal)
{
    __shared__ __align__(16) char sm[36864];
    // XCD swizzle: 832 = 8 XCDs x 104; XCD q owns z in {2q, 2q+1} -> T_z L2-resident
    const int L = blockIdx.x;
    const int q = L & 7, s = L >> 3;        // s in [0,104)
    const int z = 2 * q + (s >= 52 ? 1 : 0);
    const int x = (s >= 52) ? s - 52 : s;   // x in [0,52)
    const int t = threadIdx.x;
    const int wave = t >> 6, lane = t & 63;
    const int ln = lane & 15, quad = lane >> 4;

    if (x < 36) {
        const long zo = (long)z * Ss * Ss;
        const int ti = d_tIs[x], tj = d_tJs[x];
        const int row0 = ti * 64, col0 = tj * 64;
        f32x4 acc[4];
#pragma unroll
        for (int i = 0; i < 4; ++i) acc[i] = (f32x4){0.f, 0.f, 0.f, 0.f};
        sym_core(sm, Tc, zo, row0, col0, Ss, acc);
        const float sv = FIRST ? scal[z] : 0.f;
        const int gr0 = row0 + wave * 16 + quad * 4;
        _Float16 ov[4][4] __attribute__((aligned(8)));
#pragma unroll
        for (int nt = 0; nt < 4; ++nt) {
            const int gc = col0 + nt * 16 + ln;
#pragma unroll
            for (int r = 0; r < 4; ++r) {
                const long gi = zo + (long)(gr0 + r) * Ss + gc;
                float val;
                if (FIRST) val = sv * sv * acc[nt][r] - 2.0f * sv * (float)Tc[gi];
                else       val = 2.0f * (float)Tc[gi] + acc[nt][r];
                ov[nt][r] = (_Float16)val;
            }
        }
        if (ti == tj) {
#pragma unroll
            for (int nt = 0; nt < 4; ++nt) {
                const int gc = col0 + nt * 16 + ln;
#pragma unroll
                for (int r = 0; r < 4; ++r)
                    Tn[zo + (long)(gr0 + r) * Ss + gc] = ov[nt][r];
            }
        } else {
            sym_store_offdiag(sm, Tn, zo, row0, col0, ov);
        }
    } else {
        const int bx = x - 36;
        const int cc = bx & 7, kh = bx >> 3;
        const int col0 = cc * 64;
        const long zA = (long)z * (HD * Ss);
        const long zB = (long)z * Ss * Ss;
        f32x4 acc[4];
#pragma unroll
        for (int i = 0; i < 4; ++i) acc[i] = (f32x4){0.f, 0.f, 0.f, 0.f};
        wk_core32<FIRST ? 0 : 1>(sm, Y0, Y1, Tc, zA, zB, col0, kh * 256, kh * 256 + 256, acc);
        const float alpha = FIRST ? -scal[z] : 1.0f;
        float* O = kh ? O1 : O0;
        const int gr = wave * 16 + quad * 4;
#pragma unroll
        for (int nt = 0; nt < 4; ++nt) {
            const int gc = col0 + nt * 16 + ln;
#pragma unroll
            for (int r = 0; r < 4; ++r) {
                const long idx = zA + (long)(gr + r) * Ss + gc;
                float val = alpha * acc[nt][r];
                if (kh == 0) {
                    if (FIRST) val += 2.0f * Y0[idx];
                    else       val += 2.0f * (Y0[idx] + Y1[idx]);
                }
                O[idx] = val;
            }
        }
    }
}

// ============ yk_k: y' = 2*y + y x T, split-K=2, XCD-swizzled 1D grid (256 = 8x32) ============
__global__ __launch_bounds__(256) void yk_k(const float* __restrict__ A0,
                                            const float* __restrict__ A1,
                                            const _Float16* __restrict__ T,
                                            float* __restrict__ O0,
                                            float* __restrict__ O1)
{
    __shared__ __align__(16) char sm[20480];
    const int L = blockIdx.x;
    const int q = L & 7, s = L >> 3;        // s in [0,32)
    const int z = 2 * q + (s >= 16 ? 1 : 0);
    const int w = (s >= 16) ? s - 16 : s;   // w in [0,16)
    const int cc = w & 7, kh = w >> 3;
    const int col0 = cc * 64;
    const long zA = (long)z * (HD * Ss);
    const long zB = (long)z * Ss * Ss;
    const int t = threadIdx.x;
    const int wave = t >> 6, lane = t & 63;
    const int ln = lane & 15, quad = lane >> 4;

    f32x4 acc[4];
#pragma unroll
    for (int i = 0; i < 4; ++i) acc[i] = (f32x4){0.f, 0.f, 0.f, 0.f};
    wk_core32<1>(sm, A0, A1, T, zA, zB, col0, kh * 256, kh * 256 + 256, acc);

    float* O = kh ? O1 : O0;
    const int gr = wave * 16 + quad * 4;
#pragma unroll
    for (int nt = 0; nt < 4; ++nt) {
        const int gc = col0 + nt * 16 + ln;
#pragma unroll
        for (int r = 0; r < 4; ++r) {
            const long idx = zA + (long)(gr + r) * Ss + gc;
            float val = acc[nt][r];
            if (kh == 0) val += 2.0f * (A0[idx] + A1[idx]);
            O[idx] = val;
        }
    }
}

// ============ c2s_k: c2sT = inv_sig*s*(y x Wt) + negoff, XCD-swizzled 1D grid (128 = 8x16) ============
__global__ __launch_bounds__(256) void c2s_k(const float* __restrict__ A0,
                                             const float* __restrict__ A1,
                                             const _Float16* __restrict__ Wt,
                                             _Float16* __restrict__ c2sT,
                                             const float* __restrict__ scal,
                                             const float* __restrict__ inv_sig,
                                             const float* __restrict__ mu,
                                             float* __restrict__ negopart)
{
    __shared__ __align__(16) char sm[20480];
    __shared__ float red[64];
    const int L = blockIdx.x;
    const int q = L & 7, sIdx = L >> 3;     // sIdx in [0,16)
    const int z = 2 * q + (sIdx >= 8 ? 1 : 0);
    const int cb = (sIdx >= 8) ? sIdx - 8 : sIdx;
    const int h = z & 7;
    const int col0 = cb * 64;
    const long zA = (long)z * (HD * Ss);
    const long zB = (long)z * Ss * Ss;
    const int t = threadIdx.x;
    const int wave = t >> 6, lane = t & 63;
    const int ln = lane & 15, quad = lane >> 4;

    f32x4 acc[4];
#pragma unroll
    for (int i = 0; i < 4; ++i) acc[i] = (f32x4){0.f, 0.f, 0.f, 0.f};
    wk_core32<1>(sm, A0, A1, Wt, zA, zB, col0, col0, Ss, acc);

    if (t < 64) red[t] = 0.f;
    __syncthreads();
    const int gr = wave * 16 + quad * 4;
    float pr[4] = {0.f, 0.f, 0.f, 0.f};
    float s = scal[z];
#pragma unroll
    for (int nt = 0; nt < 4; ++nt) {
        const int gc = col0 + nt * 16 + ln;
#pragma unroll
        for (int r = 0; r < 4; ++r) {
            float val = inv_sig[h * 512 + gc] * (s * acc[nt][r]);
            pr[r] += mu[h * 512 + gc] * val;
            c2sT[zA + (long)(gr + r) * Ss + gc] = (_Float16)val;
        }
    }
#pragma unroll
    for (int r = 0; r < 4; ++r)
        atomicAdd(&red[gr + r], pr[r]);
    __syncthreads();
    if (t < 64)
        negopart[(z * 8 + cb) * 64 + t] = red[t];
}

// ============ ga_k: gat = Wh @ c2s - neg, XCD-swizzled 1D grid (128 = 8x16) ============
__global__ __launch_bounds__(256) void ga_k(const _Float16* __restrict__ Wh,
                                            const _Float16* __restrict__ c2sT,
                                            const float* __restrict__ negopart,
                                            float* __restrict__ gat)
{
    __shared__ __align__(16) char sm[36864];
    __shared__ float neg[64];
    const int L = blockIdx.x;
    const int q = L & 7, sIdx = L >> 3;     // sIdx in [0,16)
    const int z = 2 * q + (sIdx >= 8 ? 1 : 0);
    const int mb = (sIdx >= 8) ? sIdx - 8 : sIdx;
    const int b = z >> 3, h = z & 7;
    const int m0 = mb * 64;
    const long zA = (long)z * Ss * Ss;
    const long zB = (long)z * (HD * Ss);
    const int t = threadIdx.x;
    const int wave = t >> 6, lane = t & 63;
    const int ln = lane & 15, quad = lane >> 4;

    if (t < 64) {
        float s = 0.f;
#pragma unroll
        for (int k = 0; k < 8; ++k) s += negopart[(z * 8 + k) * 64 + t];
        neg[t] = s;
    }
    __syncthreads();

    f32x4 acc[4];
#pragma unroll
    for (int i = 0; i < 4; ++i) acc[i] = (f32x4){0.f, 0.f, 0.f, 0.f};
    wk_core(sm, c2sT, Wh, zB, zA, m0, 0, m0 + 64, acc);

    const int gr = wave * 16 + quad * 4;   // d index
#pragma unroll
    for (int nt = 0; nt < 4; ++nt) {
        const int m = m0 + nt * 16 + ln;
#pragma unroll
        for (int r = 0; r < 4; ++r) {
            const int d = gr + r;
            gat[(long)b * (Ss * DIM) + (long)m * DIM + h * HD + d] = acc[nt][r] - neg[d];
        }
    }
}

extern "C" void kernel_launch(void* const* d_in, const int* in_sizes, int n_in,
                              void* d_out, int out_size, void* d_ws, size_t ws_size,
                              hipStream_t stream)
{
    const float* x      = (const float*)d_in[0];
    const float* qkv_w  = (const float*)d_in[1];
    const float* qkv_b  = (const float*)d_in[2];
    const float* proj_w = (const float*)d_in[3];
    const float* proj_b = (const float*)d_in[4];
    float* out = (float*)d_out;
    float* ws  = (float*)d_ws;

    float* qkv     = ws;
    _Float16* Wh   = (_Float16*)(ws + 1572864);
    _Float16* Wt   = (_Float16*)(ws + 3670016);
    _Float16* vT   = (_Float16*)(ws + 5767168);
    _Float16* T[5];
    for (int i = 0; i < 5; ++i) T[i] = (_Float16*)(ws + 6029312 + (long)i * 2097152);
    float* Ya0 = ws + 16515072;   // fp32 y half-buffers, 524288 f each
    float* Ya1 = ws + 17039360;
    float* Yb0 = ws + 17563648;
    float* Yb1 = ws + 18087936;
    _Float16* c2sT = (_Float16*)(ws + 19136512);
    float* rsum    = ws + 19398656;   // 65536
    float* rsq     = ws + 19464192;   // 65536
    float* csum    = ws + 19529728;   // 65536
    float* scal    = ws + 19595264;   // 16
    float* mu      = ws + 19595280;   // 4096
    float* inv_sig = ws + 19599376;   // 4096
    float* negp    = ws + 19603472;   // 8192
    float* gat     = ws + 19611664;   // 524288

    dim3 blk(256);

    // 1. qkv = x @ qkv_w^T + qkv_b  (64x64 tiles: 384 blocks)
    mm64_k<<<dim3(24, 16), blk, 0, stream>>>(x, qkv_w, qkv_b, qkv, DIM, 3 * DIM);

    // 2. W fp16 (both layouts) + partials + vT  (XCD-swizzled 1056)
    wt_fused<<<dim3(1056), blk, 0, stream>>>(qkv, Wh, Wt, vT, rsum, rsq, csum);

    // 3. y0 = vT x Wt || scale || whitening stats || U = W W^T (XCD-swizzled)
    mid_k<<<dim3(728), blk, 0, stream>>>(vT, Wt, Ya0, rsum, rsq, csum, scal, mu, inv_sig,
                                         Wh, T[0]);

    // 4-7. fused NS steps (ascending k; factors commute), XCD-swizzled 1D grids:
    sq_k<1><<<dim3(832), blk, 0, stream>>>(T[0], T[1], Ya0, nullptr, Yb0, Yb1, scal);
    sq_k<0><<<dim3(832), blk, 0, stream>>>(T[1], T[2], Yb0, Yb1,     Ya0, Ya1, scal);
    sq_k<0><<<dim3(832), blk, 0, stream>>>(T[2], T[3], Ya0, Ya1,     Yb0, Yb1, scal);
    sq_k<0><<<dim3(832), blk, 0, stream>>>(T[3], T[4], Yb0, Yb1,     Ya0, Ya1, scal);

    // 8. final y update with T4 (XCD-swizzled 256)
    yk_k<<<dim3(256), blk, 0, stream>>>(Ya0, Ya1, T[4], Yb0, Yb1);

    // 9. c2sT = inv_sig * s * (y W) + negoff partials (XCD-swizzled 128)
    c2s_k<<<dim3(128), blk, 0, stream>>>(Yb0, Yb1, Wt, c2sT, scal, inv_sig, mu, negp);

    // 10. gat = W @ c2s - neg (XCD-swizzled 128)
    ga_k<<<dim3(128), blk, 0, stream>>>(Wh, c2sT, negp, gat);

    // 11. out = gat @ proj_w^T + proj_b  (64x64 tiles: 128 blocks)
    mm64_k<<<dim3(8, 16), blk, 0, stream>>>(gat, proj_w, proj_b, out, DIM, DIM);
}

// Round 13
// 195.596 us; speedup vs baseline: 1.5073x; 1.0151x over previous
//
#include <hip/hip_runtime.h>

#define Bq 2
#define Hh 8
#define Ss 512
#define HD 64
#define DIM 512

using f32x4   = __attribute__((ext_vector_type(4))) float;
using bf16x8s = __attribute__((ext_vector_type(8))) short;
typedef _Float16 f16x8 __attribute__((ext_vector_type(8)));

__constant__ int d_tIs[36] = {0,1,1,2,2,2,3,3,3,3,4,4,4,4,4,5,5,5,5,5,5,6,6,6,6,6,6,6,7,7,7,7,7,7,7,7};
__constant__ int d_tJs[36] = {0,0,1,0,1,2,0,1,2,3,0,1,2,3,4,0,1,2,3,4,5,0,1,2,3,4,5,6,0,1,2,3,4,5,6,7};

__device__ __forceinline__ float bf2f(unsigned short u) {
    return __uint_as_float(((unsigned int)u) << 16);
}
__device__ __forceinline__ unsigned short f2bf(float f) {
    unsigned int u = __float_as_uint(f);
    u = (u + 0x7FFFu + ((u >> 16) & 1u)) >> 16;   // RNE
    return (unsigned short)u;
}

// ============ mm64_k: C = A @ B^T + bias (fp32 io, split bf16x2 MFMA, 64x64 tiles) ============
__global__ __launch_bounds__(256) void mm64_k(
    const float* __restrict__ A, const float* __restrict__ B,
    const float* __restrict__ bias, float* __restrict__ C,
    int K, int ldc)
{
    const int row0 = blockIdx.y * 64, col0 = blockIdx.x * 64;
    __shared__ unsigned short AsH[64][40], AsL[64][40];
    __shared__ unsigned short BsH[64][40], BsL[64][40];
    const int t = threadIdx.x;
    const int wave = t >> 6, lane = t & 63;
    const int ln = lane & 15, quad = lane >> 4;

    f32x4 acc[4];
#pragma unroll
    for (int i = 0; i < 4; ++i) acc[i] = (f32x4){0.f, 0.f, 0.f, 0.f};

    const int sr = t >> 2, sg = (t & 3) * 8;

    for (int k0 = 0; k0 < K; k0 += 32) {
        __syncthreads();
#pragma unroll
        for (int half = 0; half < 2; ++half) {
            const float* src = half ? B : A;
            int base = half ? col0 : row0;
            const float* p = &src[(long)(base + sr) * K + k0 + sg];
            float4 f0 = *(const float4*)p;
            float4 f1 = *(const float4*)(p + 4);
            float fv[8] = {f0.x, f0.y, f0.z, f0.w, f1.x, f1.y, f1.z, f1.w};
            unsigned short hv[8], lv[8];
#pragma unroll
            for (int e = 0; e < 8; ++e) {
                hv[e] = f2bf(fv[e]);
                lv[e] = f2bf(fv[e] - bf2f(hv[e]));
            }
            uint4 H, L;
            H.x = hv[0] | (hv[1] << 16); H.y = hv[2] | (hv[3] << 16);
            H.z = hv[4] | (hv[5] << 16); H.w = hv[6] | (hv[7] << 16);
            L.x = lv[0] | (lv[1] << 16); L.y = lv[2] | (lv[3] << 16);
            L.z = lv[4] | (lv[5] << 16); L.w = lv[6] | (lv[7] << 16);
            if (!half) { *(uint4*)&AsH[sr][sg] = H; *(uint4*)&AsL[sr][sg] = L; }
            else       { *(uint4*)&BsH[sr][sg] = H; *(uint4*)&BsL[sr][sg] = L; }
        }
        __syncthreads();

        bf16x8s afH, afL, bfH[4], bfL[4];
        afH = *(const bf16x8s*)&AsH[wave * 16 + ln][quad * 8];
        afL = *(const bf16x8s*)&AsL[wave * 16 + ln][quad * 8];
#pragma unroll
        for (int nt = 0; nt < 4; ++nt) {
            bfH[nt] = *(const bf16x8s*)&BsH[nt * 16 + ln][quad * 8];
            bfL[nt] = *(const bf16x8s*)&BsL[nt * 16 + ln][quad * 8];
        }
#pragma unroll
        for (int nt = 0; nt < 4; ++nt) {
            acc[nt] = __builtin_amdgcn_mfma_f32_16x16x32_bf16(afH, bfH[nt], acc[nt], 0, 0, 0);
            acc[nt] = __builtin_amdgcn_mfma_f32_16x16x32_bf16(afH, bfL[nt], acc[nt], 0, 0, 0);
            acc[nt] = __builtin_amdgcn_mfma_f32_16x16x32_bf16(afL, bfH[nt], acc[nt], 0, 0, 0);
        }
    }

    const int gr0 = row0 + wave * 16 + quad * 4;
#pragma unroll
    for (int nt = 0; nt < 4; ++nt) {
        const int gc = col0 + nt * 16 + ln;
        float bb = bias[gc];
#pragma unroll
        for (int r = 0; r < 4; ++r)
            C[(long)(gr0 + r) * ldc + gc] = acc[nt][r] + bb;
    }
}

// ============ wt_fused: lower-tile enumeration (36+2 per z), XCD-swizzled (608 = 8x76) ============
// Mirror-tile partial zeroing: compute tile (ti,tj), ti>tj zeroes the slots its masked
// mirror (tj,ti) used to zero: rsum/rsq row tj cols i0.., csum row ti cols j0..
__global__ __launch_bounds__(256) void wt_fused(const float* __restrict__ qkv,
                                                _Float16* __restrict__ Wh,
                                                _Float16* __restrict__ Wt,
                                                _Float16* __restrict__ vT,
                                                float* __restrict__ rsum,
                                                float* __restrict__ rsq,
                                                float* __restrict__ csum)
{
    __shared__ float qs[32][64];
    __shared__ float ks[32][64];
    __shared__ float colacc[64];
    const int L = blockIdx.x;
    const int q = L & 7, s = L >> 3;      // s in [0,76)
    const int z = 2 * q + (s >= 38 ? 1 : 0);
    const int bx = (s >= 38) ? s - 38 : s;   // [0,38)
    int b = z >> 3, h = z & 7;
    int t = threadIdx.x;
    long zo = (long)z * Ss * Ss;

    if (bx >= 36) {            // vT pack: half dh (d 32-chunk), all k
        float (*sT)[33] = (float(*)[33])qs;
        int dt = (bx - 36) * 32;
        int d = t & 31, kr = t >> 5;
        for (int kt = 0; kt < Ss; kt += 32) {
            __syncthreads();
#pragma unroll
            for (int p = 0; p < 4; ++p) {
                int kk = kr + p * 8;
                sT[kk][d] = qkv[(long)b * (Ss * 3 * DIM) + (long)(kt + kk) * (3 * DIM) + 2 * DIM + h * HD + dt + d];
            }
            __syncthreads();
#pragma unroll
            for (int p = 0; p < 4; ++p) {
                int dd = kr + p * 8;
                vT[(long)z * (HD * Ss) + (long)(dt + dd) * Ss + kt + d] = (_Float16)sT[d][dd];
            }
        }
        return;
    }

    const int ti = d_tIs[bx], tj = d_tJs[bx];
    const int i0 = ti * 64, j0 = tj * 64;

    // zero mirror partial slots (covers all masked (tj,ti) tiles, tj<ti)
    if (ti > tj && t < 64) {
        rsum[((z * 8 + tj) * 512) + i0 + t] = 0.f;
        rsq [((z * 8 + tj) * 512) + i0 + t] = 0.f;
        csum[((z * 8 + ti) * 512) + j0 + t] = 0.f;
    }

    int ia = (t & 15) * 4;
    int ja = (t >> 4) * 4;
    const float* qb = qkv + (long)b * Ss * (3 * DIM) + h * HD;
    const float* kb = qb + DIM;
    float acc[4][4] = {};

    for (int d0 = 0; d0 < 64; d0 += 32) {
        __syncthreads();
        int row = t & 63, dg = (t >> 6) * 8;
        float4 qv  = *(const float4*)&qb[(long)(i0 + row) * (3 * DIM) + d0 + dg];
        float4 qv2 = *(const float4*)&qb[(long)(i0 + row) * (3 * DIM) + d0 + dg + 4];
        float4 kv  = *(const float4*)&kb[(long)(j0 + row) * (3 * DIM) + d0 + dg];
        float4 kv2 = *(const float4*)&kb[(long)(j0 + row) * (3 * DIM) + d0 + dg + 4];
        qs[dg+0][row] = qv.x;  qs[dg+1][row] = qv.y;  qs[dg+2][row] = qv.z;  qs[dg+3][row] = qv.w;
        qs[dg+4][row] = qv2.x; qs[dg+5][row] = qv2.y; qs[dg+6][row] = qv2.z; qs[dg+7][row] = qv2.w;
        ks[dg+0][row] = kv.x;  ks[dg+1][row] = kv.y;  ks[dg+2][row] = kv.z;  ks[dg+3][row] = kv.w;
        ks[dg+4][row] = kv2.x; ks[dg+5][row] = kv2.y; ks[dg+6][row] = kv2.z; ks[dg+7][row] = kv2.w;
        __syncthreads();
#pragma unroll
        for (int d = 0; d < 32; ++d) {
            float4 q0 = *(const float4*)&qs[d][ia];
            float4 k0 = *(const float4*)&ks[d][ja];
            float qv_[4] = {q0.x, q0.y, q0.z, q0.w};
            float kv_[4] = {k0.x, k0.y, k0.z, k0.w};
#pragma unroll
            for (int aa = 0; aa < 4; ++aa)
#pragma unroll
                for (int c = 0; c < 4; ++c)
                    acc[aa][c] += fabsf(qv_[aa] - kv_[c]);
        }
    }

#pragma unroll
    for (int aa = 0; aa < 4; ++aa) {
        int i = i0 + ia + aa;
#pragma unroll
        for (int c = 0; c < 4; ++c) {
            int j = j0 + ja + c;
            float e = expf(-acc[aa][c] * 0.25f);
            acc[aa][c] = (j <= i) ? e : 0.0f;
        }
    }
    // Wt rows + per-j partials
#pragma unroll
    for (int c = 0; c < 4; ++c) {
        int j = j0 + ja + c;
        float rs = 0.f, rq = 0.f;
#pragma unroll
        for (int aa = 0; aa < 4; ++aa) { rs += acc[aa][c]; rq += acc[aa][c] * acc[aa][c]; }
        _Float16 ha[4] __attribute__((aligned(8))) = {(_Float16)acc[0][c], (_Float16)acc[1][c], (_Float16)acc[2][c], (_Float16)acc[3][c]};
        *(uint2*)&Wt[zo + (long)j * Ss + i0 + ia] = *(const uint2*)ha;
#pragma unroll
        for (int off = 8; off > 0; off >>= 1) {
            rs += __shfl_down(rs, off, 16);
            rq += __shfl_down(rq, off, 16);
        }
        if ((t & 15) == 0) {
            rsum[((z * 8 + ti) * 512) + j] = rs;
            rsq [((z * 8 + ti) * 512) + j] = rq;
        }
    }
    // Wh rows
#pragma unroll
    for (int aa = 0; aa < 4; ++aa) {
        int i = i0 + ia + aa;
        _Float16 hb[4] __attribute__((aligned(8))) = {(_Float16)acc[aa][0], (_Float16)acc[aa][1], (_Float16)acc[aa][2], (_Float16)acc[aa][3]};
        *(uint2*)&Wh[zo + (long)i * Ss + j0 + ja] = *(const uint2*)hb;
    }
    // per-i partials via LDS
    __syncthreads();
    if (t < 64) colacc[t] = 0.f;
    __syncthreads();
#pragma unroll
    for (int aa = 0; aa < 4; ++aa) {
        float cs = acc[aa][0] + acc[aa][1] + acc[aa][2] + acc[aa][3];
        atomicAdd(&colacc[ia + aa], cs);
    }
    __syncthreads();
    if (t < 64) csum[((z * 8 + tj) * 512) + i0 + t] = colacc[t];
}

// ============ fp16-A wide core, BK=64, LDS double-buffered (1 barrier / 64-K step) ============
__device__ __forceinline__ void wk_core(char* smc, const _Float16* A, const _Float16* B,
                                        long zA, long zB, int col0, int kbeg, int kend,
                                        f32x4* acc)
{
    _Float16 (*As0)[72] = (_Float16(*)[72])smc;
    _Float16 (*Bs0)[72] = (_Float16(*)[72])(smc + 9216);
    _Float16 (*As1)[72] = (_Float16(*)[72])(smc + 18432);
    _Float16 (*Bs1)[72] = (_Float16(*)[72])(smc + 27648);
    const int t = threadIdx.x;
    const int wave = t >> 6, lane = t & 63;
    const int ln = lane & 15, quad = lane >> 4;
    const int r2 = t >> 2, c2 = (t & 3) * 16;
    const long aoff = zA + (long)r2 * Ss;
    const long boff = zB + (long)(col0 + r2) * Ss;

    uint4 ua0 = *(const uint4*)&A[aoff + kbeg + c2];
    uint4 ua1 = *(const uint4*)&A[aoff + kbeg + c2 + 8];
    uint4 ub0 = *(const uint4*)&B[boff + kbeg + c2];
    uint4 ub1 = *(const uint4*)&B[boff + kbeg + c2 + 8];
    *(uint4*)&As0[r2][c2]     = ua0;
    *(uint4*)&As0[r2][c2 + 8] = ua1;
    *(uint4*)&Bs0[r2][c2]     = ub0;
    *(uint4*)&Bs0[r2][c2 + 8] = ub1;
    int cur = 0;
    for (int k0 = kbeg; k0 < kend; k0 += 64) {
        int kn = k0 + 64;
        if (kn < kend) {
            ua0 = *(const uint4*)&A[aoff + kn + c2];
            ua1 = *(const uint4*)&A[aoff + kn + c2 + 8];
            ub0 = *(const uint4*)&B[boff + kn + c2];
            ub1 = *(const uint4*)&B[boff + kn + c2 + 8];
        }
        __syncthreads();
        _Float16 (*As)[72] = cur ? As1 : As0;
        _Float16 (*Bs)[72] = cur ? Bs1 : Bs0;
#pragma unroll
        for (int kk = 0; kk < 64; kk += 32) {
            f16x8 af = *(const f16x8*)&As[wave * 16 + ln][quad * 8 + kk];
#pragma unroll
            for (int nt = 0; nt < 4; ++nt) {
                f16x8 bf = *(const f16x8*)&Bs[nt * 16 + ln][quad * 8 + kk];
                acc[nt] = __builtin_amdgcn_mfma_f32_16x16x32_f16(af, bf, acc[nt], 0, 0, 0);
            }
        }
        if (kn < kend) {
            _Float16 (*An)[72] = cur ? As0 : As1;
            _Float16 (*Bn)[72] = cur ? Bs0 : Bs1;
            *(uint4*)&An[r2][c2]     = ua0;
            *(uint4*)&An[r2][c2 + 8] = ua1;
            *(uint4*)&Bn[r2][c2]     = ub0;
            *(uint4*)&Bn[r2][c2 + 8] = ub1;
        }
        cur ^= 1;
    }
}

// ============ fp32-halves-A wide core, BK=64, double-buffered (1 barrier / 64-K step) ============
template<int HASA1>
__device__ __forceinline__ void wk_core32(char* smc, const float* A0, const float* A1,
                                          const _Float16* B, long zA, long zB, int col0,
                                          int kbeg, int kend, f32x4* acc)
{
    _Float16 (*As0)[72] = (_Float16(*)[72])smc;
    _Float16 (*Bs0)[72] = (_Float16(*)[72])(smc + 9216);
    _Float16 (*As1)[72] = (_Float16(*)[72])(smc + 18432);
    _Float16 (*Bs1)[72] = (_Float16(*)[72])(smc + 27648);
    const int t = threadIdx.x;
    const int wave = t >> 6, lane = t & 63;
    const int ln = lane & 15, quad = lane >> 4;
    const int r2 = t >> 2, c2 = (t & 3) * 16;
    const long aoff = zA + (long)r2 * Ss;
    const long boff = zB + (long)(col0 + r2) * Ss;

    float pa[16], qa[16];
    uint4 ub0, ub1;
#pragma unroll
    for (int e = 0; e < 4; ++e)
        *(float4*)&pa[e * 4] = *(const float4*)&A0[aoff + kbeg + c2 + e * 4];
    if constexpr (HASA1) {
#pragma unroll
        for (int e = 0; e < 4; ++e)
            *(float4*)&qa[e * 4] = *(const float4*)&A1[aoff + kbeg + c2 + e * 4];
    }
    ub0 = *(const uint4*)&B[boff + kbeg + c2];
    ub1 = *(const uint4*)&B[boff + kbeg + c2 + 8];
    {
        _Float16 hv[16] __attribute__((aligned(16)));
#pragma unroll
        for (int e = 0; e < 16; ++e)
            hv[e] = HASA1 ? (_Float16)(pa[e] + qa[e]) : (_Float16)pa[e];
        *(uint4*)&As0[r2][c2]     = *(const uint4*)&hv[0];
        *(uint4*)&As0[r2][c2 + 8] = *(const uint4*)&hv[8];
        *(uint4*)&Bs0[r2][c2]     = ub0;
        *(uint4*)&Bs0[r2][c2 + 8] = ub1;
    }
    int cur = 0;
    for (int k0 = kbeg; k0 < kend; k0 += 64) {
        int kn = k0 + 64;
        if (kn < kend) {
#pragma unroll
            for (int e = 0; e < 4; ++e)
                *(float4*)&pa[e * 4] = *(const float4*)&A0[aoff + kn + c2 + e * 4];
            if constexpr (HASA1) {
#pragma unroll
                for (int e = 0; e < 4; ++e)
                    *(float4*)&qa[e * 4] = *(const float4*)&A1[aoff + kn + c2 + e * 4];
            }
            ub0 = *(const uint4*)&B[boff + kn + c2];
            ub1 = *(const uint4*)&B[boff + kn + c2 + 8];
        }
        __syncthreads();
        _Float16 (*As)[72] = cur ? As1 : As0;
        _Float16 (*Bs)[72] = cur ? Bs1 : Bs0;
#pragma unroll
        for (int kk = 0; kk < 64; kk += 32) {
            f16x8 af = *(const f16x8*)&As[wave * 16 + ln][quad * 8 + kk];
#pragma unroll
            for (int nt = 0; nt < 4; ++nt) {
                f16x8 bf = *(const f16x8*)&Bs[nt * 16 + ln][quad * 8 + kk];
                acc[nt] = __builtin_amdgcn_mfma_f32_16x16x32_f16(af, bf, acc[nt], 0, 0, 0);
            }
        }
        if (kn < kend) {
            _Float16 hv[16] __attribute__((aligned(16)));
#pragma unroll
            for (int e = 0; e < 16; ++e)
                hv[e] = HASA1 ? (_Float16)(pa[e] + qa[e]) : (_Float16)pa[e];
            _Float16 (*An)[72] = cur ? As0 : As1;
            _Float16 (*Bn)[72] = cur ? Bs0 : Bs1;
            *(uint4*)&An[r2][c2]     = *(const uint4*)&hv[0];
            *(uint4*)&An[r2][c2 + 8] = *(const uint4*)&hv[8];
            *(uint4*)&Bn[r2][c2]     = ub0;
            *(uint4*)&Bn[r2][c2 + 8] = ub1;
        }
        cur ^= 1;
    }
}

// ============ sym_core: 64x64 tile of A @ A^T, BK=64, double-buffered ============
__device__ __forceinline__ void sym_core(char* smc, const _Float16* A, long zo,
                                         int row0, int col0, int kend, f32x4* acc)
{
    _Float16 (*As0)[72] = (_Float16(*)[72])smc;
    _Float16 (*Bs0)[72] = (_Float16(*)[72])(smc + 9216);
    _Float16 (*As1)[72] = (_Float16(*)[72])(smc + 18432);
    _Float16 (*Bs1)[72] = (_Float16(*)[72])(smc + 27648);
    const int t = threadIdx.x;
    const int wave = t >> 6, lane = t & 63;
    const int ln = lane & 15, quad = lane >> 4;
    const int r2 = t >> 2, c2 = (t & 3) * 16;
    const long aoff = zo + (long)(row0 + r2) * Ss;
    const long boff = zo + (long)(col0 + r2) * Ss;
    uint4 ua0 = *(const uint4*)&A[aoff + c2];
    uint4 ua1 = *(const uint4*)&A[aoff + c2 + 8];
    uint4 ub0 = *(const uint4*)&A[boff + c2];
    uint4 ub1 = *(const uint4*)&A[boff + c2 + 8];
    *(uint4*)&As0[r2][c2]     = ua0;
    *(uint4*)&As0[r2][c2 + 8] = ua1;
    *(uint4*)&Bs0[r2][c2]     = ub0;
    *(uint4*)&Bs0[r2][c2 + 8] = ub1;
    int cur = 0;
    for (int k0 = 0; k0 < kend; k0 += 64) {
        int kn = k0 + 64;
        if (kn < kend) {
            ua0 = *(const uint4*)&A[aoff + kn + c2];
            ua1 = *(const uint4*)&A[aoff + kn + c2 + 8];
            ub0 = *(const uint4*)&A[boff + kn + c2];
            ub1 = *(const uint4*)&A[boff + kn + c2 + 8];
        }
        __syncthreads();
        _Float16 (*As)[72] = cur ? As1 : As0;
        _Float16 (*Bs)[72] = cur ? Bs1 : Bs0;
#pragma unroll
        for (int kk = 0; kk < 64; kk += 32) {
            f16x8 af = *(const f16x8*)&As[wave * 16 + ln][quad * 8 + kk];
#pragma unroll
            for (int nt = 0; nt < 4; ++nt) {
                f16x8 bf = *(const f16x8*)&Bs[nt * 16 + ln][quad * 8 + kk];
                acc[nt] = __builtin_amdgcn_mfma_f32_16x16x32_f16(af, bf, acc[nt], 0, 0, 0);
            }
        }
        if (kn < kend) {
            _Float16 (*An)[72] = cur ? As0 : As1;
            _Float16 (*Bn)[72] = cur ? Bs0 : Bs1;
            *(uint4*)&An[r2][c2]     = ua0;
            *(uint4*)&An[r2][c2 + 8] = ua1;
            *(uint4*)&Bn[r2][c2]     = ub0;
            *(uint4*)&Bn[r2][c2 + 8] = ub1;
        }
        cur ^= 1;
    }
}

// ============ sym_epilogue: coalesced dual-layout store of a 64x64 fp16 tile ============
__device__ __forceinline__ void sym_store_offdiag(char* smc, _Float16* T, long zo,
                                                  int row0, int col0,
                                                  const _Float16 (*ov)[4])
{
    _Float16 (*ltR)[72] = (_Float16(*)[72])smc;            // 9216 B
    _Float16 (*ltT)[72] = (_Float16(*)[72])(smc + 9216);   // 9216 B
    const int t = threadIdx.x;
    const int wave = t >> 6, lane = t & 63;
    const int ln = lane & 15, quad = lane >> 4;
    const int lr0 = wave * 16 + quad * 4;
    __syncthreads();                       // sym_core LDS reads complete
#pragma unroll
    for (int nt = 0; nt < 4; ++nt) {
        const int lc = nt * 16 + ln;
        *(uint2*)&ltT[lc][lr0] = *(const uint2*)ov[nt];
#pragma unroll
        for (int r = 0; r < 4; ++r)
            ltR[lr0 + r][lc] = ov[nt][r];
    }
    __syncthreads();
    const int tr = t >> 2, tcg = (t & 3) * 16;
    uint4 a0 = *(const uint4*)&ltR[tr][tcg];
    uint4 a1 = *(const uint4*)&ltR[tr][tcg + 8];
    _Float16* d0 = &T[zo + (long)(row0 + tr) * Ss + col0 + tcg];
    *(uint4*)&d0[0] = a0;
    *(uint4*)&d0[8] = a1;
    uint4 b0 = *(const uint4*)&ltT[tr][tcg];
    uint4 b1 = *(const uint4*)&ltT[tr][tcg + 8];
    _Float16* d1 = &T[zo + (long)(col0 + tr) * Ss + row0 + tcg];
    *(uint4*)&d1[0] = b0;
    *(uint4*)&d1[8] = b1;
}

// ============ mid_k: y0 (XCD-swz) | scal | stats | U = W W^T (XCD-swz) ============
__global__ __launch_bounds__(256) void mid_k(const _Float16* __restrict__ vT,
                                             const _Float16* __restrict__ Wt,
                                             float* __restrict__ y0,
                                             const float* __restrict__ rsum,
                                             const float* __restrict__ rsq,
                                             const float* __restrict__ csum,
                                             float* __restrict__ scal,
                                             float* __restrict__ mu,
                                             float* __restrict__ inv_sig,
                                             const _Float16* __restrict__ Wh,
                                             _Float16* __restrict__ U)
{
    __shared__ __align__(16) char sm[36864];
    int bx = blockIdx.x, t = threadIdx.x;
    if (bx < 128) {
        // XCD swizzle: q = bx&7 -> z in {2q, 2q+1}; Wt_z stays in one XCD's L2
        int q = bx & 7, s = bx >> 3;
        int z = 2 * q + (s >= 8 ? 1 : 0);
        int cc = s & 7;
        int col0 = cc * 64;
        long zA = (long)z * (HD * Ss), zB = (long)z * Ss * Ss;
        f32x4 acc[4];
#pragma unroll
        for (int i = 0; i < 4; ++i) acc[i] = (f32x4){0.f, 0.f, 0.f, 0.f};
        wk_core(sm, vT, Wt, zA, zB, col0, col0, Ss, acc);
        const int wave = t >> 6, lane = t & 63;
        const int ln = lane & 15, quad = lane >> 4;
        const int gr = wave * 16 + quad * 4;
#pragma unroll
        for (int nt = 0; nt < 4; ++nt) {
            const int gc = col0 + nt * 16 + ln;
#pragma unroll
            for (int r = 0; r < 4; ++r)
                y0[zA + (long)(gr + r) * Ss + gc] = acc[nt][r];
        }
    } else if (bx < 144) {
        int z = bx - 128;
        float* s1 = (float*)sm;
        float* s2 = s1 + 256;
        float mx1 = 0.f, mx2 = 0.f;
        for (int jj = t; jj < 512; jj += 256) {
            float rs = 0.f, cs = 0.f;
#pragma unroll
            for (int ti = 0; ti < 8; ++ti) {
                rs += rsum[(z * 8 + ti) * 512 + jj];
                cs += csum[(z * 8 + ti) * 512 + jj];
            }
            mx1 = fmaxf(mx1, rs);
            mx2 = fmaxf(mx2, cs);
        }
        s1[t] = mx1; s2[t] = mx2;
        __syncthreads();
        for (int off = 128; off > 0; off >>= 1) {
            if (t < off) {
                s1[t] = fmaxf(s1[t], s1[t + off]);
                s2[t] = fmaxf(s2[t], s2[t + off]);
            }
            __syncthreads();
        }
        if (t == 0) scal[z] = 1.0f / (s1[0] * s2[0]);
    } else if (bx < 152) {
        int h = bx - 144;
        for (int jj = t; jj < 512; jj += 256) {
            float s = 0.f, q = 0.f;
#pragma unroll
            for (int b = 0; b < 2; ++b)
#pragma unroll
                for (int ti = 0; ti < 8; ++ti) {
                    int zz = b * 8 + h;
                    s += rsum[(zz * 8 + ti) * 512 + jj];
                    q += rsq [(zz * 8 + ti) * 512 + jj];
                }
            float m_ = s / 1024.f;
            float var = (q - s * s / 1024.f) / 1023.f;
            inv_sig[h * 512 + jj] = 1.0f / sqrtf(var + 1e-5f);
            mu[h * 512 + jj] = m_;
        }
    } else {
        // U = W @ W^T: 576 blocks, XCD swizzle (q -> z pair, Wh_z L2-resident)
        int u = bx - 152;
        int q = u & 7, s = u >> 3;          // s in [0,72)
        int z = 2 * q + (s >= 36 ? 1 : 0);
        int tile = (s >= 36) ? s - 36 : s;
        const long zo = (long)z * Ss * Ss;
        const int ti = d_tIs[tile], tj = d_tJs[tile];
        const int row0 = ti * 64, col0 = tj * 64;
        f32x4 acc[4];
#pragma unroll
        for (int i = 0; i < 4; ++i) acc[i] = (f32x4){0.f, 0.f, 0.f, 0.f};
        sym_core(sm, Wh, zo, row0, col0, col0 + 64, acc);   // K truncated: W lower-tri
        const int wave = t >> 6, lane = t & 63;
        const int ln = lane & 15, quad = lane >> 4;
        _Float16 ov[4][4] __attribute__((aligned(8)));
#pragma unroll
        for (int nt = 0; nt < 4; ++nt)
#pragma unroll
            for (int r = 0; r < 4; ++r)
                ov[nt][r] = (_Float16)acc[nt][r];
        if (ti == tj) {
            const int gr0 = row0 + wave * 16 + quad * 4;
#pragma unroll
            for (int nt = 0; nt < 4; ++nt) {
                const int gc = col0 + nt * 16 + ln;
#pragma unroll
                for (int r = 0; r < 4; ++r)
                    U[zo + (long)(gr0 + r) * Ss + gc] = ov[nt][r];
            }
        } else {
            sym_store_offdiag(sm, U, zo, row0, col0, ov);
        }
    }
}

// ============ sq_k<FIRST>: fused T-squaring + y-update, XCD-swizzled 1D grid (832) ============
template<int FIRST>
__global__ __launch_bounds__(256) void sq_k(const _Float16* __restrict__ Tc,
                                            _Float16* __restrict__ Tn,
                                            const float* __restrict__ Y0,
                                            const float* __restrict__ Y1,
                                            float* __restrict__ O0,
                                            float* __restrict__ O1,
                                            const float* __restrict__ scal)
{
    __shared__ __align__(16) char sm[36864];
    // XCD swizzle: 832 = 8 XCDs x 104; XCD q owns z in {2q, 2q+1} -> T_z L2-resident
    const int L = blockIdx.x;
    const int q = L & 7, s = L >> 3;        // s in [0,104)
    const int z = 2 * q + (s >= 52 ? 1 : 0);
    const int x = (s >= 52) ? s - 52 : s;   // x in [0,52)
    const int t = threadIdx.x;
    const int wave = t >> 6, lane = t & 63;
    const int ln = lane & 15, quad = lane >> 4;

    if (x < 36) {
        const long zo = (long)z * Ss * Ss;
        const int ti = d_tIs[x], tj = d_tJs[x];
        const int row0 = ti * 64, col0 = tj * 64;
        f32x4 acc[4];
#pragma unroll
        for (int i = 0; i < 4; ++i) acc[i] = (f32x4){0.f, 0.f, 0.f, 0.f};
        sym_core(sm, Tc, zo, row0, col0, Ss, acc);
        const float sv = FIRST ? scal[z] : 0.f;
        const int gr0 = row0 + wave * 16 + quad * 4;
        _Float16 ov[4][4] __attribute__((aligned(8)));
#pragma unroll
        for (int nt = 0; nt < 4; ++nt) {
            const int gc = col0 + nt * 16 + ln;
#pragma unroll
            for (int r = 0; r < 4; ++r) {
                const long gi = zo + (long)(gr0 + r) * Ss + gc;
                float val;
                if (FIRST) val = sv * sv * acc[nt][r] - 2.0f * sv * (float)Tc[gi];
                else       val = 2.0f * (float)Tc[gi] + acc[nt][r];
                ov[nt][r] = (_Float16)val;
            }
        }
        if (ti == tj) {
#pragma unroll
            for (int nt = 0; nt < 4; ++nt) {
                const int gc = col0 + nt * 16 + ln;
#pragma unroll
                for (int r = 0; r < 4; ++r)
                    Tn[zo + (long)(gr0 + r) * Ss + gc] = ov[nt][r];
            }
        } else {
            sym_store_offdiag(sm, Tn, zo, row0, col0, ov);
        }
    } else {
        const int bx = x - 36;
        const int cc = bx & 7, kh = bx >> 3;
        const int col0 = cc * 64;
        const long zA = (long)z * (HD * Ss);
        const long zB = (long)z * Ss * Ss;
        f32x4 acc[4];
#pragma unroll
        for (int i = 0; i < 4; ++i) acc[i] = (f32x4){0.f, 0.f, 0.f, 0.f};
        wk_core32<FIRST ? 0 : 1>(sm, Y0, Y1, Tc, zA, zB, col0, kh * 256, kh * 256 + 256, acc);
        const float alpha = FIRST ? -scal[z] : 1.0f;
        float* O = kh ? O1 : O0;
        const int gr = wave * 16 + quad * 4;
#pragma unroll
        for (int nt = 0; nt < 4; ++nt) {
            const int gc = col0 + nt * 16 + ln;
#pragma unroll
            for (int r = 0; r < 4; ++r) {
                const long idx = zA + (long)(gr + r) * Ss + gc;
                float val = alpha * acc[nt][r];
                if (kh == 0) {
                    if (FIRST) val += 2.0f * Y0[idx];
                    else       val += 2.0f * (Y0[idx] + Y1[idx]);
                }
                O[idx] = val;
            }
        }
    }
}

// ============ yk_k: y' = 2*y + y x T, split-K=2, XCD-swizzled 1D grid (256 = 8x32) ============
__global__ __launch_bounds__(256) void yk_k(const float* __restrict__ A0,
                                            const float* __restrict__ A1,
                                            const _Float16* __restrict__ T,
                                            float* __restrict__ O0,
                                            float* __restrict__ O1)
{
    __shared__ __align__(16) char sm[36864];
    const int L = blockIdx.x;
    const int q = L & 7, s = L >> 3;        // s in [0,32)
    const int z = 2 * q + (s >= 16 ? 1 : 0);
    const int w = (s >= 16) ? s - 16 : s;   // w in [0,16)
    const int cc = w & 7, kh = w >> 3;
    const int col0 = cc * 64;
    const long zA = (long)z * (HD * Ss);
    const long zB = (long)z * Ss * Ss;
    const int t = threadIdx.x;
    const int wave = t >> 6, lane = t & 63;
    const int ln = lane & 15, quad = lane >> 4;

    f32x4 acc[4];
#pragma unroll
    for (int i = 0; i < 4; ++i) acc[i] = (f32x4){0.f, 0.f, 0.f, 0.f};
    wk_core32<1>(sm, A0, A1, T, zA, zB, col0, kh * 256, kh * 256 + 256, acc);

    float* O = kh ? O1 : O0;
    const int gr = wave * 16 + quad * 4;
#pragma unroll
    for (int nt = 0; nt < 4; ++nt) {
        const int gc = col0 + nt * 16 + ln;
#pragma unroll
        for (int r = 0; r < 4; ++r) {
            const long idx = zA + (long)(gr + r) * Ss + gc;
            float val = acc[nt][r];
            if (kh == 0) val += 2.0f * (A0[idx] + A1[idx]);
            O[idx] = val;
        }
    }
}

// ============ c2s_k: c2sT = inv_sig*s*(y x Wt) + negoff, XCD-swizzled 1D grid (128 = 8x16) ============
__global__ __launch_bounds__(256) void c2s_k(const float* __restrict__ A0,
                                             const float* __restrict__ A1,
                                             const _Float16* __restrict__ Wt,
                                             _Float16* __restrict__ c2sT,
                                             const float* __restrict__ scal,
                                             const float* __restrict__ inv_sig,
                                             const float* __restrict__ mu,
                                             float* __restrict__ negopart)
{
    __shared__ __align__(16) char sm[36864];
    __shared__ float red[64];
    const int L = blockIdx.x;
    const int q = L & 7, sIdx = L >> 3;     // sIdx in [0,16)
    const int z = 2 * q + (sIdx >= 8 ? 1 : 0);
    const int cb = (sIdx >= 8) ? sIdx - 8 : sIdx;
    const int h = z & 7;
    const int col0 = cb * 64;
    const long zA = (long)z * (HD * Ss);
    const long zB = (long)z * Ss * Ss;
    const int t = threadIdx.x;
    const int wave = t >> 6, lane = t & 63;
    const int ln = lane & 15, quad = lane >> 4;

    f32x4 acc[4];
#pragma unroll
    for (int i = 0; i < 4; ++i) acc[i] = (f32x4){0.f, 0.f, 0.f, 0.f};
    wk_core32<1>(sm, A0, A1, Wt, zA, zB, col0, col0, Ss, acc);

    if (t < 64) red[t] = 0.f;
    __syncthreads();
    const int gr = wave * 16 + quad * 4;
    float pr[4] = {0.f, 0.f, 0.f, 0.f};
    float s = scal[z];
#pragma unroll
    for (int nt = 0; nt < 4; ++nt) {
        const int gc = col0 + nt * 16 + ln;
#pragma unroll
        for (int r = 0; r < 4; ++r) {
            float val = inv_sig[h * 512 + gc] * (s * acc[nt][r]);
            pr[r] += mu[h * 512 + gc] * val;
            c2sT[zA + (long)(gr + r) * Ss + gc] = (_Float16)val;
        }
    }
#pragma unroll
    for (int r = 0; r < 4; ++r)
        atomicAdd(&red[gr + r], pr[r]);
    __syncthreads();
    if (t < 64)
        negopart[(z * 8 + cb) * 64 + t] = red[t];
}

// ============ ga_k: gat = Wh @ c2s - neg, XCD-swizzled 1D grid (128 = 8x16) ============
__global__ __launch_bounds__(256) void ga_k(const _Float16* __restrict__ Wh,
                                            const _Float16* __restrict__ c2sT,
                                            const float* __restrict__ negopart,
                                            float* __restrict__ gat)
{
    __shared__ __align__(16) char sm[36864];
    __shared__ float neg[64];
    const int L = blockIdx.x;
    const int q = L & 7, sIdx = L >> 3;     // sIdx in [0,16)
    const int z = 2 * q + (sIdx >= 8 ? 1 : 0);
    const int mb = (sIdx >= 8) ? sIdx - 8 : sIdx;
    const int b = z >> 3, h = z & 7;
    const int m0 = mb * 64;
    const long zA = (long)z * Ss * Ss;
    const long zB = (long)z * (HD * Ss);
    const int t = threadIdx.x;
    const int wave = t >> 6, lane = t & 63;
    const int ln = lane & 15, quad = lane >> 4;

    if (t < 64) {
        float s = 0.f;
#pragma unroll
        for (int k = 0; k < 8; ++k) s += negopart[(z * 8 + k) * 64 + t];
        neg[t] = s;
    }
    __syncthreads();

    f32x4 acc[4];
#pragma unroll
    for (int i = 0; i < 4; ++i) acc[i] = (f32x4){0.f, 0.f, 0.f, 0.f};
    wk_core(sm, c2sT, Wh, zB, zA, m0, 0, m0 + 64, acc);

    const int gr = wave * 16 + quad * 4;   // d index
#pragma unroll
    for (int nt = 0; nt < 4; ++nt) {
        const int m = m0 + nt * 16 + ln;
#pragma unroll
        for (int r = 0; r < 4; ++r) {
            const int d = gr + r;
            gat[(long)b * (Ss * DIM) + (long)m * DIM + h * HD + d] = acc[nt][r] - neg[d];
        }
    }
}

extern "C" void kernel_launch(void* const* d_in, const int* in_sizes, int n_in,
                              void* d_out, int out_size, void* d_ws, size_t ws_size,
                              hipStream_t stream)
{
    const float* x      = (const float*)d_in[0];
    const float* qkv_w  = (const float*)d_in[1];
    const float* qkv_b  = (const float*)d_in[2];
    const float* proj_w = (const float*)d_in[3];
    const float* proj_b = (const float*)d_in[4];
    float* out = (float*)d_out;
    float* ws  = (float*)d_ws;

    float* qkv     = ws;
    _Float16* Wh   = (_Float16*)(ws + 1572864);
    _Float16* Wt   = (_Float16*)(ws + 3670016);
    _Float16* vT   = (_Float16*)(ws + 5767168);
    _Float16* T[5];
    for (int i = 0; i < 5; ++i) T[i] = (_Float16*)(ws + 6029312 + (long)i * 2097152);
    float* Ya0 = ws + 16515072;   // fp32 y half-buffers, 524288 f each
    float* Ya1 = ws + 17039360;
    float* Yb0 = ws + 17563648;
    float* Yb1 = ws + 18087936;
    _Float16* c2sT = (_Float16*)(ws + 19136512);
    float* rsum    = ws + 19398656;   // 65536
    float* rsq     = ws + 19464192;   // 65536
    float* csum    = ws + 19529728;   // 65536
    float* scal    = ws + 19595264;   // 16
    float* mu      = ws + 19595280;   // 4096
    float* inv_sig = ws + 19599376;   // 4096
    float* negp    = ws + 19603472;   // 8192
    float* gat     = ws + 19611664;   // 524288

    dim3 blk(256);

    // 1. qkv = x @ qkv_w^T + qkv_b  (64x64 tiles: 384 blocks)
    mm64_k<<<dim3(24, 16), blk, 0, stream>>>(x, qkv_w, qkv_b, qkv, DIM, 3 * DIM);

    // 2. W fp16 (both layouts) + partials + vT  (lower tiles only, XCD-swizzled 608)
    wt_fused<<<dim3(608), blk, 0, stream>>>(qkv, Wh, Wt, vT, rsum, rsq, csum);

    // 3. y0 = vT x Wt || scale || whitening stats || U = W W^T (XCD-swizzled)
    mid_k<<<dim3(728), blk, 0, stream>>>(vT, Wt, Ya0, rsum, rsq, csum, scal, mu, inv_sig,
                                         Wh, T[0]);

    // 4-7. fused NS steps (ascending k; factors commute), XCD-swizzled 1D grids:
    sq_k<1><<<dim3(832), blk, 0, stream>>>(T[0], T[1], Ya0, nullptr, Yb0, Yb1, scal);
    sq_k<0><<<dim3(832), blk, 0, stream>>>(T[1], T[2], Yb0, Yb1,     Ya0, Ya1, scal);
    sq_k<0><<<dim3(832), blk, 0, stream>>>(T[2], T[3], Ya0, Ya1,     Yb0, Yb1, scal);
    sq_k<0><<<dim3(832), blk, 0, stream>>>(T[3], T[4], Yb0, Yb1,     Ya0, Ya1, scal);

    // 8. final y update with T4 (XCD-swizzled 256)
    yk_k<<<dim3(256), blk, 0, stream>>>(Ya0, Ya1, T[4], Yb0, Yb1);

    // 9. c2sT = inv_sig * s * (y W) + negoff partials (XCD-swizzled 128)
    c2s_k<<<dim3(128), blk, 0, stream>>>(Yb0, Yb1, Wt, c2sT, scal, inv_sig, mu, negp);

    // 10. gat = W @ c2s - neg (XCD-swizzled 128)
    ga_k<<<dim3(128), blk, 0, stream>>>(Wh, c2sT, negp, gat);

    // 11. out = gat @ proj_w^T + proj_b  (64x64 tiles: 128 blocks)
    mm64_k<<<dim3(8, 16), blk, 0, stream>>>(gat, proj_w, proj_b, out, DIM, DIM);
}